// Round 12
// baseline (398.569 us; speedup 1.0000x reference)
//
#include <hip/hip_runtime.h>

typedef unsigned short ushort_t;
typedef unsigned int uint_t;
typedef unsigned char uchar_t;
typedef unsigned long long ull_t;

#define N_NODES 50000
#define N_EDGES 800000
#define HID 128
#define NGRAPH 64
#define NB_SCAN 196   // ceil(50000/256) == coarse buckets
#define N_RT 3125     // row tiles of 16 nodes
#define NBKT 196
#define CHUNK 4096    // edges per pass-A block
#define NB_TEMP 12500 // temporal blocks (x512 elems)
#define NB_WS 512     // wsplit blocks
#define BCAP 6144     // passB LDS stage capacity (mean 4096 + 32 sigma)

typedef __attribute__((ext_vector_type(8))) short short8;
typedef __attribute__((ext_vector_type(4))) float float4v;
typedef __attribute__((ext_vector_type(2))) float float2v;

// ---------- bf16 helpers ----------
__device__ __forceinline__ float bf2f(uint_t u) {
    union { uint_t i; float f; } v; v.i = u << 16; return v.f;
}
__device__ __forceinline__ ushort_t f2bf(float f) {
    union { float f; uint_t i; } v; v.f = f;
    uint_t r = v.i + 0x7FFFu + ((v.i >> 16) & 1u);
    return (ushort_t)(r >> 16);
}

// ---------- fp8 e4m3 helpers ----------
#if __has_builtin(__builtin_amdgcn_cvt_pk_fp8_f32) && __has_builtin(__builtin_amdgcn_cvt_pk_f32_fp8)
#define HAS_FP8_CVT 1
#else
#define HAS_FP8_CVT 0
#endif

__device__ __forceinline__ uchar_t f2fp8(float x) {
#if HAS_FP8_CVT
    int p = __builtin_amdgcn_cvt_pk_fp8_f32(x, x, 0, false);
    return (uchar_t)(p & 0xFF);
#else
    union { float f; uint_t u; } v; v.f = x;
    uint_t s = (v.u >> 31) << 7;
    float a = fabsf(x);
    a = fminf(a, 448.f);
    if (a < 0.015625f) {
        int m3 = (int)(a * 512.f + 0.5f);
        return (uchar_t)(s | (uint_t)m3);
    }
    v.f = a;
    uint_t r = v.u + 0x7FFFFu + ((v.u >> 20) & 1u);
    uint_t e = r >> 23;
    return (uchar_t)(s | ((e - 120u) << 3) | ((r >> 20) & 7u));
#endif
}

__device__ __forceinline__ float fp8dec1(uint_t b) {
    uint_t e = (b >> 3) & 15u, mnt = b & 7u;
    union { uint_t u; float f; } v;
    v.u = ((e + 120u) << 23) | (mnt << 20);
    float mag = e ? v.f : (float)mnt * 0.001953125f;  // 2^-9
    return (b & 0x80u) ? -mag : mag;
}

__device__ __forceinline__ void fp8x4_dec2(uint_t w, float2v* o) {
#if HAS_FP8_CVT
    o[0] = __builtin_amdgcn_cvt_pk_f32_fp8(w, false);
    o[1] = __builtin_amdgcn_cvt_pk_f32_fp8(w, true);
#else
    float2v a, b;
    a.x = fp8dec1(w & 0xFFu);  a.y = fp8dec1((w >> 8) & 0xFFu);
    b.x = fp8dec1((w >> 16) & 0xFFu); b.y = fp8dec1(w >> 24);
    o[0] = a; o[1] = b;
#endif
}

// ---------- CSR: degree histogram ----------
__global__ void deg_kernel(const int* __restrict__ ei, int* __restrict__ deg) {
    int e = blockIdx.x * blockDim.x + threadIdx.x;
    if (e < N_EDGES) atomicAdd(&deg[ei[N_EDGES + e]], 1);
}

// ---------- single-dispatch scan: decoupled lookback over 196 blocks --------
// Also inits bucketcur, off[N_NODES], and zeroes sums/cnt.
// sstate[b] packed: (state<<32)|value. state 1=aggregate, 2=inclusive prefix.
__global__ __launch_bounds__(256) void scan_kernel(
    const int* __restrict__ deg, int* __restrict__ off,
    int* __restrict__ bucketcur, float* __restrict__ sums,
    float* __restrict__ cnt, ull_t* __restrict__ sstate) {
    __shared__ int buf[256];
    __shared__ int pre_s;
    int b = blockIdx.x, t = threadIdx.x;
    int n = b * 256 + t;
    int v = (n < N_NODES) ? deg[n] : 0;
    buf[t] = v;
    __syncthreads();
    #pragma unroll
    for (int s = 1; s < 256; s <<= 1) {
        int add = (t >= s) ? buf[t - s] : 0;
        __syncthreads();
        buf[t] += add;
        __syncthreads();
    }
    int incl = buf[t];
    int total = buf[255];
    if (t == 0) {
        if (b == 0) {
            atomicExch(&sstate[0], (2ULL << 32) | (uint_t)total);
            pre_s = 0;
        } else {
            atomicExch(&sstate[b], (1ULL << 32) | (uint_t)total);
            int run = 0, i = b - 1;
            while (true) {
                ull_t w;
                do { w = atomicAdd(&sstate[i], 0ULL); } while ((w >> 32) == 0);
                run += (int)(uint_t)w;
                if ((w >> 32) == 2ULL) break;
                i--;
            }
            pre_s = run;
            atomicExch(&sstate[b], (2ULL << 32) | (uint_t)(run + total));
        }
    }
    __syncthreads();
    int pre = pre_s;
    if (n < N_NODES) off[n] = pre + incl - v;
    if (t == 0) bucketcur[b] = pre;
    if (b == NB_SCAN - 1 && t == 0) off[N_NODES] = pre + total;
    // zero pool accumulators (pool runs much later)
    if (b < 32) sums[b * 256 + t] = 0.f;
    if (b == 32 && t < NGRAPH) cnt[t] = 0.f;
}

// ---------- prep mega-kernel: passA bucket-scatter + temporal + wsplit ------
__global__ __launch_bounds__(256) void prep_kernel(
    const int* __restrict__ ei, const int* __restrict__ off,
    int* __restrict__ bucketcur, int* __restrict__ arena,
    const float* __restrict__ x, const float* __restrict__ ts,
    ushort_t* __restrict__ h,
    const float* __restrict__ Wq1, const float* __restrict__ Wk1,
    const float* __restrict__ Wv1, const float* __restrict__ Ws1,
    const float* __restrict__ Wq2, const float* __restrict__ Wk2,
    const float* __restrict__ Wv2, const float* __restrict__ Ws2,
    const float* __restrict__ bq1, const float* __restrict__ bk1,
    const float* __restrict__ bv1, const float* __restrict__ bs1,
    const float* __restrict__ bq2, const float* __restrict__ bk2,
    const float* __restrict__ bv2, const float* __restrict__ bs2,
    ushort_t* __restrict__ WF, float* __restrict__ bias_cat) {
    __shared__ int hist[NBKT];
    __shared__ int lofs[NBKT];
    __shared__ int lcur[NBKT];
    __shared__ int gbase[NBKT];
    __shared__ int sbuf[256];
    __shared__ uint_t staging[CHUNK];
    __shared__ int tot_s;

    int blk = blockIdx.x;
    int t = threadIdx.x;

    if (blk < NBKT) {
        // ---------------- pass A ----------------
        if (t < NBKT) hist[t] = 0;
        __syncthreads();
        int e0 = blk * CHUNK;
        int srcs[16], dsts[16];
        #pragma unroll
        for (int i = 0; i < 16; i++) {
            int idx = e0 + i * 256 + t;
            bool v = idx < N_EDGES;
            srcs[i] = v ? ei[idx] : -1;
            dsts[i] = v ? ei[N_EDGES + idx] : -1;
            if (v) atomicAdd(&hist[dsts[i] >> 8], 1);
        }
        __syncthreads();
        int hv = (t < NBKT) ? hist[t] : 0;
        sbuf[t] = hv;
        __syncthreads();
        #pragma unroll
        for (int s = 1; s < 256; s <<= 1) {
            int add = (t >= s) ? sbuf[t - s] : 0;
            __syncthreads();
            sbuf[t] += add;
            __syncthreads();
        }
        if (t < NBKT) {
            lofs[t] = sbuf[t] - hv;
            lcur[t] = sbuf[t] - hv;
        }
        if (t == NBKT - 1) tot_s = sbuf[NBKT - 1];
        __syncthreads();
        #pragma unroll
        for (int i = 0; i < 16; i++) {
            if (srcs[i] >= 0) {
                int bkt = dsts[i] >> 8;
                int pos = atomicAdd(&lcur[bkt], 1);
                staging[pos] = ((uint_t)bkt << 24) | ((uint_t)(dsts[i] & 255) << 16)
                             | (uint_t)srcs[i];
            }
        }
        __syncthreads();
        if (t < NBKT) {
            int hcnt = hist[t];
            gbase[t] = hcnt ? atomicAdd(&bucketcur[t], hcnt) : 0;
        }
        __syncthreads();
        int tot = tot_s;
        for (int i = t; i < tot; i += 256) {
            uint_t e = staging[i];
            int bkt = e >> 24;
            arena[gbase[bkt] + (i - lofs[bkt])] = (int)(e & 0xFFFFFF);
        }
    } else if (blk < NBKT + NB_TEMP) {
        // ---------------- temporal ----------------
        int base = (blk - NBKT) * 512;
        #pragma unroll
        for (int u = 0; u < 2; u++) {
            int tid = base + u * 256 + t;
            int rt   = tid >> 11;
            int kt   = (tid >> 9) & 3;
            int lane = (tid >> 3) & 63;
            int j    = tid & 7;
            int n = rt * 16 + (lane & 15);
            int c = kt * 32 + (lane >> 4) * 8 + j;
            float tv = ts[n];
            const float coef = -0.07195570687f;  // -ln(10000)/128
            float ang = tv * __expf((float)(c & ~1) * coef);
            float pe = (c & 1) ? __cosf(ang) : __sinf(ang);
            h[tid] = f2bf(x[n * 128 + c] + pe);
        }
    } else {
        // ---------------- wsplit ----------------
        int tid = (blk - NBKT - NB_TEMP) * 256 + t;  // 0..131071
        int j    = tid & 7;
        int lane = (tid >> 3) & 63;
        int kt   = (tid >> 9) & 3;
        int cgy  = (tid >> 11) & 31;
        int L    = tid >> 16;
        int col = cgy * 16 + (lane & 15);
        int k   = kt * 32 + (lane >> 4) * 8 + j;
        int mat = col >> 7, c = col & 127;
        const float* W = (L == 0)
            ? ((mat == 0) ? Wq1 : (mat == 1) ? Wk1 : (mat == 2) ? Wv1 : Ws1)
            : ((mat == 0) ? Wq2 : (mat == 1) ? Wk2 : (mat == 2) ? Wv2 : Ws2);
        size_t base = (size_t)L * 65536 + (size_t)cgy * 2048 + (size_t)kt * 512;
        WF[base + lane * 8 + j] = f2bf(W[k * 128 + c]);
        if (kt == 0 && (lane >> 4) == 0 && j == 0) {
            const float* b = (L == 0)
                ? ((mat == 0) ? bq1 : (mat == 1) ? bk1 : (mat == 2) ? bv1 : bs1)
                : ((mat == 0) ? bq2 : (mat == 1) ? bk2 : (mat == 2) ? bv2 : bs2);
            bias_cat[L * 512 + col] = b[c];
        }
    }
}

// ---------- shared gemm body (used by fused L1 kernel and plain L2) ----------
__device__ __forceinline__ void gemm_body(
    int rp, int cg0, int lane, int quad, int m,
    const ushort_t* __restrict__ hf, const ushort_t* __restrict__ WF,
    const float* __restrict__ bias_cat,
    ushort_t* __restrict__ qsb, uchar_t* __restrict__ kv8) {
    int rt0 = rp * 2;
    if (rt0 >= N_RT) return;
    int rt1 = rt0 + 1;
    int rt1c = (rt1 < N_RT) ? rt1 : rt0;

    short8 a0[4], a1[4];
    {
        const ushort_t* b0 = hf + (size_t)rt0 * 2048 + lane * 8;
        const ushort_t* b1 = hf + (size_t)rt1c * 2048 + lane * 8;
        #pragma unroll
        for (int kt = 0; kt < 4; kt++) {
            a0[kt] = *reinterpret_cast<const short8*>(b0 + kt * 512);
            a1[kt] = *reinterpret_cast<const short8*>(b1 + kt * 512);
        }
    }

    const ushort_t* wfl = WF + (size_t)cg0 * 2048 + lane * 8;
    #pragma unroll 2
    for (int cg = 0; cg < 8; cg++) {
        const ushort_t* fp = wfl + (size_t)cg * 2048;
        float4v acc0 = {0.f, 0.f, 0.f, 0.f};
        float4v acc1 = {0.f, 0.f, 0.f, 0.f};
        #pragma unroll
        for (int kt = 0; kt < 4; kt++) {
            short8 bh = *reinterpret_cast<const short8*>(fp + kt * 512);
            acc0 = __builtin_amdgcn_mfma_f32_16x16x32_bf16(a0[kt], bh, acc0, 0, 0, 0);
            acc1 = __builtin_amdgcn_mfma_f32_16x16x32_bf16(a1[kt], bh, acc1, 0, 0, 0);
        }
        int col = (cg0 + cg) * 16 + m;
        float bias = bias_cat[col];
        int mat = col >> 7;
        #pragma unroll
        for (int r = 0; r < 4; r++) {
            float v0 = acc0[r] + bias;
            size_t row0 = (size_t)rt0 * 16 + quad * 4 + r;
            if (mat == 0)      qsb[row0 * 256 + col] = f2bf(v0);
            else if (mat == 3) qsb[row0 * 256 + (col - 256)] = f2bf(v0);
            else               kv8[row0 * 256 + (col - 128)] = f2fp8(v0);
        }
        if (rt1 < N_RT) {
            #pragma unroll
            for (int r = 0; r < 4; r++) {
                float v1 = acc1[r] + bias;
                size_t row1 = (size_t)rt1 * 16 + quad * 4 + r;
                if (mat == 0)      qsb[row1 * 256 + col] = f2bf(v1);
                else if (mat == 3) qsb[row1 * 256 + (col - 256)] = f2bf(v1);
                else               kv8[row1 * 256 + (col - 128)] = f2fp8(v1);
            }
        }
    }
}

// ---------- fused: passB (blocks 0..195) + gemm L1 (blocks 196..1759) -------
__global__ __launch_bounds__(256) void g1_kernel(
    const int* __restrict__ off, const int* __restrict__ arena,
    int* __restrict__ csr,
    const ushort_t* __restrict__ hf, const ushort_t* __restrict__ WF,
    const float* __restrict__ bias_cat,
    ushort_t* __restrict__ qsb, uchar_t* __restrict__ kv8) {
    __shared__ uint_t smem[BCAP + 257 + 256];
    int blk = blockIdx.x;
    int t = threadIdx.x;
    if (blk < NBKT) {
        // ---- passB: arena bucket -> exact csr positions ----
        uint_t* stage = smem;
        int* offL = (int*)(smem + BCAP);
        int* lcur = (int*)(smem + BCAP + 257);
        int n0 = blk * 256;
        int nEnd = (n0 + 256 < N_NODES) ? n0 + 256 : N_NODES;
        int base = off[n0];
        int end = off[nEnd];
        int size = end - base;
        if (n0 + t < nEnd) offL[t] = off[n0 + t] - base;
        lcur[t] = 0;
        __syncthreads();
        int lim = (size < BCAP) ? size : BCAP;
        for (int i = t; i < lim; i += 256) stage[i] = (uint_t)arena[base + i];
        __syncthreads();
        for (int i = t; i < size; i += 256) {
            uint_t e = (i < BCAP) ? stage[i] : (uint_t)arena[base + i];
            int dlow = (e >> 16) & 255;
            int src = (int)(e & 0xFFFF);
            int pos = offL[dlow] + atomicAdd(&lcur[dlow], 1);
            csr[base + pos] = src;
        }
    } else {
        // ---- gemm L1 ----
        int blk2 = blk - NBKT;           // 0..1563
        int y = blk2 / 391, bx = blk2 % 391;
        int wave = t >> 6, lane = t & 63;
        gemm_body(bx * 4 + wave, y * 8, lane, lane >> 4, lane & 15,
                  hf, WF, bias_cat, qsb, kv8);
    }
}

// ---------- plain gemm (layer 2) ----------
__global__ __launch_bounds__(256) void gemm_qkvs(
    const ushort_t* __restrict__ hf,
    const ushort_t* __restrict__ WF,
    const float* __restrict__ bias_cat,
    ushort_t* __restrict__ qsb, uchar_t* __restrict__ kv8) {
    int t = threadIdx.x;
    int wave = t >> 6, lane = t & 63;
    gemm_body(blockIdx.x * 4 + wave, blockIdx.y * 8, lane, lane >> 4, lane & 15,
              hf, WF, bias_cat, qsb, kv8);
}

// ---------- fused per-node attention + skip + BN + relu -> h (frag-major) ----
// One wave per node; quarter-wave per edge (4 in flight); pk_fma_f32 dot.
__global__ __launch_bounds__(256) void node_attn_bn(
    const int* __restrict__ off, const int* __restrict__ csr_src,
    const ushort_t* __restrict__ qsb, const uchar_t* __restrict__ kv8,
    const float* __restrict__ bng, const float* __restrict__ bnb,
    const float* __restrict__ bnm, const float* __restrict__ bnv,
    ushort_t* __restrict__ h) {
    int wave = threadIdx.x >> 6;
    int n = blockIdx.x * 4 + wave;
    if (n >= N_NODES) return;
    int lane = threadIdx.x & 63;
    int qtr = lane >> 4, s16 = lane & 15;
    int c0 = s16 * 8;

    const ushort_t* row_qs = qsb + (size_t)n * 256;
    float2v q2[4];
    {
        uint4 qu = *reinterpret_cast<const uint4*>(row_qs + c0);
        q2[0].x = bf2f(qu.x & 0xffff) * 0.125f; q2[0].y = bf2f(qu.x >> 16) * 0.125f;
        q2[1].x = bf2f(qu.y & 0xffff) * 0.125f; q2[1].y = bf2f(qu.y >> 16) * 0.125f;
        q2[2].x = bf2f(qu.z & 0xffff) * 0.125f; q2[2].y = bf2f(qu.z >> 16) * 0.125f;
        q2[3].x = bf2f(qu.w & 0xffff) * 0.125f; q2[3].y = bf2f(qu.w >> 16) * 0.125f;
    }

    int e0 = off[n], e1 = off[n + 1];
    float l = 0.f;
    float2v o2[4];
    o2[0] = (float2v){0.f, 0.f}; o2[1] = (float2v){0.f, 0.f};
    o2[2] = (float2v){0.f, 0.f}; o2[3] = (float2v){0.f, 0.f};

    int src_next = (e0 + qtr < e1) ? csr_src[e0 + qtr] : 0;
    for (int p = e0; p < e1; p += 4) {
        int idx = p + qtr;
        bool valid = idx < e1;
        int src = src_next;
        int nidx = idx + 4;
        if (nidx < e1) src_next = csr_src[nidx];
        const uchar_t* kvp = kv8 + (size_t)src * 256;
        uint2 ku = *reinterpret_cast<const uint2*>(kvp + c0);
        uint2 vu = *reinterpret_cast<const uint2*>(kvp + 128 + c0);
        float2v k2[4], vv2[4];
        fp8x4_dec2(ku.x, k2);  fp8x4_dec2(ku.y, k2 + 2);
        fp8x4_dec2(vu.x, vv2); fp8x4_dec2(vu.y, vv2 + 2);
        float2v d2 = q2[0] * k2[0];
        d2 += q2[1] * k2[1];
        d2 += q2[2] * k2[2];
        d2 += q2[3] * k2[3];
        float d = d2.x + d2.y;
        d += __shfl_xor(d, 1);
        d += __shfl_xor(d, 2);
        d += __shfl_xor(d, 4);
        float pe = valid ? __expf(d) : 0.f;
        l += pe;
        float2v pe2; pe2.x = pe; pe2.y = pe;
        o2[0] += pe2 * vv2[0];
        o2[1] += pe2 * vv2[1];
        o2[2] += pe2 * vv2[2];
        o2[3] += pe2 * vv2[3];
    }
    #pragma unroll
    for (int offx = 16; offx <= 32; offx <<= 1) {
        l += __shfl_xor(l, offx);
        #pragma unroll
        for (int i = 0; i < 4; i++) {
            o2[i].x += __shfl_xor(o2[i].x, offx);
            o2[i].y += __shfl_xor(o2[i].y, offx);
        }
    }

    if (qtr == 0) {
        float inv = 1.f / (l + 1e-16f);
        float o[8] = {o2[0].x, o2[0].y, o2[1].x, o2[1].y,
                      o2[2].x, o2[2].y, o2[3].x, o2[3].y};
        float sv[8];
        {
            uint4 su = *reinterpret_cast<const uint4*>(row_qs + 128 + c0);
            sv[0] = bf2f(su.x & 0xffff); sv[1] = bf2f(su.x >> 16);
            sv[2] = bf2f(su.y & 0xffff); sv[3] = bf2f(su.y >> 16);
            sv[4] = bf2f(su.z & 0xffff); sv[5] = bf2f(su.z >> 16);
            sv[6] = bf2f(su.w & 0xffff); sv[7] = bf2f(su.w >> 16);
        }
        float gv[8], bv[8], mv[8], vr[8];
        *reinterpret_cast<float4*>(gv)     = *reinterpret_cast<const float4*>(bng + c0);
        *reinterpret_cast<float4*>(gv + 4) = *reinterpret_cast<const float4*>(bng + c0 + 4);
        *reinterpret_cast<float4*>(bv)     = *reinterpret_cast<const float4*>(bnb + c0);
        *reinterpret_cast<float4*>(bv + 4) = *reinterpret_cast<const float4*>(bnb + c0 + 4);
        *reinterpret_cast<float4*>(mv)     = *reinterpret_cast<const float4*>(bnm + c0);
        *reinterpret_cast<float4*>(mv + 4) = *reinterpret_cast<const float4*>(bnm + c0 + 4);
        *reinterpret_cast<float4*>(vr)     = *reinterpret_cast<const float4*>(bnv + c0);
        *reinterpret_cast<float4*>(vr + 4) = *reinterpret_cast<const float4*>(bnv + c0 + 4);
        uint_t hw[4];
        #pragma unroll
        for (int i = 0; i < 8; i++) {
            float val = fmaxf(o[i] * inv + sv[i], 0.f);
            val = (val - mv[i]) * rsqrtf(vr[i] + 1e-5f) * gv[i] + bv[i];
            val = fmaxf(val, 0.f);
            ushort_t hb = f2bf(val);
            if (i & 1) hw[i >> 1] |= (uint_t)hb << 16;
            else       hw[i >> 1] = hb;
        }
        int rt = n >> 4, mnode = n & 15;
        int kt = s16 >> 2, qd = s16 & 3;
        size_t fidx = (size_t)rt * 2048 + kt * 512 + (mnode + 16 * qd) * 8;
        uint4 hp; hp.x = hw[0]; hp.y = hw[1]; hp.z = hw[2]; hp.w = hw[3];
        *reinterpret_cast<uint4*>(h + fidx) = hp;
    }
}

// ---------- global mean pool ----------
__global__ void pool_kernel(const ushort_t* __restrict__ h,
                            const int* __restrict__ batch,
                            float* __restrict__ sums,
                            float* __restrict__ cnt) {
    int t = threadIdx.x;
    int c = t & 127, half = t >> 7;
    int kt = c >> 5, qd = (c >> 3) & 3, j = c & 7;
    int base = blockIdx.x * 128;
    float acc = 0.f, accc = 0.f;
    int gcur = -1;
    for (int i = 0; i < 64; i++) {
        int n = base + 2 * i + half;
        if (n >= N_NODES) break;
        int g = batch[n];
        if (g != gcur) {
            if (gcur >= 0) {
                atomicAdd(&sums[gcur * 128 + c], acc);
                if (c == 0) atomicAdd(&cnt[gcur], accc);
            }
            acc = 0.f; accc = 0.f; gcur = g;
        }
        size_t fidx = (size_t)(n >> 4) * 2048 + kt * 512 + ((n & 15) + 16 * qd) * 8 + j;
        acc += bf2f((uint_t)h[fidx]);
        accc += 1.f;
    }
    if (gcur >= 0) {
        atomicAdd(&sums[gcur * 128 + c], acc);
        if (c == 0) atomicAdd(&cnt[gcur], accc);
    }
}

// ---------- final fusion MLP ----------
__global__ void final_mlp(const float* __restrict__ sums, const float* __restrict__ cnt,
                          const float* __restrict__ doc,
                          const float* __restrict__ Wdoc, const float* __restrict__ bdoc,
                          const float* __restrict__ Wfus, const float* __restrict__ bfus,
                          const float* __restrict__ Wtask, const float* __restrict__ btask,
                          const float* __restrict__ Wtime, const float* __restrict__ btime,
                          float* __restrict__ out) {
    int b = blockIdx.x;
    int t = threadIdx.x;
    __shared__ float gbuf[128], dbuf[128], fbuf[128];
    float c = fmaxf(cnt[b], 1.0f);
    gbuf[t] = sums[b * 128 + t] / c;
    float acc = bdoc[t];
    for (int k = 0; k < 512; k++)
        acc += doc[b * 512 + k] * Wdoc[k * 128 + t];
    dbuf[t] = fmaxf(acc, 0.f);
    __syncthreads();
    float f = bfus[t];
    for (int k = 0; k < 128; k++) f += gbuf[k] * Wfus[k * 128 + t];
    for (int k = 0; k < 128; k++) f += dbuf[k] * Wfus[(128 + k) * 128 + t];
    fbuf[t] = fmaxf(f, 0.f);
    __syncthreads();
    if (t < 16) {
        float a = btask[t];
        for (int k = 0; k < 128; k++) a += fbuf[k] * Wtask[k * 16 + t];
        out[b * 16 + t] = a;
    } else if (t == 16) {
        float a = btime[0];
        for (int k = 0; k < 128; k++) a += fbuf[k] * Wtime[k];
        out[NGRAPH * 16 + b] = a;
    }
}

extern "C" void kernel_launch(void* const* d_in, const int* in_sizes, int n_in,
                              void* d_out, int out_size, void* d_ws, size_t ws_size,
                              hipStream_t stream) {
    (void)in_sizes; (void)n_in; (void)out_size; (void)ws_size;
    const float* x    = (const float*)d_in[0];
    const int*   ei   = (const int*)d_in[1];
    const int*   batch= (const int*)d_in[2];
    const float* ts   = (const float*)d_in[3];
    const float* doc  = (const float*)d_in[4];
    const float* Wq1  = (const float*)d_in[5];
    const float* bq1  = (const float*)d_in[6];
    const float* Wk1  = (const float*)d_in[7];
    const float* bk1  = (const float*)d_in[8];
    const float* Wv1  = (const float*)d_in[9];
    const float* bv1  = (const float*)d_in[10];
    const float* Ws1  = (const float*)d_in[11];
    const float* bs1  = (const float*)d_in[12];
    const float* Wq2  = (const float*)d_in[13];
    const float* bq2  = (const float*)d_in[14];
    const float* Wk2  = (const float*)d_in[15];
    const float* bk2  = (const float*)d_in[16];
    const float* Wv2  = (const float*)d_in[17];
    const float* bv2  = (const float*)d_in[18];
    const float* Ws2  = (const float*)d_in[19];
    const float* bs2  = (const float*)d_in[20];
    const float* bn1g = (const float*)d_in[21];
    const float* bn1b = (const float*)d_in[22];
    const float* bn1m = (const float*)d_in[23];
    const float* bn1v = (const float*)d_in[24];
    const float* bn2g = (const float*)d_in[25];
    const float* bn2b = (const float*)d_in[26];
    const float* bn2m = (const float*)d_in[27];
    const float* bn2v = (const float*)d_in[28];
    const float* Wdoc = (const float*)d_in[29];
    const float* bdoc = (const float*)d_in[30];
    const float* Wfus = (const float*)d_in[31];
    const float* bfus = (const float*)d_in[32];
    const float* Wtask= (const float*)d_in[33];
    const float* btask= (const float*)d_in[34];
    const float* Wtime= (const float*)d_in[35];
    const float* btime= (const float*)d_in[36];

    char* ws = (char*)d_ws;
    ushort_t* h      = (ushort_t*)(ws + 0);           // 12.8 MB
    ushort_t* qsb    = (ushort_t*)(ws + 12800000);    // 25.6 MB
    uchar_t*  kv8    = (uchar_t*)(ws + 38400000);     // 12.8 MB
    ushort_t* WF     = (ushort_t*)(ws + 51200000);    // 256 KB
    float*    biasc  = (float*)(ws + 51462144);       // 4 KB
    int*      deg    = (int*)(ws + 51466240);         // 200000 B
    ull_t*    sstate = (ull_t*)(ws + 51666240);       // 1568 B (8-aligned)
    float*    sums   = (float*)(ws + 51667808);       // 32768 B
    float*    cnt    = (float*)(ws + 51700576);       // 256 B
    int*      off    = (int*)(ws + 51700832);         // 200004 B
    int*      bucketcur = (int*)(ws + 51900836);      // 784 B
    int*      arena  = (int*)(ws + 51901620);         // 3.2 MB
    int*      csr    = (int*)(ws + 55101620);         // 3.2 MB

    float* out = (float*)d_out;

    // zero deg + scan state in one memset (graph-capturable)
    hipMemsetAsync(deg, 0, 200000 + 1568, stream);

    deg_kernel<<<3125, 256, 0, stream>>>(ei, deg);
    scan_kernel<<<NB_SCAN, 256, 0, stream>>>(deg, off, bucketcur, sums, cnt, sstate);
    prep_kernel<<<NBKT + NB_TEMP + NB_WS, 256, 0, stream>>>(
        ei, off, bucketcur, arena, x, ts, h,
        Wq1, Wk1, Wv1, Ws1, Wq2, Wk2, Wv2, Ws2,
        bq1, bk1, bv1, bs1, bq2, bk2, bv2, bs2, WF, biasc);

    const size_t WF_LAYER = 65536;  // shorts per layer

    // ---- layer 1 (gemm fused with passB) ----
    g1_kernel<<<NBKT + 4 * 391, 256, 0, stream>>>(off, arena, csr, h, WF, biasc,
                                                  qsb, kv8);
    node_attn_bn<<<12500, 256, 0, stream>>>(off, csr, qsb, kv8, bn1g, bn1b, bn1m, bn1v, h);

    // ---- layer 2 ----
    gemm_qkvs<<<dim3(391, 4), 256, 0, stream>>>(h, WF + WF_LAYER, biasc + 512, qsb, kv8);
    node_attn_bn<<<12500, 256, 0, stream>>>(off, csr, qsb, kv8, bn2g, bn2b, bn2m, bn2v, h);

    // ---- pool + fusion head ----
    pool_kernel<<<391, 256, 0, stream>>>(h, batch, sums, cnt);
    final_mlp<<<NGRAPH, 128, 0, stream>>>(sums, cnt, doc, Wdoc, bdoc, Wfus, bfus,
                                          Wtask, btask, Wtime, btime, out);
}

// Round 13
// 389.328 us; speedup vs baseline: 1.0237x; 1.0237x over previous
//
#include <hip/hip_runtime.h>

typedef unsigned short ushort_t;
typedef unsigned int uint_t;
typedef unsigned char uchar_t;
typedef unsigned long long ull_t;

#define N_NODES 50000
#define N_EDGES 800000
#define HID 128
#define NGRAPH 64
#define NB_SCAN 196   // ceil(50000/256) == coarse buckets
#define N_RT 3125     // row tiles of 16 nodes
#define NBKT 196
#define CHUNK 4096    // edges per pass-A block
#define NB_TEMP 12500 // temporal blocks (x512 elems)
#define NB_WS 512     // wsplit blocks
#define BCAP 6144     // passB LDS stage capacity

typedef __attribute__((ext_vector_type(8))) short short8;
typedef __attribute__((ext_vector_type(4))) float float4v;
typedef __attribute__((ext_vector_type(2))) float float2v;

// ---------- bf16 helpers ----------
__device__ __forceinline__ float bf2f(uint_t u) {
    union { uint_t i; float f; } v; v.i = u << 16; return v.f;
}
__device__ __forceinline__ ushort_t f2bf(float f) {
    union { float f; uint_t i; } v; v.f = f;
    uint_t r = v.i + 0x7FFFu + ((v.i >> 16) & 1u);
    return (ushort_t)(r >> 16);
}

// ---------- fp8 e4m3 helpers ----------
#if __has_builtin(__builtin_amdgcn_cvt_pk_fp8_f32) && __has_builtin(__builtin_amdgcn_cvt_pk_f32_fp8)
#define HAS_FP8_CVT 1
#else
#define HAS_FP8_CVT 0
#endif

__device__ __forceinline__ uchar_t f2fp8(float x) {
#if HAS_FP8_CVT
    int p = __builtin_amdgcn_cvt_pk_fp8_f32(x, x, 0, false);
    return (uchar_t)(p & 0xFF);
#else
    union { float f; uint_t u; } v; v.f = x;
    uint_t s = (v.u >> 31) << 7;
    float a = fabsf(x);
    a = fminf(a, 448.f);
    if (a < 0.015625f) {
        int m3 = (int)(a * 512.f + 0.5f);
        return (uchar_t)(s | (uint_t)m3);
    }
    v.f = a;
    uint_t r = v.u + 0x7FFFFu + ((v.u >> 20) & 1u);
    uint_t e = r >> 23;
    return (uchar_t)(s | ((e - 120u) << 3) | ((r >> 20) & 7u));
#endif
}

__device__ __forceinline__ float fp8dec1(uint_t b) {
    uint_t e = (b >> 3) & 15u, mnt = b & 7u;
    union { uint_t u; float f; } v;
    v.u = ((e + 120u) << 23) | (mnt << 20);
    float mag = e ? v.f : (float)mnt * 0.001953125f;  // 2^-9
    return (b & 0x80u) ? -mag : mag;
}

__device__ __forceinline__ void fp8x4_dec2(uint_t w, float2v* o) {
#if HAS_FP8_CVT
    o[0] = __builtin_amdgcn_cvt_pk_f32_fp8(w, false);
    o[1] = __builtin_amdgcn_cvt_pk_f32_fp8(w, true);
#else
    float2v a, b;
    a.x = fp8dec1(w & 0xFFu);  a.y = fp8dec1((w >> 8) & 0xFFu);
    b.x = fp8dec1((w >> 16) & 0xFFu); b.y = fp8dec1(w >> 24);
    o[0] = a; o[1] = b;
#endif
}

// ---------- CSR: degree histogram ----------
__global__ void deg_kernel(const int* __restrict__ ei, int* __restrict__ deg) {
    int e = blockIdx.x * blockDim.x + threadIdx.x;
    if (e < N_EDGES) atomicAdd(&deg[ei[N_EDGES + e]], 1);
}

// ---------- single-dispatch scan: decoupled lookback over 196 blocks --------
__global__ __launch_bounds__(256) void scan_kernel(
    const int* __restrict__ deg, int* __restrict__ off,
    int* __restrict__ bucketcur, float* __restrict__ sums,
    float* __restrict__ cnt, ull_t* __restrict__ sstate) {
    __shared__ int buf[256];
    __shared__ int pre_s;
    int b = blockIdx.x, t = threadIdx.x;
    int n = b * 256 + t;
    int v = (n < N_NODES) ? deg[n] : 0;
    buf[t] = v;
    __syncthreads();
    #pragma unroll
    for (int s = 1; s < 256; s <<= 1) {
        int add = (t >= s) ? buf[t - s] : 0;
        __syncthreads();
        buf[t] += add;
        __syncthreads();
    }
    int incl = buf[t];
    int total = buf[255];
    if (t == 0) {
        if (b == 0) {
            atomicExch(&sstate[0], (2ULL << 32) | (uint_t)total);
            pre_s = 0;
        } else {
            atomicExch(&sstate[b], (1ULL << 32) | (uint_t)total);
            int run = 0, i = b - 1;
            while (true) {
                ull_t w;
                do { w = atomicAdd(&sstate[i], 0ULL); } while ((w >> 32) == 0);
                run += (int)(uint_t)w;
                if ((w >> 32) == 2ULL) break;
                i--;
            }
            pre_s = run;
            atomicExch(&sstate[b], (2ULL << 32) | (uint_t)(run + total));
        }
    }
    __syncthreads();
    int pre = pre_s;
    if (n < N_NODES) off[n] = pre + incl - v;
    if (t == 0) bucketcur[b] = pre;
    if (b == NB_SCAN - 1 && t == 0) off[N_NODES] = pre + total;
    if (b < 32) sums[b * 256 + t] = 0.f;
    if (b == 32 && t < NGRAPH) cnt[t] = 0.f;
}

// ---------- prep mega-kernel: passA bucket-scatter + temporal + wsplit ------
__global__ __launch_bounds__(256) void prep_kernel(
    const int* __restrict__ ei, const int* __restrict__ off,
    int* __restrict__ bucketcur, int* __restrict__ arena,
    const float* __restrict__ x, const float* __restrict__ ts,
    ushort_t* __restrict__ h,
    const float* __restrict__ Wq1, const float* __restrict__ Wk1,
    const float* __restrict__ Wv1, const float* __restrict__ Ws1,
    const float* __restrict__ Wq2, const float* __restrict__ Wk2,
    const float* __restrict__ Wv2, const float* __restrict__ Ws2,
    const float* __restrict__ bq1, const float* __restrict__ bk1,
    const float* __restrict__ bv1, const float* __restrict__ bs1,
    const float* __restrict__ bq2, const float* __restrict__ bk2,
    const float* __restrict__ bv2, const float* __restrict__ bs2,
    ushort_t* __restrict__ WF, float* __restrict__ bias_cat) {
    __shared__ int hist[NBKT];
    __shared__ int lofs[NBKT];
    __shared__ int lcur[NBKT];
    __shared__ int gbase[NBKT];
    __shared__ int sbuf[256];
    __shared__ uint_t staging[CHUNK];
    __shared__ int tot_s;

    int blk = blockIdx.x;
    int t = threadIdx.x;

    if (blk < NBKT) {
        if (t < NBKT) hist[t] = 0;
        __syncthreads();
        int e0 = blk * CHUNK;
        int srcs[16], dsts[16];
        #pragma unroll
        for (int i = 0; i < 16; i++) {
            int idx = e0 + i * 256 + t;
            bool v = idx < N_EDGES;
            srcs[i] = v ? ei[idx] : -1;
            dsts[i] = v ? ei[N_EDGES + idx] : -1;
            if (v) atomicAdd(&hist[dsts[i] >> 8], 1);
        }
        __syncthreads();
        int hv = (t < NBKT) ? hist[t] : 0;
        sbuf[t] = hv;
        __syncthreads();
        #pragma unroll
        for (int s = 1; s < 256; s <<= 1) {
            int add = (t >= s) ? sbuf[t - s] : 0;
            __syncthreads();
            sbuf[t] += add;
            __syncthreads();
        }
        if (t < NBKT) {
            lofs[t] = sbuf[t] - hv;
            lcur[t] = sbuf[t] - hv;
        }
        if (t == NBKT - 1) tot_s = sbuf[NBKT - 1];
        __syncthreads();
        #pragma unroll
        for (int i = 0; i < 16; i++) {
            if (srcs[i] >= 0) {
                int bkt = dsts[i] >> 8;
                int pos = atomicAdd(&lcur[bkt], 1);
                staging[pos] = ((uint_t)bkt << 24) | ((uint_t)(dsts[i] & 255) << 16)
                             | (uint_t)srcs[i];
            }
        }
        __syncthreads();
        if (t < NBKT) {
            int hcnt = hist[t];
            gbase[t] = hcnt ? atomicAdd(&bucketcur[t], hcnt) : 0;
        }
        __syncthreads();
        int tot = tot_s;
        for (int i = t; i < tot; i += 256) {
            uint_t e = staging[i];
            int bkt = e >> 24;
            arena[gbase[bkt] + (i - lofs[bkt])] = (int)(e & 0xFFFFFF);
        }
    } else if (blk < NBKT + NB_TEMP) {
        int base = (blk - NBKT) * 512;
        #pragma unroll
        for (int u = 0; u < 2; u++) {
            int tid = base + u * 256 + t;
            int rt   = tid >> 11;
            int kt   = (tid >> 9) & 3;
            int lane = (tid >> 3) & 63;
            int j    = tid & 7;
            int n = rt * 16 + (lane & 15);
            int c = kt * 32 + (lane >> 4) * 8 + j;
            float tv = ts[n];
            const float coef = -0.07195570687f;  // -ln(10000)/128
            float ang = tv * __expf((float)(c & ~1) * coef);
            float pe = (c & 1) ? __cosf(ang) : __sinf(ang);
            h[tid] = f2bf(x[n * 128 + c] + pe);
        }
    } else {
        int tid = (blk - NBKT - NB_TEMP) * 256 + t;  // 0..131071
        int j    = tid & 7;
        int lane = (tid >> 3) & 63;
        int kt   = (tid >> 9) & 3;
        int cgy  = (tid >> 11) & 31;
        int L    = tid >> 16;
        int col = cgy * 16 + (lane & 15);
        int k   = kt * 32 + (lane >> 4) * 8 + j;
        int mat = col >> 7, c = col & 127;
        const float* W = (L == 0)
            ? ((mat == 0) ? Wq1 : (mat == 1) ? Wk1 : (mat == 2) ? Wv1 : Ws1)
            : ((mat == 0) ? Wq2 : (mat == 1) ? Wk2 : (mat == 2) ? Wv2 : Ws2);
        size_t base = (size_t)L * 65536 + (size_t)cgy * 2048 + (size_t)kt * 512;
        WF[base + lane * 8 + j] = f2bf(W[k * 128 + c]);
        if (kt == 0 && (lane >> 4) == 0 && j == 0) {
            const float* b = (L == 0)
                ? ((mat == 0) ? bq1 : (mat == 1) ? bk1 : (mat == 2) ? bv1 : bs1)
                : ((mat == 0) ? bq2 : (mat == 1) ? bk2 : (mat == 2) ? bv2 : bs2);
            bias_cat[L * 512 + col] = b[c];
        }
    }
}

// ---------- shared gemm body ----------
__device__ __forceinline__ void gemm_body(
    int rp, int cg0, int lane, int quad, int m,
    const ushort_t* __restrict__ hf, const ushort_t* __restrict__ WF,
    const float* __restrict__ bias_cat,
    ushort_t* __restrict__ qsb, uchar_t* __restrict__ kv8) {
    int rt0 = rp * 2;
    if (rt0 >= N_RT) return;
    int rt1 = rt0 + 1;
    int rt1c = (rt1 < N_RT) ? rt1 : rt0;

    short8 a0[4], a1[4];
    {
        const ushort_t* b0 = hf + (size_t)rt0 * 2048 + lane * 8;
        const ushort_t* b1 = hf + (size_t)rt1c * 2048 + lane * 8;
        #pragma unroll
        for (int kt = 0; kt < 4; kt++) {
            a0[kt] = *reinterpret_cast<const short8*>(b0 + kt * 512);
            a1[kt] = *reinterpret_cast<const short8*>(b1 + kt * 512);
        }
    }

    const ushort_t* wfl = WF + (size_t)cg0 * 2048 + lane * 8;
    #pragma unroll 2
    for (int cg = 0; cg < 8; cg++) {
        const ushort_t* fp = wfl + (size_t)cg * 2048;
        float4v acc0 = {0.f, 0.f, 0.f, 0.f};
        float4v acc1 = {0.f, 0.f, 0.f, 0.f};
        #pragma unroll
        for (int kt = 0; kt < 4; kt++) {
            short8 bh = *reinterpret_cast<const short8*>(fp + kt * 512);
            acc0 = __builtin_amdgcn_mfma_f32_16x16x32_bf16(a0[kt], bh, acc0, 0, 0, 0);
            acc1 = __builtin_amdgcn_mfma_f32_16x16x32_bf16(a1[kt], bh, acc1, 0, 0, 0);
        }
        int col = (cg0 + cg) * 16 + m;
        float bias = bias_cat[col];
        int mat = col >> 7;
        #pragma unroll
        for (int r = 0; r < 4; r++) {
            float v0 = acc0[r] + bias;
            size_t row0 = (size_t)rt0 * 16 + quad * 4 + r;
            if (mat == 0)      qsb[row0 * 256 + col] = f2bf(v0);
            else if (mat == 3) qsb[row0 * 256 + (col - 256)] = f2bf(v0);
            else               kv8[row0 * 256 + (col - 128)] = f2fp8(v0);
        }
        if (rt1 < N_RT) {
            #pragma unroll
            for (int r = 0; r < 4; r++) {
                float v1 = acc1[r] + bias;
                size_t row1 = (size_t)rt1 * 16 + quad * 4 + r;
                if (mat == 0)      qsb[row1 * 256 + col] = f2bf(v1);
                else if (mat == 3) qsb[row1 * 256 + (col - 256)] = f2bf(v1);
                else               kv8[row1 * 256 + (col - 128)] = f2fp8(v1);
            }
        }
    }
}

// ---------- fused: passB (blocks 0..195) + gemm L1 (blocks 196..1759) -------
__global__ __launch_bounds__(256) void g1_kernel(
    const int* __restrict__ off, const int* __restrict__ arena,
    int* __restrict__ csr,
    const ushort_t* __restrict__ hf, const ushort_t* __restrict__ WF,
    const float* __restrict__ bias_cat,
    ushort_t* __restrict__ qsb, uchar_t* __restrict__ kv8) {
    __shared__ uint_t smem[BCAP + 257 + 256];
    int blk = blockIdx.x;
    int t = threadIdx.x;
    if (blk < NBKT) {
        uint_t* stage = smem;
        int* offL = (int*)(smem + BCAP);
        int* lcur = (int*)(smem + BCAP + 257);
        int n0 = blk * 256;
        int nEnd = (n0 + 256 < N_NODES) ? n0 + 256 : N_NODES;
        int base = off[n0];
        int end = off[nEnd];
        int size = end - base;
        if (n0 + t < nEnd) offL[t] = off[n0 + t] - base;
        lcur[t] = 0;
        __syncthreads();
        int lim = (size < BCAP) ? size : BCAP;
        for (int i = t; i < lim; i += 256) stage[i] = (uint_t)arena[base + i];
        __syncthreads();
        for (int i = t; i < size; i += 256) {
            uint_t e = (i < BCAP) ? stage[i] : (uint_t)arena[base + i];
            int dlow = (e >> 16) & 255;
            int src = (int)(e & 0xFFFF);
            int pos = offL[dlow] + atomicAdd(&lcur[dlow], 1);
            csr[base + pos] = src;
        }
    } else {
        int blk2 = blk - NBKT;           // 0..1563
        int y = blk2 / 391, bx = blk2 % 391;
        int wave = t >> 6, lane = t & 63;
        gemm_body(bx * 4 + wave, y * 8, lane, lane >> 4, lane & 15,
                  hf, WF, bias_cat, qsb, kv8);
    }
}

// ---------- plain gemm (layer 2) ----------
__global__ __launch_bounds__(256) void gemm_qkvs(
    const ushort_t* __restrict__ hf,
    const ushort_t* __restrict__ WF,
    const float* __restrict__ bias_cat,
    ushort_t* __restrict__ qsb, uchar_t* __restrict__ kv8) {
    int t = threadIdx.x;
    int wave = t >> 6, lane = t & 63;
    gemm_body(blockIdx.x * 4 + wave, blockIdx.y * 8, lane, lane >> 4, lane & 15,
              hf, WF, bias_cat, qsb, kv8);
}

// ---------- fused per-node attention + skip + BN + relu -> h (frag-major) ----
// One wave per node; quarter-wave per edge; 2x-unrolled edge loop -> two
// independent decode->dot->shfl->exp chains in flight (8 edges/wave-iter).
__global__ __launch_bounds__(256) void node_attn_bn(
    const int* __restrict__ off, const int* __restrict__ csr_src,
    const ushort_t* __restrict__ qsb, const uchar_t* __restrict__ kv8,
    const float* __restrict__ bng, const float* __restrict__ bnb,
    const float* __restrict__ bnm, const float* __restrict__ bnv,
    ushort_t* __restrict__ h) {
    int wave = threadIdx.x >> 6;
    int n = blockIdx.x * 4 + wave;
    if (n >= N_NODES) return;
    int lane = threadIdx.x & 63;
    int qtr = lane >> 4, s16 = lane & 15;
    int c0 = s16 * 8;

    const ushort_t* row_qs = qsb + (size_t)n * 256;
    float2v q2[4];
    {
        uint4 qu = *reinterpret_cast<const uint4*>(row_qs + c0);
        q2[0].x = bf2f(qu.x & 0xffff) * 0.125f; q2[0].y = bf2f(qu.x >> 16) * 0.125f;
        q2[1].x = bf2f(qu.y & 0xffff) * 0.125f; q2[1].y = bf2f(qu.y >> 16) * 0.125f;
        q2[2].x = bf2f(qu.z & 0xffff) * 0.125f; q2[2].y = bf2f(qu.z >> 16) * 0.125f;
        q2[3].x = bf2f(qu.w & 0xffff) * 0.125f; q2[3].y = bf2f(qu.w >> 16) * 0.125f;
    }

    int e0 = off[n], e1 = off[n + 1];
    float l = 0.f;
    float2v o2[4];
    o2[0] = (float2v){0.f, 0.f}; o2[1] = (float2v){0.f, 0.f};
    o2[2] = (float2v){0.f, 0.f}; o2[3] = (float2v){0.f, 0.f};

    int src_a = (e0 + qtr < e1) ? csr_src[e0 + qtr] : 0;
    int src_b = (e0 + 4 + qtr < e1) ? csr_src[e0 + 4 + qtr] : 0;
    for (int p = e0; p < e1; p += 8) {
        int ia = p + qtr, ib = p + 4 + qtr;
        bool va = ia < e1, vb = ib < e1;
        int sa = src_a, sb = src_b;
        int na = p + 8 + qtr, nb = p + 12 + qtr;
        if (na < e1) src_a = csr_src[na];
        if (nb < e1) src_b = csr_src[nb];
        const uchar_t* kpa = kv8 + (size_t)sa * 256;
        const uchar_t* kpb = kv8 + (size_t)sb * 256;
        uint2 kua = *reinterpret_cast<const uint2*>(kpa + c0);
        uint2 vua = *reinterpret_cast<const uint2*>(kpa + 128 + c0);
        uint2 kub = *reinterpret_cast<const uint2*>(kpb + c0);
        uint2 vub = *reinterpret_cast<const uint2*>(kpb + 128 + c0);
        float2v ka2[4], wa2[4], kb2[4], wb2[4];
        fp8x4_dec2(kua.x, ka2);  fp8x4_dec2(kua.y, ka2 + 2);
        fp8x4_dec2(kub.x, kb2);  fp8x4_dec2(kub.y, kb2 + 2);
        fp8x4_dec2(vua.x, wa2);  fp8x4_dec2(vua.y, wa2 + 2);
        fp8x4_dec2(vub.x, wb2);  fp8x4_dec2(vub.y, wb2 + 2);
        float2v da2 = q2[0] * ka2[0];
        float2v db2 = q2[0] * kb2[0];
        da2 += q2[1] * ka2[1];  db2 += q2[1] * kb2[1];
        da2 += q2[2] * ka2[2];  db2 += q2[2] * kb2[2];
        da2 += q2[3] * ka2[3];  db2 += q2[3] * kb2[3];
        float da = da2.x + da2.y;
        float db = db2.x + db2.y;
        da += __shfl_xor(da, 1);  db += __shfl_xor(db, 1);
        da += __shfl_xor(da, 2);  db += __shfl_xor(db, 2);
        da += __shfl_xor(da, 4);  db += __shfl_xor(db, 4);
        float pea = va ? __expf(da) : 0.f;
        float peb = vb ? __expf(db) : 0.f;
        l += pea + peb;
        float2v pa; pa.x = pea; pa.y = pea;
        float2v pb; pb.x = peb; pb.y = peb;
        #pragma unroll
        for (int i = 0; i < 4; i++) {
            o2[i] += pa * wa2[i];
            o2[i] += pb * wb2[i];
        }
    }
    #pragma unroll
    for (int offx = 16; offx <= 32; offx <<= 1) {
        l += __shfl_xor(l, offx);
        #pragma unroll
        for (int i = 0; i < 4; i++) {
            o2[i].x += __shfl_xor(o2[i].x, offx);
            o2[i].y += __shfl_xor(o2[i].y, offx);
        }
    }

    if (qtr == 0) {
        float inv = 1.f / (l + 1e-16f);
        float o[8] = {o2[0].x, o2[0].y, o2[1].x, o2[1].y,
                      o2[2].x, o2[2].y, o2[3].x, o2[3].y};
        float sv[8];
        {
            uint4 su = *reinterpret_cast<const uint4*>(row_qs + 128 + c0);
            sv[0] = bf2f(su.x & 0xffff); sv[1] = bf2f(su.x >> 16);
            sv[2] = bf2f(su.y & 0xffff); sv[3] = bf2f(su.y >> 16);
            sv[4] = bf2f(su.z & 0xffff); sv[5] = bf2f(su.z >> 16);
            sv[6] = bf2f(su.w & 0xffff); sv[7] = bf2f(su.w >> 16);
        }
        float gv[8], bv[8], mv[8], vr[8];
        *reinterpret_cast<float4*>(gv)     = *reinterpret_cast<const float4*>(bng + c0);
        *reinterpret_cast<float4*>(gv + 4) = *reinterpret_cast<const float4*>(bng + c0 + 4);
        *reinterpret_cast<float4*>(bv)     = *reinterpret_cast<const float4*>(bnb + c0);
        *reinterpret_cast<float4*>(bv + 4) = *reinterpret_cast<const float4*>(bnb + c0 + 4);
        *reinterpret_cast<float4*>(mv)     = *reinterpret_cast<const float4*>(bnm + c0);
        *reinterpret_cast<float4*>(mv + 4) = *reinterpret_cast<const float4*>(bnm + c0 + 4);
        *reinterpret_cast<float4*>(vr)     = *reinterpret_cast<const float4*>(bnv + c0);
        *reinterpret_cast<float4*>(vr + 4) = *reinterpret_cast<const float4*>(bnv + c0 + 4);
        uint_t hw[4];
        #pragma unroll
        for (int i = 0; i < 8; i++) {
            float val = fmaxf(o[i] * inv + sv[i], 0.f);
            val = (val - mv[i]) * rsqrtf(vr[i] + 1e-5f) * gv[i] + bv[i];
            val = fmaxf(val, 0.f);
            ushort_t hb = f2bf(val);
            if (i & 1) hw[i >> 1] |= (uint_t)hb << 16;
            else       hw[i >> 1] = hb;
        }
        int rt = n >> 4, mnode = n & 15;
        int kt = s16 >> 2, qd = s16 & 3;
        size_t fidx = (size_t)rt * 2048 + kt * 512 + (mnode + 16 * qd) * 8;
        uint4 hp; hp.x = hw[0]; hp.y = hw[1]; hp.z = hw[2]; hp.w = hw[3];
        *reinterpret_cast<uint4*>(h + fidx) = hp;
    }
}

// ---------- global mean pool ----------
__global__ void pool_kernel(const ushort_t* __restrict__ h,
                            const int* __restrict__ batch,
                            float* __restrict__ sums,
                            float* __restrict__ cnt) {
    int t = threadIdx.x;
    int c = t & 127, half = t >> 7;
    int kt = c >> 5, qd = (c >> 3) & 3, j = c & 7;
    int base = blockIdx.x * 128;
    float acc = 0.f, accc = 0.f;
    int gcur = -1;
    for (int i = 0; i < 64; i++) {
        int n = base + 2 * i + half;
        if (n >= N_NODES) break;
        int g = batch[n];
        if (g != gcur) {
            if (gcur >= 0) {
                atomicAdd(&sums[gcur * 128 + c], acc);
                if (c == 0) atomicAdd(&cnt[gcur], accc);
            }
            acc = 0.f; accc = 0.f; gcur = g;
        }
        size_t fidx = (size_t)(n >> 4) * 2048 + kt * 512 + ((n & 15) + 16 * qd) * 8 + j;
        acc += bf2f((uint_t)h[fidx]);
        accc += 1.f;
    }
    if (gcur >= 0) {
        atomicAdd(&sums[gcur * 128 + c], acc);
        if (c == 0) atomicAdd(&cnt[gcur], accc);
    }
}

// ---------- final fusion MLP ----------
__global__ void final_mlp(const float* __restrict__ sums, const float* __restrict__ cnt,
                          const float* __restrict__ doc,
                          const float* __restrict__ Wdoc, const float* __restrict__ bdoc,
                          const float* __restrict__ Wfus, const float* __restrict__ bfus,
                          const float* __restrict__ Wtask, const float* __restrict__ btask,
                          const float* __restrict__ Wtime, const float* __restrict__ btime,
                          float* __restrict__ out) {
    int b = blockIdx.x;
    int t = threadIdx.x;
    __shared__ float gbuf[128], dbuf[128], fbuf[128];
    float c = fmaxf(cnt[b], 1.0f);
    gbuf[t] = sums[b * 128 + t] / c;
    float acc = bdoc[t];
    for (int k = 0; k < 512; k++)
        acc += doc[b * 512 + k] * Wdoc[k * 128 + t];
    dbuf[t] = fmaxf(acc, 0.f);
    __syncthreads();
    float f = bfus[t];
    for (int k = 0; k < 128; k++) f += gbuf[k] * Wfus[k * 128 + t];
    for (int k = 0; k < 128; k++) f += dbuf[k] * Wfus[(128 + k) * 128 + t];
    fbuf[t] = fmaxf(f, 0.f);
    __syncthreads();
    if (t < 16) {
        float a = btask[t];
        for (int k = 0; k < 128; k++) a += fbuf[k] * Wtask[k * 16 + t];
        out[b * 16 + t] = a;
    } else if (t == 16) {
        float a = btime[0];
        for (int k = 0; k < 128; k++) a += fbuf[k] * Wtime[k];
        out[NGRAPH * 16 + b] = a;
    }
}

extern "C" void kernel_launch(void* const* d_in, const int* in_sizes, int n_in,
                              void* d_out, int out_size, void* d_ws, size_t ws_size,
                              hipStream_t stream) {
    (void)in_sizes; (void)n_in; (void)out_size; (void)ws_size;
    const float* x    = (const float*)d_in[0];
    const int*   ei   = (const int*)d_in[1];
    const int*   batch= (const int*)d_in[2];
    const float* ts   = (const float*)d_in[3];
    const float* doc  = (const float*)d_in[4];
    const float* Wq1  = (const float*)d_in[5];
    const float* bq1  = (const float*)d_in[6];
    const float* Wk1  = (const float*)d_in[7];
    const float* bk1  = (const float*)d_in[8];
    const float* Wv1  = (const float*)d_in[9];
    const float* bv1  = (const float*)d_in[10];
    const float* Ws1  = (const float*)d_in[11];
    const float* bs1  = (const float*)d_in[12];
    const float* Wq2  = (const float*)d_in[13];
    const float* bq2  = (const float*)d_in[14];
    const float* Wk2  = (const float*)d_in[15];
    const float* bk2  = (const float*)d_in[16];
    const float* Wv2  = (const float*)d_in[17];
    const float* bv2  = (const float*)d_in[18];
    const float* Ws2  = (const float*)d_in[19];
    const float* bs2  = (const float*)d_in[20];
    const float* bn1g = (const float*)d_in[21];
    const float* bn1b = (const float*)d_in[22];
    const float* bn1m = (const float*)d_in[23];
    const float* bn1v = (const float*)d_in[24];
    const float* bn2g = (const float*)d_in[25];
    const float* bn2b = (const float*)d_in[26];
    const float* bn2m = (const float*)d_in[27];
    const float* bn2v = (const float*)d_in[28];
    const float* Wdoc = (const float*)d_in[29];
    const float* bdoc = (const float*)d_in[30];
    const float* Wfus = (const float*)d_in[31];
    const float* bfus = (const float*)d_in[32];
    const float* Wtask= (const float*)d_in[33];
    const float* btask= (const float*)d_in[34];
    const float* Wtime= (const float*)d_in[35];
    const float* btime= (const float*)d_in[36];

    char* ws = (char*)d_ws;
    ushort_t* h      = (ushort_t*)(ws + 0);           // 12.8 MB
    ushort_t* qsb    = (ushort_t*)(ws + 12800000);    // 25.6 MB
    uchar_t*  kv8    = (uchar_t*)(ws + 38400000);     // 12.8 MB
    ushort_t* WF     = (ushort_t*)(ws + 51200000);    // 256 KB
    float*    biasc  = (float*)(ws + 51462144);       // 4 KB
    int*      deg    = (int*)(ws + 51466240);         // 200000 B
    ull_t*    sstate = (ull_t*)(ws + 51666240);       // 1568 B
    float*    sums   = (float*)(ws + 51667808);       // 32768 B
    float*    cnt    = (float*)(ws + 51700576);       // 256 B
    int*      off    = (int*)(ws + 51700832);         // 200004 B
    int*      bucketcur = (int*)(ws + 51900836);      // 784 B
    int*      arena  = (int*)(ws + 51901620);         // 3.2 MB
    int*      csr    = (int*)(ws + 55101620);         // 3.2 MB

    float* out = (float*)d_out;

    hipMemsetAsync(deg, 0, 200000 + 1568, stream);

    deg_kernel<<<3125, 256, 0, stream>>>(ei, deg);
    scan_kernel<<<NB_SCAN, 256, 0, stream>>>(deg, off, bucketcur, sums, cnt, sstate);
    prep_kernel<<<NBKT + NB_TEMP + NB_WS, 256, 0, stream>>>(
        ei, off, bucketcur, arena, x, ts, h,
        Wq1, Wk1, Wv1, Ws1, Wq2, Wk2, Wv2, Ws2,
        bq1, bk1, bv1, bs1, bq2, bk2, bv2, bs2, WF, biasc);

    const size_t WF_LAYER = 65536;  // shorts per layer

    // ---- layer 1 (gemm fused with passB) ----
    g1_kernel<<<NBKT + 4 * 391, 256, 0, stream>>>(off, arena, csr, h, WF, biasc,
                                                  qsb, kv8);
    node_attn_bn<<<12500, 256, 0, stream>>>(off, csr, qsb, kv8, bn1g, bn1b, bn1m, bn1v, h);

    // ---- layer 2 ----
    gemm_qkvs<<<dim3(391, 4), 256, 0, stream>>>(h, WF + WF_LAYER, biasc + 512, qsb, kv8);
    node_attn_bn<<<12500, 256, 0, stream>>>(off, csr, qsb, kv8, bn2g, bn2b, bn2m, bn2v, h);

    // ---- pool + fusion head ----
    pool_kernel<<<391, 256, 0, stream>>>(h, batch, sums, cnt);
    final_mlp<<<NGRAPH, 128, 0, stream>>>(sums, cnt, doc, Wdoc, bdoc, Wfus, bfus,
                                          Wtask, btask, Wtime, btime, out);
}

// Round 14
// 381.677 us; speedup vs baseline: 1.0443x; 1.0200x over previous
//
#include <hip/hip_runtime.h>

typedef unsigned short ushort_t;
typedef unsigned int uint_t;
typedef unsigned char uchar_t;
typedef unsigned long long ull_t;

#define N_NODES 50000
#define N_EDGES 800000
#define HID 128
#define NGRAPH 64
#define NB_SCAN 196   // ceil(50000/256) == coarse buckets
#define N_RT 3125     // row tiles of 16 nodes
#define NBKT 196
#define CHUNK 4096    // edges per pass-A block
#define NB_TEMP 12500 // temporal blocks (x512 elems)
#define NB_WS 512     // wsplit blocks
#define NB_GEMM 1564  // 4*391
#define BCAP 6144     // passB LDS stage capacity

typedef __attribute__((ext_vector_type(8))) short short8;
typedef __attribute__((ext_vector_type(4))) float float4v;
typedef __attribute__((ext_vector_type(2))) float float2v;

// ---------- bf16 helpers ----------
__device__ __forceinline__ float bf2f(uint_t u) {
    union { uint_t i; float f; } v; v.i = u << 16; return v.f;
}
__device__ __forceinline__ ushort_t f2bf(float f) {
    union { float f; uint_t i; } v; v.f = f;
    uint_t r = v.i + 0x7FFFu + ((v.i >> 16) & 1u);
    return (ushort_t)(r >> 16);
}

// ---------- fp8 e4m3 helpers ----------
#if __has_builtin(__builtin_amdgcn_cvt_pk_fp8_f32) && __has_builtin(__builtin_amdgcn_cvt_pk_f32_fp8)
#define HAS_FP8_CVT 1
#else
#define HAS_FP8_CVT 0
#endif

__device__ __forceinline__ uchar_t f2fp8(float x) {
#if HAS_FP8_CVT
    int p = __builtin_amdgcn_cvt_pk_fp8_f32(x, x, 0, false);
    return (uchar_t)(p & 0xFF);
#else
    union { float f; uint_t u; } v; v.f = x;
    uint_t s = (v.u >> 31) << 7;
    float a = fabsf(x);
    a = fminf(a, 448.f);
    if (a < 0.015625f) {
        int m3 = (int)(a * 512.f + 0.5f);
        return (uchar_t)(s | (uint_t)m3);
    }
    v.f = a;
    uint_t r = v.u + 0x7FFFFu + ((v.u >> 20) & 1u);
    uint_t e = r >> 23;
    return (uchar_t)(s | ((e - 120u) << 3) | ((r >> 20) & 7u));
#endif
}

__device__ __forceinline__ float fp8dec1(uint_t b) {
    uint_t e = (b >> 3) & 15u, mnt = b & 7u;
    union { uint_t u; float f; } v;
    v.u = ((e + 120u) << 23) | (mnt << 20);
    float mag = e ? v.f : (float)mnt * 0.001953125f;  // 2^-9
    return (b & 0x80u) ? -mag : mag;
}

__device__ __forceinline__ void fp8x4_dec2(uint_t w, float2v* o) {
#if HAS_FP8_CVT
    o[0] = __builtin_amdgcn_cvt_pk_f32_fp8(w, false);
    o[1] = __builtin_amdgcn_cvt_pk_f32_fp8(w, true);
#else
    float2v a, b;
    a.x = fp8dec1(w & 0xFFu);  a.y = fp8dec1((w >> 8) & 0xFFu);
    b.x = fp8dec1((w >> 16) & 0xFFu); b.y = fp8dec1(w >> 24);
    o[0] = a; o[1] = b;
#endif
}

// ---------- CSR: degree histogram ----------
__global__ void deg_kernel(const int* __restrict__ ei, int* __restrict__ deg) {
    int e = blockIdx.x * blockDim.x + threadIdx.x;
    if (e < N_EDGES) atomicAdd(&deg[ei[N_EDGES + e]], 1);
}

// ---------- single-dispatch scan: decoupled lookback over 196 blocks --------
__global__ __launch_bounds__(256) void scan_kernel(
    const int* __restrict__ deg, int* __restrict__ off,
    int* __restrict__ bucketcur, float* __restrict__ sums,
    float* __restrict__ cnt, ull_t* __restrict__ sstate) {
    __shared__ int buf[256];
    __shared__ int pre_s;
    int b = blockIdx.x, t = threadIdx.x;
    int n = b * 256 + t;
    int v = (n < N_NODES) ? deg[n] : 0;
    buf[t] = v;
    __syncthreads();
    #pragma unroll
    for (int s = 1; s < 256; s <<= 1) {
        int add = (t >= s) ? buf[t - s] : 0;
        __syncthreads();
        buf[t] += add;
        __syncthreads();
    }
    int incl = buf[t];
    int total = buf[255];
    if (t == 0) {
        if (b == 0) {
            atomicExch(&sstate[0], (2ULL << 32) | (uint_t)total);
            pre_s = 0;
        } else {
            atomicExch(&sstate[b], (1ULL << 32) | (uint_t)total);
            int run = 0, i = b - 1;
            while (true) {
                ull_t w;
                do { w = atomicAdd(&sstate[i], 0ULL); } while ((w >> 32) == 0);
                run += (int)(uint_t)w;
                if ((w >> 32) == 2ULL) break;
                i--;
            }
            pre_s = run;
            atomicExch(&sstate[b], (2ULL << 32) | (uint_t)(run + total));
        }
    }
    __syncthreads();
    int pre = pre_s;
    if (n < N_NODES) off[n] = pre + incl - v;
    if (t == 0) bucketcur[b] = pre;
    if (b == NB_SCAN - 1 && t == 0) off[N_NODES] = pre + total;
    if (b < 32) sums[b * 256 + t] = 0.f;
    if (b == 32 && t < NGRAPH) cnt[t] = 0.f;
}

// ---------- prep mega-kernel: passA + temporal + wsplit + docemb ------------
__global__ __launch_bounds__(256) void prep_kernel(
    const int* __restrict__ ei, const int* __restrict__ off,
    int* __restrict__ bucketcur, int* __restrict__ arena,
    const float* __restrict__ x, const float* __restrict__ ts,
    ushort_t* __restrict__ h,
    const float* __restrict__ Wq1, const float* __restrict__ Wk1,
    const float* __restrict__ Wv1, const float* __restrict__ Ws1,
    const float* __restrict__ Wq2, const float* __restrict__ Wk2,
    const float* __restrict__ Wv2, const float* __restrict__ Ws2,
    const float* __restrict__ bq1, const float* __restrict__ bk1,
    const float* __restrict__ bv1, const float* __restrict__ bs1,
    const float* __restrict__ bq2, const float* __restrict__ bk2,
    const float* __restrict__ bv2, const float* __restrict__ bs2,
    ushort_t* __restrict__ WF, float* __restrict__ bias_cat,
    const float* __restrict__ doc, const float* __restrict__ Wdoc,
    const float* __restrict__ bdoc, float* __restrict__ docemb) {
    __shared__ int hist[NBKT];
    __shared__ int lofs[NBKT];
    __shared__ int lcur[NBKT];
    __shared__ int gbase[NBKT];
    __shared__ int sbuf[256];
    __shared__ uint_t staging[CHUNK];
    __shared__ int tot_s;

    int blk = blockIdx.x;
    int t = threadIdx.x;

    if (blk < NBKT) {
        // ---------------- pass A ----------------
        if (t < NBKT) hist[t] = 0;
        __syncthreads();
        int e0 = blk * CHUNK;
        int srcs[16], dsts[16];
        #pragma unroll
        for (int i = 0; i < 16; i++) {
            int idx = e0 + i * 256 + t;
            bool v = idx < N_EDGES;
            srcs[i] = v ? ei[idx] : -1;
            dsts[i] = v ? ei[N_EDGES + idx] : -1;
            if (v) atomicAdd(&hist[dsts[i] >> 8], 1);
        }
        __syncthreads();
        int hv = (t < NBKT) ? hist[t] : 0;
        sbuf[t] = hv;
        __syncthreads();
        #pragma unroll
        for (int s = 1; s < 256; s <<= 1) {
            int add = (t >= s) ? sbuf[t - s] : 0;
            __syncthreads();
            sbuf[t] += add;
            __syncthreads();
        }
        if (t < NBKT) {
            lofs[t] = sbuf[t] - hv;
            lcur[t] = sbuf[t] - hv;
        }
        if (t == NBKT - 1) tot_s = sbuf[NBKT - 1];
        __syncthreads();
        #pragma unroll
        for (int i = 0; i < 16; i++) {
            if (srcs[i] >= 0) {
                int bkt = dsts[i] >> 8;
                int pos = atomicAdd(&lcur[bkt], 1);
                staging[pos] = ((uint_t)bkt << 24) | ((uint_t)(dsts[i] & 255) << 16)
                             | (uint_t)srcs[i];
            }
        }
        __syncthreads();
        if (t < NBKT) {
            int hcnt = hist[t];
            gbase[t] = hcnt ? atomicAdd(&bucketcur[t], hcnt) : 0;
        }
        __syncthreads();
        int tot = tot_s;
        for (int i = t; i < tot; i += 256) {
            uint_t e = staging[i];
            int bkt = e >> 24;
            arena[gbase[bkt] + (i - lofs[bkt])] = (int)(e & 0xFFFFFF);
        }
    } else if (blk < NBKT + NB_TEMP) {
        // ---------------- temporal ----------------
        int base = (blk - NBKT) * 512;
        #pragma unroll
        for (int u = 0; u < 2; u++) {
            int tid = base + u * 256 + t;
            int rt   = tid >> 11;
            int kt   = (tid >> 9) & 3;
            int lane = (tid >> 3) & 63;
            int j    = tid & 7;
            int n = rt * 16 + (lane & 15);
            int c = kt * 32 + (lane >> 4) * 8 + j;
            float tv = ts[n];
            const float coef = -0.07195570687f;  // -ln(10000)/128
            float ang = tv * __expf((float)(c & ~1) * coef);
            float pe = (c & 1) ? __cosf(ang) : __sinf(ang);
            h[tid] = f2bf(x[n * 128 + c] + pe);
        }
    } else if (blk < NBKT + NB_TEMP + NB_WS) {
        // ---------------- wsplit ----------------
        int tid = (blk - NBKT - NB_TEMP) * 256 + t;  // 0..131071
        int j    = tid & 7;
        int lane = (tid >> 3) & 63;
        int kt   = (tid >> 9) & 3;
        int cgy  = (tid >> 11) & 31;
        int L    = tid >> 16;
        int col = cgy * 16 + (lane & 15);
        int k   = kt * 32 + (lane >> 4) * 8 + j;
        int mat = col >> 7, c = col & 127;
        const float* W = (L == 0)
            ? ((mat == 0) ? Wq1 : (mat == 1) ? Wk1 : (mat == 2) ? Wv1 : Ws1)
            : ((mat == 0) ? Wq2 : (mat == 1) ? Wk2 : (mat == 2) ? Wv2 : Ws2);
        size_t base = (size_t)L * 65536 + (size_t)cgy * 2048 + (size_t)kt * 512;
        WF[base + lane * 8 + j] = f2bf(W[k * 128 + c]);
        if (kt == 0 && (lane >> 4) == 0 && j == 0) {
            const float* b = (L == 0)
                ? ((mat == 0) ? bq1 : (mat == 1) ? bk1 : (mat == 2) ? bv1 : bs1)
                : ((mat == 0) ? bq2 : (mat == 1) ? bk2 : (mat == 2) ? bv2 : bs2);
            bias_cat[L * 512 + col] = b[c];
        }
    } else {
        // ---------------- docemb: relu(doc @ Wdoc + bdoc), one graph/block --
        int b = blk - NBKT - NB_TEMP - NB_WS;   // 0..63
        int c = t & 127, half = t >> 7;
        float* red = (float*)staging;           // reuse LDS
        float acc = (half == 0) ? bdoc[c] : 0.f;
        int k0 = half * 256;
        #pragma unroll 8
        for (int k = 0; k < 256; k++)
            acc += doc[b * 512 + k0 + k] * Wdoc[(size_t)(k0 + k) * 128 + c];
        red[t] = acc;
        __syncthreads();
        if (t < 128) docemb[b * 128 + c] = fmaxf(red[t] + red[t + 128], 0.f);
    }
}

// ---------- shared gemm body ----------
__device__ __forceinline__ void gemm_body(
    int rp, int cg0, int lane, int quad, int m,
    const ushort_t* __restrict__ hf, const ushort_t* __restrict__ WF,
    const float* __restrict__ bias_cat,
    ushort_t* __restrict__ qsb, uchar_t* __restrict__ kv8) {
    int rt0 = rp * 2;
    if (rt0 >= N_RT) return;
    int rt1 = rt0 + 1;
    int rt1c = (rt1 < N_RT) ? rt1 : rt0;

    short8 a0[4], a1[4];
    {
        const ushort_t* b0 = hf + (size_t)rt0 * 2048 + lane * 8;
        const ushort_t* b1 = hf + (size_t)rt1c * 2048 + lane * 8;
        #pragma unroll
        for (int kt = 0; kt < 4; kt++) {
            a0[kt] = *reinterpret_cast<const short8*>(b0 + kt * 512);
            a1[kt] = *reinterpret_cast<const short8*>(b1 + kt * 512);
        }
    }

    const ushort_t* wfl = WF + (size_t)cg0 * 2048 + lane * 8;
    #pragma unroll 2
    for (int cg = 0; cg < 8; cg++) {
        const ushort_t* fp = wfl + (size_t)cg * 2048;
        float4v acc0 = {0.f, 0.f, 0.f, 0.f};
        float4v acc1 = {0.f, 0.f, 0.f, 0.f};
        #pragma unroll
        for (int kt = 0; kt < 4; kt++) {
            short8 bh = *reinterpret_cast<const short8*>(fp + kt * 512);
            acc0 = __builtin_amdgcn_mfma_f32_16x16x32_bf16(a0[kt], bh, acc0, 0, 0, 0);
            acc1 = __builtin_amdgcn_mfma_f32_16x16x32_bf16(a1[kt], bh, acc1, 0, 0, 0);
        }
        int col = (cg0 + cg) * 16 + m;
        float bias = bias_cat[col];
        int mat = col >> 7;
        #pragma unroll
        for (int r = 0; r < 4; r++) {
            float v0 = acc0[r] + bias;
            size_t row0 = (size_t)rt0 * 16 + quad * 4 + r;
            if (mat == 0)      qsb[row0 * 256 + col] = f2bf(v0);
            else if (mat == 3) qsb[row0 * 256 + (col - 256)] = f2bf(v0);
            else               kv8[row0 * 256 + (col - 128)] = f2fp8(v0);
        }
        if (rt1 < N_RT) {
            #pragma unroll
            for (int r = 0; r < 4; r++) {
                float v1 = acc1[r] + bias;
                size_t row1 = (size_t)rt1 * 16 + quad * 4 + r;
                if (mat == 0)      qsb[row1 * 256 + col] = f2bf(v1);
                else if (mat == 3) qsb[row1 * 256 + (col - 256)] = f2bf(v1);
                else               kv8[row1 * 256 + (col - 128)] = f2fp8(v1);
            }
        }
    }
}

// ---------- fused: passB + gemm L1 + fusdoc ---------------------------------
__global__ __launch_bounds__(256) void g1_kernel(
    const int* __restrict__ off, const int* __restrict__ arena,
    int* __restrict__ csr,
    const ushort_t* __restrict__ hf, const ushort_t* __restrict__ WF,
    const float* __restrict__ bias_cat,
    ushort_t* __restrict__ qsb, uchar_t* __restrict__ kv8,
    const float* __restrict__ docemb, const float* __restrict__ Wfus,
    const float* __restrict__ bfus, float* __restrict__ fusdoc) {
    __shared__ uint_t smem[BCAP + 257 + 256];
    int blk = blockIdx.x;
    int t = threadIdx.x;
    if (blk < NBKT) {
        uint_t* stage = smem;
        int* offL = (int*)(smem + BCAP);
        int* lcur = (int*)(smem + BCAP + 257);
        int n0 = blk * 256;
        int nEnd = (n0 + 256 < N_NODES) ? n0 + 256 : N_NODES;
        int base = off[n0];
        int end = off[nEnd];
        int size = end - base;
        if (n0 + t < nEnd) offL[t] = off[n0 + t] - base;
        lcur[t] = 0;
        __syncthreads();
        int lim = (size < BCAP) ? size : BCAP;
        for (int i = t; i < lim; i += 256) stage[i] = (uint_t)arena[base + i];
        __syncthreads();
        for (int i = t; i < size; i += 256) {
            uint_t e = (i < BCAP) ? stage[i] : (uint_t)arena[base + i];
            int dlow = (e >> 16) & 255;
            int src = (int)(e & 0xFFFF);
            int pos = offL[dlow] + atomicAdd(&lcur[dlow], 1);
            csr[base + pos] = src;
        }
    } else if (blk < NBKT + NB_GEMM) {
        int blk2 = blk - NBKT;           // 0..1563
        int y = blk2 / 391, bx = blk2 % 391;
        int wave = t >> 6, lane = t & 63;
        gemm_body(bx * 4 + wave, y * 8, lane, lane >> 4, lane & 15,
                  hf, WF, bias_cat, qsb, kv8);
    } else {
        // ---- fusdoc[b][c] = bfus[c] + docemb[b] @ Wfus[128:256] ----
        int b = blk - NBKT - NB_GEMM;    // 0..63
        int c = t & 127, half = t >> 7;
        float* de = (float*)smem;        // 128 floats
        float* red = (float*)smem + 128;
        if (t < 128) de[t] = docemb[b * 128 + t];
        __syncthreads();
        float acc = (half == 0) ? bfus[c] : 0.f;
        int k0 = half * 64;
        #pragma unroll 8
        for (int k = 0; k < 64; k++)
            acc += de[k0 + k] * Wfus[(size_t)(128 + k0 + k) * 128 + c];
        red[t] = acc;
        __syncthreads();
        if (t < 128) fusdoc[b * 128 + c] = red[t] + red[t + 128];
    }
}

// ---------- plain gemm (layer 2) ----------
__global__ __launch_bounds__(256) void gemm_qkvs(
    const ushort_t* __restrict__ hf,
    const ushort_t* __restrict__ WF,
    const float* __restrict__ bias_cat,
    ushort_t* __restrict__ qsb, uchar_t* __restrict__ kv8) {
    int t = threadIdx.x;
    int wave = t >> 6, lane = t & 63;
    gemm_body(blockIdx.x * 4 + wave, blockIdx.y * 8, lane, lane >> 4, lane & 15,
              hf, WF, bias_cat, qsb, kv8);
}

// ---------- fused per-node attention + skip + BN + relu -> h (frag-major) ----
__global__ __launch_bounds__(256) void node_attn_bn(
    const int* __restrict__ off, const int* __restrict__ csr_src,
    const ushort_t* __restrict__ qsb, const uchar_t* __restrict__ kv8,
    const float* __restrict__ bng, const float* __restrict__ bnb,
    const float* __restrict__ bnm, const float* __restrict__ bnv,
    ushort_t* __restrict__ h) {
    int wave = threadIdx.x >> 6;
    int n = blockIdx.x * 4 + wave;
    if (n >= N_NODES) return;
    int lane = threadIdx.x & 63;
    int qtr = lane >> 4, s16 = lane & 15;
    int c0 = s16 * 8;

    const ushort_t* row_qs = qsb + (size_t)n * 256;
    float2v q2[4];
    {
        uint4 qu = *reinterpret_cast<const uint4*>(row_qs + c0);
        q2[0].x = bf2f(qu.x & 0xffff) * 0.125f; q2[0].y = bf2f(qu.x >> 16) * 0.125f;
        q2[1].x = bf2f(qu.y & 0xffff) * 0.125f; q2[1].y = bf2f(qu.y >> 16) * 0.125f;
        q2[2].x = bf2f(qu.z & 0xffff) * 0.125f; q2[2].y = bf2f(qu.z >> 16) * 0.125f;
        q2[3].x = bf2f(qu.w & 0xffff) * 0.125f; q2[3].y = bf2f(qu.w >> 16) * 0.125f;
    }

    int e0 = off[n], e1 = off[n + 1];
    float l = 0.f;
    float2v o2[4];
    o2[0] = (float2v){0.f, 0.f}; o2[1] = (float2v){0.f, 0.f};
    o2[2] = (float2v){0.f, 0.f}; o2[3] = (float2v){0.f, 0.f};

    int src_a = (e0 + qtr < e1) ? csr_src[e0 + qtr] : 0;
    int src_b = (e0 + 4 + qtr < e1) ? csr_src[e0 + 4 + qtr] : 0;
    for (int p = e0; p < e1; p += 8) {
        int ia = p + qtr, ib = p + 4 + qtr;
        bool va = ia < e1, vb = ib < e1;
        int sa = src_a, sb = src_b;
        int na = p + 8 + qtr, nb = p + 12 + qtr;
        if (na < e1) src_a = csr_src[na];
        if (nb < e1) src_b = csr_src[nb];
        const uchar_t* kpa = kv8 + (size_t)sa * 256;
        const uchar_t* kpb = kv8 + (size_t)sb * 256;
        uint2 kua = *reinterpret_cast<const uint2*>(kpa + c0);
        uint2 vua = *reinterpret_cast<const uint2*>(kpa + 128 + c0);
        uint2 kub = *reinterpret_cast<const uint2*>(kpb + c0);
        uint2 vub = *reinterpret_cast<const uint2*>(kpb + 128 + c0);
        float2v ka2[4], wa2[4], kb2[4], wb2[4];
        fp8x4_dec2(kua.x, ka2);  fp8x4_dec2(kua.y, ka2 + 2);
        fp8x4_dec2(kub.x, kb2);  fp8x4_dec2(kub.y, kb2 + 2);
        fp8x4_dec2(vua.x, wa2);  fp8x4_dec2(vua.y, wa2 + 2);
        fp8x4_dec2(vub.x, wb2);  fp8x4_dec2(vub.y, wb2 + 2);
        float2v da2 = q2[0] * ka2[0];
        float2v db2 = q2[0] * kb2[0];
        da2 += q2[1] * ka2[1];  db2 += q2[1] * kb2[1];
        da2 += q2[2] * ka2[2];  db2 += q2[2] * kb2[2];
        da2 += q2[3] * ka2[3];  db2 += q2[3] * kb2[3];
        float da = da2.x + da2.y;
        float db = db2.x + db2.y;
        da += __shfl_xor(da, 1);  db += __shfl_xor(db, 1);
        da += __shfl_xor(da, 2);  db += __shfl_xor(db, 2);
        da += __shfl_xor(da, 4);  db += __shfl_xor(db, 4);
        float pea = va ? __expf(da) : 0.f;
        float peb = vb ? __expf(db) : 0.f;
        l += pea + peb;
        float2v pa; pa.x = pea; pa.y = pea;
        float2v pb; pb.x = peb; pb.y = peb;
        #pragma unroll
        for (int i = 0; i < 4; i++) {
            o2[i] += pa * wa2[i];
            o2[i] += pb * wb2[i];
        }
    }
    #pragma unroll
    for (int offx = 16; offx <= 32; offx <<= 1) {
        l += __shfl_xor(l, offx);
        #pragma unroll
        for (int i = 0; i < 4; i++) {
            o2[i].x += __shfl_xor(o2[i].x, offx);
            o2[i].y += __shfl_xor(o2[i].y, offx);
        }
    }

    if (qtr == 0) {
        float inv = 1.f / (l + 1e-16f);
        float o[8] = {o2[0].x, o2[0].y, o2[1].x, o2[1].y,
                      o2[2].x, o2[2].y, o2[3].x, o2[3].y};
        float sv[8];
        {
            uint4 su = *reinterpret_cast<const uint4*>(row_qs + 128 + c0);
            sv[0] = bf2f(su.x & 0xffff); sv[1] = bf2f(su.x >> 16);
            sv[2] = bf2f(su.y & 0xffff); sv[3] = bf2f(su.y >> 16);
            sv[4] = bf2f(su.z & 0xffff); sv[5] = bf2f(su.z >> 16);
            sv[6] = bf2f(su.w & 0xffff); sv[7] = bf2f(su.w >> 16);
        }
        float gv[8], bv[8], mv[8], vr[8];
        *reinterpret_cast<float4*>(gv)     = *reinterpret_cast<const float4*>(bng + c0);
        *reinterpret_cast<float4*>(gv + 4) = *reinterpret_cast<const float4*>(bng + c0 + 4);
        *reinterpret_cast<float4*>(bv)     = *reinterpret_cast<const float4*>(bnb + c0);
        *reinterpret_cast<float4*>(bv + 4) = *reinterpret_cast<const float4*>(bnb + c0 + 4);
        *reinterpret_cast<float4*>(mv)     = *reinterpret_cast<const float4*>(bnm + c0);
        *reinterpret_cast<float4*>(mv + 4) = *reinterpret_cast<const float4*>(bnm + c0 + 4);
        *reinterpret_cast<float4*>(vr)     = *reinterpret_cast<const float4*>(bnv + c0);
        *reinterpret_cast<float4*>(vr + 4) = *reinterpret_cast<const float4*>(bnv + c0 + 4);
        uint_t hw[4];
        #pragma unroll
        for (int i = 0; i < 8; i++) {
            float val = fmaxf(o[i] * inv + sv[i], 0.f);
            val = (val - mv[i]) * rsqrtf(vr[i] + 1e-5f) * gv[i] + bv[i];
            val = fmaxf(val, 0.f);
            ushort_t hb = f2bf(val);
            if (i & 1) hw[i >> 1] |= (uint_t)hb << 16;
            else       hw[i >> 1] = hb;
        }
        int rt = n >> 4, mnode = n & 15;
        int kt = s16 >> 2, qd = s16 & 3;
        size_t fidx = (size_t)rt * 2048 + kt * 512 + (mnode + 16 * qd) * 8;
        uint4 hp; hp.x = hw[0]; hp.y = hw[1]; hp.z = hw[2]; hp.w = hw[3];
        *reinterpret_cast<uint4*>(h + fidx) = hp;
    }
}

// ---------- global mean pool ----------
__global__ void pool_kernel(const ushort_t* __restrict__ h,
                            const int* __restrict__ batch,
                            float* __restrict__ sums,
                            float* __restrict__ cnt) {
    int t = threadIdx.x;
    int c = t & 127, half = t >> 7;
    int kt = c >> 5, qd = (c >> 3) & 3, j = c & 7;
    int base = blockIdx.x * 128;
    float acc = 0.f, accc = 0.f;
    int gcur = -1;
    for (int i = 0; i < 64; i++) {
        int n = base + 2 * i + half;
        if (n >= N_NODES) break;
        int g = batch[n];
        if (g != gcur) {
            if (gcur >= 0) {
                atomicAdd(&sums[gcur * 128 + c], acc);
                if (c == 0) atomicAdd(&cnt[gcur], accc);
            }
            acc = 0.f; accc = 0.f; gcur = g;
        }
        size_t fidx = (size_t)(n >> 4) * 2048 + kt * 512 + ((n & 15) + 16 * qd) * 8 + j;
        acc += bf2f((uint_t)h[fidx]);
        accc += 1.f;
    }
    if (gcur >= 0) {
        atomicAdd(&sums[gcur * 128 + c], acc);
        if (c == 0) atomicAdd(&cnt[gcur], accc);
    }
}

// ---------- final head: gbuf@Wfus[0:128] + fusdoc -> relu -> task/time -----
__global__ __launch_bounds__(128) void final_mlp(
    const float* __restrict__ sums, const float* __restrict__ cnt,
    const float* __restrict__ fusdoc, const float* __restrict__ Wfus,
    const float* __restrict__ Wtask, const float* __restrict__ btask,
    const float* __restrict__ Wtime, const float* __restrict__ btime,
    float* __restrict__ out) {
    int b = blockIdx.x;
    int t = threadIdx.x;
    __shared__ float gbuf[128], fbuf[128];
    float c = fmaxf(cnt[b], 1.0f);
    gbuf[t] = sums[b * 128 + t] / c;
    __syncthreads();
    float f = fusdoc[b * 128 + t];
    #pragma unroll 8
    for (int k = 0; k < 128; k++) f += gbuf[k] * Wfus[(size_t)k * 128 + t];
    fbuf[t] = fmaxf(f, 0.f);
    __syncthreads();
    if (t < 16) {
        float a = btask[t];
        #pragma unroll 8
        for (int k = 0; k < 128; k++) a += fbuf[k] * Wtask[k * 16 + t];
        out[b * 16 + t] = a;
    } else if (t == 16) {
        float a = btime[0];
        #pragma unroll 8
        for (int k = 0; k < 128; k++) a += fbuf[k] * Wtime[k];
        out[NGRAPH * 16 + b] = a;
    }
}

extern "C" void kernel_launch(void* const* d_in, const int* in_sizes, int n_in,
                              void* d_out, int out_size, void* d_ws, size_t ws_size,
                              hipStream_t stream) {
    (void)in_sizes; (void)n_in; (void)out_size; (void)ws_size;
    const float* x    = (const float*)d_in[0];
    const int*   ei   = (const int*)d_in[1];
    const int*   batch= (const int*)d_in[2];
    const float* ts   = (const float*)d_in[3];
    const float* doc  = (const float*)d_in[4];
    const float* Wq1  = (const float*)d_in[5];
    const float* bq1  = (const float*)d_in[6];
    const float* Wk1  = (const float*)d_in[7];
    const float* bk1  = (const float*)d_in[8];
    const float* Wv1  = (const float*)d_in[9];
    const float* bv1  = (const float*)d_in[10];
    const float* Ws1  = (const float*)d_in[11];
    const float* bs1  = (const float*)d_in[12];
    const float* Wq2  = (const float*)d_in[13];
    const float* bq2  = (const float*)d_in[14];
    const float* Wk2  = (const float*)d_in[15];
    const float* bk2  = (const float*)d_in[16];
    const float* Wv2  = (const float*)d_in[17];
    const float* bv2  = (const float*)d_in[18];
    const float* Ws2  = (const float*)d_in[19];
    const float* bs2  = (const float*)d_in[20];
    const float* bn1g = (const float*)d_in[21];
    const float* bn1b = (const float*)d_in[22];
    const float* bn1m = (const float*)d_in[23];
    const float* bn1v = (const float*)d_in[24];
    const float* bn2g = (const float*)d_in[25];
    const float* bn2b = (const float*)d_in[26];
    const float* bn2m = (const float*)d_in[27];
    const float* bn2v = (const float*)d_in[28];
    const float* Wdoc = (const float*)d_in[29];
    const float* bdoc = (const float*)d_in[30];
    const float* Wfus = (const float*)d_in[31];
    const float* bfus = (const float*)d_in[32];
    const float* Wtask= (const float*)d_in[33];
    const float* btask= (const float*)d_in[34];
    const float* Wtime= (const float*)d_in[35];
    const float* btime= (const float*)d_in[36];

    char* ws = (char*)d_ws;
    ushort_t* h      = (ushort_t*)(ws + 0);           // 12.8 MB
    ushort_t* qsb    = (ushort_t*)(ws + 12800000);    // 25.6 MB
    uchar_t*  kv8    = (uchar_t*)(ws + 38400000);     // 12.8 MB
    ushort_t* WF     = (ushort_t*)(ws + 51200000);    // 256 KB
    float*    biasc  = (float*)(ws + 51462144);       // 4 KB
    int*      deg    = (int*)(ws + 51466240);         // 200000 B
    ull_t*    sstate = (ull_t*)(ws + 51666240);       // 1568 B
    float*    sums   = (float*)(ws + 51667808);       // 32768 B
    float*    cnt    = (float*)(ws + 51700576);       // 256 B
    int*      off    = (int*)(ws + 51700832);         // 200004 B
    int*      bucketcur = (int*)(ws + 51900836);      // 784 B
    int*      arena  = (int*)(ws + 51901620);         // 3.2 MB
    int*      csr    = (int*)(ws + 55101620);         // 3.2 MB
    float*    docemb = (float*)(ws + 58301620);       // 32 KB
    float*    fusdoc = (float*)(ws + 58334388);       // 32 KB

    float* out = (float*)d_out;

    hipMemsetAsync(deg, 0, 200000 + 1568, stream);

    deg_kernel<<<3125, 256, 0, stream>>>(ei, deg);
    scan_kernel<<<NB_SCAN, 256, 0, stream>>>(deg, off, bucketcur, sums, cnt, sstate);
    prep_kernel<<<NBKT + NB_TEMP + NB_WS + NGRAPH, 256, 0, stream>>>(
        ei, off, bucketcur, arena, x, ts, h,
        Wq1, Wk1, Wv1, Ws1, Wq2, Wk2, Wv2, Ws2,
        bq1, bk1, bv1, bs1, bq2, bk2, bv2, bs2, WF, biasc,
        doc, Wdoc, bdoc, docemb);

    const size_t WF_LAYER = 65536;  // shorts per layer

    // ---- layer 1 (gemm fused with passB + fusdoc) ----
    g1_kernel<<<NBKT + NB_GEMM + NGRAPH, 256, 0, stream>>>(
        off, arena, csr, h, WF, biasc, qsb, kv8, docemb, Wfus, bfus, fusdoc);
    node_attn_bn<<<12500, 256, 0, stream>>>(off, csr, qsb, kv8, bn1g, bn1b, bn1m, bn1v, h);

    // ---- layer 2 ----
    gemm_qkvs<<<dim3(391, 4), 256, 0, stream>>>(h, WF + WF_LAYER, biasc + 512, qsb, kv8);
    node_attn_bn<<<12500, 256, 0, stream>>>(off, csr, qsb, kv8, bn2g, bn2b, bn2m, bn2v, h);

    // ---- pool + final head ----
    pool_kernel<<<391, 256, 0, stream>>>(h, batch, sums, cnt);
    final_mlp<<<NGRAPH, 128, 0, stream>>>(sums, cnt, fusdoc, Wfus,
                                          Wtask, btask, Wtime, btime, out);
}

// Round 15
// 363.601 us; speedup vs baseline: 1.0962x; 1.0497x over previous
//
#include <hip/hip_runtime.h>

typedef unsigned short ushort_t;
typedef unsigned int uint_t;
typedef unsigned char uchar_t;
typedef unsigned long long ull_t;

#define N_NODES 50000
#define N_EDGES 800000
#define HID 128
#define NGRAPH 64
#define N_RT 3125     // row tiles of 16 nodes
#define NBKT 196      // coarse buckets of 256 nodes
#define CHUNK 4096    // edges per pass-A block
#define NB_TEMP 12500 // temporal blocks (x512 elems)
#define NB_WS 512     // wsplit blocks
#define NB_GEMM 1564  // 4*391
#define BCAP 6144     // passB LDS stage capacity (mean 4096 + 32 sigma)
#define BMAX 8192     // arena slot per bucket (mean + 64 sigma)
#define NB_POOL 782

typedef __attribute__((ext_vector_type(8))) short short8;
typedef __attribute__((ext_vector_type(4))) float float4v;
typedef __attribute__((ext_vector_type(2))) float float2v;

// ---------- bf16 helpers ----------
__device__ __forceinline__ float bf2f(uint_t u) {
    union { uint_t i; float f; } v; v.i = u << 16; return v.f;
}
__device__ __forceinline__ ushort_t f2bf(float f) {
    union { float f; uint_t i; } v; v.f = f;
    uint_t r = v.i + 0x7FFFu + ((v.i >> 16) & 1u);
    return (ushort_t)(r >> 16);
}

// ---------- fp8 e4m3 helpers ----------
#if __has_builtin(__builtin_amdgcn_cvt_pk_fp8_f32) && __has_builtin(__builtin_amdgcn_cvt_pk_f32_fp8)
#define HAS_FP8_CVT 1
#else
#define HAS_FP8_CVT 0
#endif

__device__ __forceinline__ uchar_t f2fp8(float x) {
#if HAS_FP8_CVT
    int p = __builtin_amdgcn_cvt_pk_fp8_f32(x, x, 0, false);
    return (uchar_t)(p & 0xFF);
#else
    union { float f; uint_t u; } v; v.f = x;
    uint_t s = (v.u >> 31) << 7;
    float a = fabsf(x);
    a = fminf(a, 448.f);
    if (a < 0.015625f) {
        int m3 = (int)(a * 512.f + 0.5f);
        return (uchar_t)(s | (uint_t)m3);
    }
    v.f = a;
    uint_t r = v.u + 0x7FFFFu + ((v.u >> 20) & 1u);
    uint_t e = r >> 23;
    return (uchar_t)(s | ((e - 120u) << 3) | ((r >> 20) & 7u));
#endif
}

__device__ __forceinline__ float fp8dec1(uint_t b) {
    uint_t e = (b >> 3) & 15u, mnt = b & 7u;
    union { uint_t u; float f; } v;
    v.u = ((e + 120u) << 23) | (mnt << 20);
    float mag = e ? v.f : (float)mnt * 0.001953125f;  // 2^-9
    return (b & 0x80u) ? -mag : mag;
}

__device__ __forceinline__ void fp8x4_dec2(uint_t w, float2v* o) {
#if HAS_FP8_CVT
    o[0] = __builtin_amdgcn_cvt_pk_f32_fp8(w, false);
    o[1] = __builtin_amdgcn_cvt_pk_f32_fp8(w, true);
#else
    float2v a, b;
    a.x = fp8dec1(w & 0xFFu);  a.y = fp8dec1((w >> 8) & 0xFFu);
    b.x = fp8dec1((w >> 16) & 0xFFu); b.y = fp8dec1(w >> 24);
    o[0] = a; o[1] = b;
#endif
}

// ---------- prep mega-kernel: passA + temporal + wsplit + docemb ------------
// passA writes edges into fixed per-bucket arena slots [bkt*BMAX, ...) --
// no prefix scan needed beforehand; bucketcur (zeroed) counts per bucket.
__global__ __launch_bounds__(256) void prep_kernel(
    const int* __restrict__ ei,
    int* __restrict__ bucketcur, int* __restrict__ arena,
    const float* __restrict__ x, const float* __restrict__ ts,
    ushort_t* __restrict__ h,
    const float* __restrict__ Wq1, const float* __restrict__ Wk1,
    const float* __restrict__ Wv1, const float* __restrict__ Ws1,
    const float* __restrict__ Wq2, const float* __restrict__ Wk2,
    const float* __restrict__ Wv2, const float* __restrict__ Ws2,
    const float* __restrict__ bq1, const float* __restrict__ bk1,
    const float* __restrict__ bv1, const float* __restrict__ bs1,
    const float* __restrict__ bq2, const float* __restrict__ bk2,
    const float* __restrict__ bv2, const float* __restrict__ bs2,
    ushort_t* __restrict__ WF, float* __restrict__ bias_cat,
    const float* __restrict__ doc, const float* __restrict__ Wdoc,
    const float* __restrict__ bdoc, float* __restrict__ docemb,
    float* __restrict__ sums, float* __restrict__ cnt) {
    __shared__ int hist[NBKT];
    __shared__ int lofs[NBKT];
    __shared__ int lcur[NBKT];
    __shared__ int gbase[NBKT];
    __shared__ int sbuf[256];
    __shared__ uint_t staging[CHUNK];
    __shared__ int tot_s;

    int blk = blockIdx.x;
    int t = threadIdx.x;

    if (blk < NBKT) {
        // ---------------- pass A ----------------
        if (t < NBKT) hist[t] = 0;
        __syncthreads();
        int e0 = blk * CHUNK;
        int srcs[16], dsts[16];
        #pragma unroll
        for (int i = 0; i < 16; i++) {
            int idx = e0 + i * 256 + t;
            bool v = idx < N_EDGES;
            srcs[i] = v ? ei[idx] : -1;
            dsts[i] = v ? ei[N_EDGES + idx] : -1;
            if (v) atomicAdd(&hist[dsts[i] >> 8], 1);
        }
        __syncthreads();
        int hv = (t < NBKT) ? hist[t] : 0;
        sbuf[t] = hv;
        __syncthreads();
        #pragma unroll
        for (int s = 1; s < 256; s <<= 1) {
            int add = (t >= s) ? sbuf[t - s] : 0;
            __syncthreads();
            sbuf[t] += add;
            __syncthreads();
        }
        if (t < NBKT) {
            lofs[t] = sbuf[t] - hv;
            lcur[t] = sbuf[t] - hv;
        }
        if (t == NBKT - 1) tot_s = sbuf[NBKT - 1];
        __syncthreads();
        #pragma unroll
        for (int i = 0; i < 16; i++) {
            if (srcs[i] >= 0) {
                int bkt = dsts[i] >> 8;
                int pos = atomicAdd(&lcur[bkt], 1);
                staging[pos] = ((uint_t)bkt << 24) | ((uint_t)(dsts[i] & 255) << 16)
                             | (uint_t)srcs[i];
            }
        }
        __syncthreads();
        if (t < NBKT) {
            int hcnt = hist[t];
            gbase[t] = t * BMAX + (hcnt ? atomicAdd(&bucketcur[t], hcnt) : 0);
        }
        __syncthreads();
        int tot = tot_s;
        for (int i = t; i < tot; i += 256) {
            uint_t e = staging[i];
            int bkt = e >> 24;
            arena[gbase[bkt] + (i - lofs[bkt])] = (int)(e & 0xFFFFFF);
        }
    } else if (blk < NBKT + NB_TEMP) {
        // ---------------- temporal ----------------
        int base = (blk - NBKT) * 512;
        #pragma unroll
        for (int u = 0; u < 2; u++) {
            int tid = base + u * 256 + t;
            int rt   = tid >> 11;
            int kt   = (tid >> 9) & 3;
            int lane = (tid >> 3) & 63;
            int j    = tid & 7;
            int n = rt * 16 + (lane & 15);
            int c = kt * 32 + (lane >> 4) * 8 + j;
            float tv = ts[n];
            const float coef = -0.07195570687f;  // -ln(10000)/128
            float ang = tv * __expf((float)(c & ~1) * coef);
            float pe = (c & 1) ? __cosf(ang) : __sinf(ang);
            h[tid] = f2bf(x[n * 128 + c] + pe);
        }
    } else if (blk < NBKT + NB_TEMP + NB_WS) {
        // ---------------- wsplit ----------------
        int tid = (blk - NBKT - NB_TEMP) * 256 + t;  // 0..131071
        int j    = tid & 7;
        int lane = (tid >> 3) & 63;
        int kt   = (tid >> 9) & 3;
        int cgy  = (tid >> 11) & 31;
        int L    = tid >> 16;
        int col = cgy * 16 + (lane & 15);
        int k   = kt * 32 + (lane >> 4) * 8 + j;
        int mat = col >> 7, c = col & 127;
        const float* W = (L == 0)
            ? ((mat == 0) ? Wq1 : (mat == 1) ? Wk1 : (mat == 2) ? Wv1 : Ws1)
            : ((mat == 0) ? Wq2 : (mat == 1) ? Wk2 : (mat == 2) ? Wv2 : Ws2);
        size_t base = (size_t)L * 65536 + (size_t)cgy * 2048 + (size_t)kt * 512;
        WF[base + lane * 8 + j] = f2bf(W[k * 128 + c]);
        if (kt == 0 && (lane >> 4) == 0 && j == 0) {
            const float* b = (L == 0)
                ? ((mat == 0) ? bq1 : (mat == 1) ? bk1 : (mat == 2) ? bv1 : bs1)
                : ((mat == 0) ? bq2 : (mat == 1) ? bk2 : (mat == 2) ? bv2 : bs2);
            bias_cat[L * 512 + col] = b[c];
        }
    } else {
        // ---------------- docemb + zero pool accumulators ----------------
        int b = blk - NBKT - NB_TEMP - NB_WS;   // 0..63
        int c = t & 127, half = t >> 7;
        if (t < 128) sums[b * 128 + t] = 0.f;
        if (t == 128) cnt[b] = 0.f;
        float* red = (float*)staging;           // reuse LDS
        float acc = (half == 0) ? bdoc[c] : 0.f;
        int k0 = half * 256;
        #pragma unroll 8
        for (int k = 0; k < 256; k++)
            acc += doc[b * 512 + k0 + k] * Wdoc[(size_t)(k0 + k) * 128 + c];
        red[t] = acc;
        __syncthreads();
        if (t < 128) docemb[b * 128 + c] = fmaxf(red[t] + red[t + 128], 0.f);
    }
}

// ---------- shared gemm body ----------
__device__ __forceinline__ void gemm_body(
    int rp, int cg0, int lane, int quad, int m,
    const ushort_t* __restrict__ hf, const ushort_t* __restrict__ WF,
    const float* __restrict__ bias_cat,
    ushort_t* __restrict__ qsb, uchar_t* __restrict__ kv8) {
    int rt0 = rp * 2;
    if (rt0 >= N_RT) return;
    int rt1 = rt0 + 1;
    int rt1c = (rt1 < N_RT) ? rt1 : rt0;

    short8 a0[4], a1[4];
    {
        const ushort_t* b0 = hf + (size_t)rt0 * 2048 + lane * 8;
        const ushort_t* b1 = hf + (size_t)rt1c * 2048 + lane * 8;
        #pragma unroll
        for (int kt = 0; kt < 4; kt++) {
            a0[kt] = *reinterpret_cast<const short8*>(b0 + kt * 512);
            a1[kt] = *reinterpret_cast<const short8*>(b1 + kt * 512);
        }
    }

    const ushort_t* wfl = WF + (size_t)cg0 * 2048 + lane * 8;
    #pragma unroll 2
    for (int cg = 0; cg < 8; cg++) {
        const ushort_t* fp = wfl + (size_t)cg * 2048;
        float4v acc0 = {0.f, 0.f, 0.f, 0.f};
        float4v acc1 = {0.f, 0.f, 0.f, 0.f};
        #pragma unroll
        for (int kt = 0; kt < 4; kt++) {
            short8 bh = *reinterpret_cast<const short8*>(fp + kt * 512);
            acc0 = __builtin_amdgcn_mfma_f32_16x16x32_bf16(a0[kt], bh, acc0, 0, 0, 0);
            acc1 = __builtin_amdgcn_mfma_f32_16x16x32_bf16(a1[kt], bh, acc1, 0, 0, 0);
        }
        int col = (cg0 + cg) * 16 + m;
        float bias = bias_cat[col];
        int mat = col >> 7;
        #pragma unroll
        for (int r = 0; r < 4; r++) {
            float v0 = acc0[r] + bias;
            size_t row0 = (size_t)rt0 * 16 + quad * 4 + r;
            if (mat == 0)      qsb[row0 * 256 + col] = f2bf(v0);
            else if (mat == 3) qsb[row0 * 256 + (col - 256)] = f2bf(v0);
            else               kv8[row0 * 256 + (col - 128)] = f2fp8(v0);
        }
        if (rt1 < N_RT) {
            #pragma unroll
            for (int r = 0; r < 4; r++) {
                float v1 = acc1[r] + bias;
                size_t row1 = (size_t)rt1 * 16 + quad * 4 + r;
                if (mat == 0)      qsb[row1 * 256 + col] = f2bf(v1);
                else if (mat == 3) qsb[row1 * 256 + (col - 256)] = f2bf(v1);
                else               kv8[row1 * 256 + (col - 128)] = f2fp8(v1);
            }
        }
    }
}

// ---------- fused: passB (off+csr build) + gemm L1 + fusdoc -----------------
__global__ __launch_bounds__(256) void g1_kernel(
    int* __restrict__ off, const int* __restrict__ arena,
    const int* __restrict__ bucketcur, int* __restrict__ csr,
    const ushort_t* __restrict__ hf, const ushort_t* __restrict__ WF,
    const float* __restrict__ bias_cat,
    ushort_t* __restrict__ qsb, uchar_t* __restrict__ kv8,
    const float* __restrict__ docemb, const float* __restrict__ Wfus,
    const float* __restrict__ bfus, float* __restrict__ fusdoc) {
    __shared__ uint_t smem[BCAP + 1024];
    __shared__ int bbase_s;
    int blk = blockIdx.x;
    int t = threadIdx.x;
    if (blk < NBKT) {
        // ---- passB: derive off[] + exact csr from arena bucket ----
        uint_t* stage = smem;
        int* lcnt = (int*)(smem + BCAP);
        int* exc  = (int*)(smem + BCAP + 256);
        int* lcur = (int*)(smem + BCAP + 512);
        int* sb   = (int*)(smem + BCAP + 768);
        // bucket-level exclusive scan (196 counts)
        int bc = (t < NBKT) ? bucketcur[t] : 0;
        sb[t] = bc;
        __syncthreads();
        #pragma unroll
        for (int s = 1; s < 256; s <<= 1) {
            int a = (t >= s) ? sb[t - s] : 0;
            __syncthreads();
            sb[t] += a;
            __syncthreads();
        }
        if (t == 0) bbase_s = (blk == 0) ? 0 : sb[blk - 1];
        lcnt[t] = 0; lcur[t] = 0;
        __syncthreads();
        int bbase = bbase_s;
        int size = bucketcur[blk];
        int abase = blk * BMAX;
        int lim = (size < BCAP) ? size : BCAP;
        for (int i = t; i < lim; i += 256) stage[i] = (uint_t)arena[abase + i];
        __syncthreads();
        for (int i = t; i < size; i += 256) {
            uint_t e = (i < BCAP) ? stage[i] : (uint_t)arena[abase + i];
            atomicAdd(&lcnt[(e >> 16) & 255], 1);
        }
        __syncthreads();
        int v = lcnt[t];
        sb[t] = v;
        __syncthreads();
        #pragma unroll
        for (int s = 1; s < 256; s <<= 1) {
            int a = (t >= s) ? sb[t - s] : 0;
            __syncthreads();
            sb[t] += a;
            __syncthreads();
        }
        exc[t] = sb[t] - v;
        int n0 = blk * 256;
        if (n0 + t < N_NODES) off[n0 + t] = bbase + sb[t] - v;
        if (blk == NBKT - 1 && t == 0) off[N_NODES] = N_EDGES;
        __syncthreads();
        for (int i = t; i < size; i += 256) {
            uint_t e = (i < BCAP) ? stage[i] : (uint_t)arena[abase + i];
            int dlow = (e >> 16) & 255;
            int src = (int)(e & 0xFFFF);
            int pos = exc[dlow] + atomicAdd(&lcur[dlow], 1);
            csr[bbase + pos] = src;
        }
    } else if (blk < NBKT + NB_GEMM) {
        int blk2 = blk - NBKT;           // 0..1563
        int y = blk2 / 391, bx = blk2 % 391;
        int wave = t >> 6, lane = t & 63;
        gemm_body(bx * 4 + wave, y * 8, lane, lane >> 4, lane & 15,
                  hf, WF, bias_cat, qsb, kv8);
    } else {
        // ---- fusdoc[b][c] = bfus[c] + docemb[b] @ Wfus[128:256] ----
        int b = blk - NBKT - NB_GEMM;    // 0..63
        int c = t & 127, half = t >> 7;
        float* de = (float*)smem;
        float* red = (float*)smem + 128;
        if (t < 128) de[t] = docemb[b * 128 + t];
        __syncthreads();
        float acc = (half == 0) ? bfus[c] : 0.f;
        int k0 = half * 64;
        #pragma unroll 8
        for (int k = 0; k < 64; k++)
            acc += de[k0 + k] * Wfus[(size_t)(128 + k0 + k) * 128 + c];
        red[t] = acc;
        __syncthreads();
        if (t < 128) fusdoc[b * 128 + c] = red[t] + red[t + 128];
    }
}

// ---------- plain gemm (layer 2) ----------
__global__ __launch_bounds__(256) void gemm_qkvs(
    const ushort_t* __restrict__ hf,
    const ushort_t* __restrict__ WF,
    const float* __restrict__ bias_cat,
    ushort_t* __restrict__ qsb, uchar_t* __restrict__ kv8) {
    int t = threadIdx.x;
    int wave = t >> 6, lane = t & 63;
    gemm_body(blockIdx.x * 4 + wave, blockIdx.y * 8, lane, lane >> 4, lane & 15,
              hf, WF, bias_cat, qsb, kv8);
}

// ---------- fused per-node attention + skip + BN + relu -> h (frag-major) ----
__global__ __launch_bounds__(256) void node_attn_bn(
    const int* __restrict__ off, const int* __restrict__ csr_src,
    const ushort_t* __restrict__ qsb, const uchar_t* __restrict__ kv8,
    const float* __restrict__ bng, const float* __restrict__ bnb,
    const float* __restrict__ bnm, const float* __restrict__ bnv,
    ushort_t* __restrict__ h) {
    int wave = threadIdx.x >> 6;
    int n = blockIdx.x * 4 + wave;
    if (n >= N_NODES) return;
    int lane = threadIdx.x & 63;
    int qtr = lane >> 4, s16 = lane & 15;
    int c0 = s16 * 8;

    const ushort_t* row_qs = qsb + (size_t)n * 256;
    float2v q2[4];
    {
        uint4 qu = *reinterpret_cast<const uint4*>(row_qs + c0);
        q2[0].x = bf2f(qu.x & 0xffff) * 0.125f; q2[0].y = bf2f(qu.x >> 16) * 0.125f;
        q2[1].x = bf2f(qu.y & 0xffff) * 0.125f; q2[1].y = bf2f(qu.y >> 16) * 0.125f;
        q2[2].x = bf2f(qu.z & 0xffff) * 0.125f; q2[2].y = bf2f(qu.z >> 16) * 0.125f;
        q2[3].x = bf2f(qu.w & 0xffff) * 0.125f; q2[3].y = bf2f(qu.w >> 16) * 0.125f;
    }

    int e0 = off[n], e1 = off[n + 1];
    float l = 0.f;
    float2v o2[4];
    o2[0] = (float2v){0.f, 0.f}; o2[1] = (float2v){0.f, 0.f};
    o2[2] = (float2v){0.f, 0.f}; o2[3] = (float2v){0.f, 0.f};

    int src_a = (e0 + qtr < e1) ? csr_src[e0 + qtr] : 0;
    int src_b = (e0 + 4 + qtr < e1) ? csr_src[e0 + 4 + qtr] : 0;
    for (int p = e0; p < e1; p += 8) {
        int ia = p + qtr, ib = p + 4 + qtr;
        bool va = ia < e1, vb = ib < e1;
        int sa = src_a, sb = src_b;
        int na = p + 8 + qtr, nb = p + 12 + qtr;
        if (na < e1) src_a = csr_src[na];
        if (nb < e1) src_b = csr_src[nb];
        const uchar_t* kpa = kv8 + (size_t)sa * 256;
        const uchar_t* kpb = kv8 + (size_t)sb * 256;
        uint2 kua = *reinterpret_cast<const uint2*>(kpa + c0);
        uint2 vua = *reinterpret_cast<const uint2*>(kpa + 128 + c0);
        uint2 kub = *reinterpret_cast<const uint2*>(kpb + c0);
        uint2 vub = *reinterpret_cast<const uint2*>(kpb + 128 + c0);
        float2v ka2[4], wa2[4], kb2[4], wb2[4];
        fp8x4_dec2(kua.x, ka2);  fp8x4_dec2(kua.y, ka2 + 2);
        fp8x4_dec2(kub.x, kb2);  fp8x4_dec2(kub.y, kb2 + 2);
        fp8x4_dec2(vua.x, wa2);  fp8x4_dec2(vua.y, wa2 + 2);
        fp8x4_dec2(vub.x, wb2);  fp8x4_dec2(vub.y, wb2 + 2);
        float2v da2 = q2[0] * ka2[0];
        float2v db2 = q2[0] * kb2[0];
        da2 += q2[1] * ka2[1];  db2 += q2[1] * kb2[1];
        da2 += q2[2] * ka2[2];  db2 += q2[2] * kb2[2];
        da2 += q2[3] * ka2[3];  db2 += q2[3] * kb2[3];
        float da = da2.x + da2.y;
        float db = db2.x + db2.y;
        da += __shfl_xor(da, 1);  db += __shfl_xor(db, 1);
        da += __shfl_xor(da, 2);  db += __shfl_xor(db, 2);
        da += __shfl_xor(da, 4);  db += __shfl_xor(db, 4);
        float pea = va ? __expf(da) : 0.f;
        float peb = vb ? __expf(db) : 0.f;
        l += pea + peb;
        float2v pa; pa.x = pea; pa.y = pea;
        float2v pb; pb.x = peb; pb.y = peb;
        #pragma unroll
        for (int i = 0; i < 4; i++) {
            o2[i] += pa * wa2[i];
            o2[i] += pb * wb2[i];
        }
    }
    #pragma unroll
    for (int offx = 16; offx <= 32; offx <<= 1) {
        l += __shfl_xor(l, offx);
        #pragma unroll
        for (int i = 0; i < 4; i++) {
            o2[i].x += __shfl_xor(o2[i].x, offx);
            o2[i].y += __shfl_xor(o2[i].y, offx);
        }
    }

    if (qtr == 0) {
        float inv = 1.f / (l + 1e-16f);
        float o[8] = {o2[0].x, o2[0].y, o2[1].x, o2[1].y,
                      o2[2].x, o2[2].y, o2[3].x, o2[3].y};
        float sv[8];
        {
            uint4 su = *reinterpret_cast<const uint4*>(row_qs + 128 + c0);
            sv[0] = bf2f(su.x & 0xffff); sv[1] = bf2f(su.x >> 16);
            sv[2] = bf2f(su.y & 0xffff); sv[3] = bf2f(su.y >> 16);
            sv[4] = bf2f(su.z & 0xffff); sv[5] = bf2f(su.z >> 16);
            sv[6] = bf2f(su.w & 0xffff); sv[7] = bf2f(su.w >> 16);
        }
        float gv[8], bv[8], mv[8], vr[8];
        *reinterpret_cast<float4*>(gv)     = *reinterpret_cast<const float4*>(bng + c0);
        *reinterpret_cast<float4*>(gv + 4) = *reinterpret_cast<const float4*>(bng + c0 + 4);
        *reinterpret_cast<float4*>(bv)     = *reinterpret_cast<const float4*>(bnb + c0);
        *reinterpret_cast<float4*>(bv + 4) = *reinterpret_cast<const float4*>(bnb + c0 + 4);
        *reinterpret_cast<float4*>(mv)     = *reinterpret_cast<const float4*>(bnm + c0);
        *reinterpret_cast<float4*>(mv + 4) = *reinterpret_cast<const float4*>(bnm + c0 + 4);
        *reinterpret_cast<float4*>(vr)     = *reinterpret_cast<const float4*>(bnv + c0);
        *reinterpret_cast<float4*>(vr + 4) = *reinterpret_cast<const float4*>(bnv + c0 + 4);
        uint_t hw[4];
        #pragma unroll
        for (int i = 0; i < 8; i++) {
            float val = fmaxf(o[i] * inv + sv[i], 0.f);
            val = (val - mv[i]) * rsqrtf(vr[i] + 1e-5f) * gv[i] + bv[i];
            val = fmaxf(val, 0.f);
            ushort_t hb = f2bf(val);
            if (i & 1) hw[i >> 1] |= (uint_t)hb << 16;
            else       hw[i >> 1] = hb;
        }
        int rt = n >> 4, mnode = n & 15;
        int kt = s16 >> 2, qd = s16 & 3;
        size_t fidx = (size_t)rt * 2048 + kt * 512 + (mnode + 16 * qd) * 8;
        uint4 hp; hp.x = hw[0]; hp.y = hw[1]; hp.z = hw[2]; hp.w = hw[3];
        *reinterpret_cast<uint4*>(h + fidx) = hp;
    }
}

// ---------- global mean pool: coalesced fragment reads + LDS accumulate ----
// one block per 4 row-tiles (64 nodes); batch sorted -> <=4 graphs per block.
__global__ __launch_bounds__(256) void pool_kernel(
    const ushort_t* __restrict__ h, const int* __restrict__ batch,
    float* __restrict__ sums, float* __restrict__ cnt) {
    __shared__ float lsum[4][128];
    __shared__ int sbatch[64];
    __shared__ int lcnt4[4];
    __shared__ int gmin_s;
    int t = threadIdx.x;
    int rtbase = blockIdx.x * 4;
    int nbase = rtbase * 16;
    for (int i = t; i < 512; i += 256) ((float*)lsum)[i] = 0.f;
    if (t < 4) lcnt4[t] = 0;
    if (t < 64) {
        int n = nbase + t;
        sbatch[t] = (n < N_NODES) ? batch[n] : -1;
    }
    __syncthreads();
    if (t == 0) gmin_s = sbatch[0];
    __syncthreads();
    int gmin = gmin_s;
    if (t < 64 && sbatch[t] >= 0) {
        int gi = sbatch[t] - gmin;
        gi = (gi < 0) ? 0 : (gi > 3 ? 3 : gi);
        atomicAdd(&lcnt4[gi], 1);
    }
    #pragma unroll
    for (int li = 0; li < 4; li++) {
        int flat = li * 256 + t;          // 0..1023 uint4 slots
        int rtl = flat >> 8;              // 0..3
        int rt = rtbase + rtl;
        if (rt >= N_RT) continue;
        int w = flat & 255;
        int lane = w & 63;
        int kt = w >> 6;
        const ushort_t* p = h + (size_t)rt * 2048 + (size_t)w * 8;
        uint4 d = *reinterpret_cast<const uint4*>(p);
        int node_l = rtl * 16 + (lane & 15);
        int gi = sbatch[node_l] - gmin;
        gi = (gi < 0) ? 0 : (gi > 3 ? 3 : gi);
        int cb = kt * 32 + (lane >> 4) * 8;
        atomicAdd(&lsum[gi][cb + 0], bf2f(d.x & 0xffff));
        atomicAdd(&lsum[gi][cb + 1], bf2f(d.x >> 16));
        atomicAdd(&lsum[gi][cb + 2], bf2f(d.y & 0xffff));
        atomicAdd(&lsum[gi][cb + 3], bf2f(d.y >> 16));
        atomicAdd(&lsum[gi][cb + 4], bf2f(d.z & 0xffff));
        atomicAdd(&lsum[gi][cb + 5], bf2f(d.z >> 16));
        atomicAdd(&lsum[gi][cb + 6], bf2f(d.w & 0xffff));
        atomicAdd(&lsum[gi][cb + 7], bf2f(d.w >> 16));
    }
    __syncthreads();
    int gi = t >> 7;       // 0..1
    int c = t & 127;
    #pragma unroll
    for (int rep = 0; rep < 2; rep++) {
        int g2 = gi + rep * 2;
        int g = gmin + g2;
        if (g >= 0 && g < NGRAPH) {
            float v = lsum[g2][c];
            if (v != 0.f) atomicAdd(&sums[g * 128 + c], v);
            if (c == 0 && lcnt4[g2] > 0) atomicAdd(&cnt[g], (float)lcnt4[g2]);
        }
    }
}

// ---------- final head: gbuf@Wfus[0:128] + fusdoc -> relu -> task/time -----
__global__ __launch_bounds__(128) void final_mlp(
    const float* __restrict__ sums, const float* __restrict__ cnt,
    const float* __restrict__ fusdoc, const float* __restrict__ Wfus,
    const float* __restrict__ Wtask, const float* __restrict__ btask,
    const float* __restrict__ Wtime, const float* __restrict__ btime,
    float* __restrict__ out) {
    int b = blockIdx.x;
    int t = threadIdx.x;
    __shared__ float gbuf[128], fbuf[128];
    float c = fmaxf(cnt[b], 1.0f);
    gbuf[t] = sums[b * 128 + t] / c;
    __syncthreads();
    float f = fusdoc[b * 128 + t];
    #pragma unroll 8
    for (int k = 0; k < 128; k++) f += gbuf[k] * Wfus[(size_t)k * 128 + t];
    fbuf[t] = fmaxf(f, 0.f);
    __syncthreads();
    if (t < 16) {
        float a = btask[t];
        #pragma unroll 8
        for (int k = 0; k < 128; k++) a += fbuf[k] * Wtask[k * 16 + t];
        out[b * 16 + t] = a;
    } else if (t == 16) {
        float a = btime[0];
        #pragma unroll 8
        for (int k = 0; k < 128; k++) a += fbuf[k] * Wtime[k];
        out[NGRAPH * 16 + b] = a;
    }
}

extern "C" void kernel_launch(void* const* d_in, const int* in_sizes, int n_in,
                              void* d_out, int out_size, void* d_ws, size_t ws_size,
                              hipStream_t stream) {
    (void)in_sizes; (void)n_in; (void)out_size; (void)ws_size;
    const float* x    = (const float*)d_in[0];
    const int*   ei   = (const int*)d_in[1];
    const int*   batch= (const int*)d_in[2];
    const float* ts   = (const float*)d_in[3];
    const float* doc  = (const float*)d_in[4];
    const float* Wq1  = (const float*)d_in[5];
    const float* bq1  = (const float*)d_in[6];
    const float* Wk1  = (const float*)d_in[7];
    const float* bk1  = (const float*)d_in[8];
    const float* Wv1  = (const float*)d_in[9];
    const float* bv1  = (const float*)d_in[10];
    const float* Ws1  = (const float*)d_in[11];
    const float* bs1  = (const float*)d_in[12];
    const float* Wq2  = (const float*)d_in[13];
    const float* bq2  = (const float*)d_in[14];
    const float* Wk2  = (const float*)d_in[15];
    const float* bk2  = (const float*)d_in[16];
    const float* Wv2  = (const float*)d_in[17];
    const float* bv2  = (const float*)d_in[18];
    const float* Ws2  = (const float*)d_in[19];
    const float* bs2  = (const float*)d_in[20];
    const float* bn1g = (const float*)d_in[21];
    const float* bn1b = (const float*)d_in[22];
    const float* bn1m = (const float*)d_in[23];
    const float* bn1v = (const float*)d_in[24];
    const float* bn2g = (const float*)d_in[25];
    const float* bn2b = (const float*)d_in[26];
    const float* bn2m = (const float*)d_in[27];
    const float* bn2v = (const float*)d_in[28];
    const float* Wdoc = (const float*)d_in[29];
    const float* bdoc = (const float*)d_in[30];
    const float* Wfus = (const float*)d_in[31];
    const float* bfus = (const float*)d_in[32];
    const float* Wtask= (const float*)d_in[33];
    const float* btask= (const float*)d_in[34];
    const float* Wtime= (const float*)d_in[35];
    const float* btime= (const float*)d_in[36];

    char* ws = (char*)d_ws;
    ushort_t* h      = (ushort_t*)(ws + 0);           // 12.8 MB
    ushort_t* qsb    = (ushort_t*)(ws + 12800000);    // 25.6 MB
    uchar_t*  kv8    = (uchar_t*)(ws + 38400000);     // 12.8 MB
    ushort_t* WF     = (ushort_t*)(ws + 51200000);    // 256 KB
    float*    biasc  = (float*)(ws + 51462144);       // 4 KB
    float*    sums   = (float*)(ws + 51466240);       // 32768 B
    float*    cnt    = (float*)(ws + 51499008);       // 256 B
    int*      off    = (int*)(ws + 51499264);         // 200004 B
    int*      bucketcur = (int*)(ws + 51699268);      // 784 B
    int*      arena  = (int*)(ws + 51700052);         // 196*8192*4 = 6.42 MB
    int*      csr    = (int*)(ws + 58122580);         // 3.2 MB
    float*    docemb = (float*)(ws + 61322580);       // 32 KB
    float*    fusdoc = (float*)(ws + 61355348);       // 32 KB

    float* out = (float*)d_out;

    hipMemsetAsync(bucketcur, 0, 784, stream);

    prep_kernel<<<NBKT + NB_TEMP + NB_WS + NGRAPH, 256, 0, stream>>>(
        ei, bucketcur, arena, x, ts, h,
        Wq1, Wk1, Wv1, Ws1, Wq2, Wk2, Wv2, Ws2,
        bq1, bk1, bv1, bs1, bq2, bk2, bv2, bs2, WF, biasc,
        doc, Wdoc, bdoc, docemb, sums, cnt);

    const size_t WF_LAYER = 65536;  // shorts per layer

    // ---- layer 1 (gemm fused with passB(off+csr) + fusdoc) ----
    g1_kernel<<<NBKT + NB_GEMM + NGRAPH, 256, 0, stream>>>(
        off, arena, bucketcur, csr, h, WF, biasc, qsb, kv8,
        docemb, Wfus, bfus, fusdoc);
    node_attn_bn<<<12500, 256, 0, stream>>>(off, csr, qsb, kv8, bn1g, bn1b, bn1m, bn1v, h);

    // ---- layer 2 ----
    gemm_qkvs<<<dim3(391, 4), 256, 0, stream>>>(h, WF + WF_LAYER, biasc + 512, qsb, kv8);
    node_attn_bn<<<12500, 256, 0, stream>>>(off, csr, qsb, kv8, bn2g, bn2b, bn2m, bn2v, h);

    // ---- pool + final head ----
    pool_kernel<<<NB_POOL, 256, 0, stream>>>(h, batch, sums, cnt);
    final_mlp<<<NGRAPH, 128, 0, stream>>>(sums, cnt, fusdoc, Wfus,
                                          Wtask, btask, Wtime, btime, out);
}

// Round 16
// 357.931 us; speedup vs baseline: 1.1135x; 1.0158x over previous
//
#include <hip/hip_runtime.h>

typedef unsigned short ushort_t;
typedef unsigned int uint_t;
typedef unsigned char uchar_t;
typedef unsigned long long ull_t;

#define N_NODES 50000
#define N_EDGES 800000
#define HID 128
#define NGRAPH 64
#define N_RT 3125     // row tiles of 16 nodes
#define NBKT 196      // coarse buckets of 256 nodes
#define CHUNK 4096    // edges per pass-A block
#define NB_TEMP 12500 // temporal blocks (x512 elems)
#define NB_WS 512     // wsplit blocks
#define NB_GEMM 1564  // 4*391
#define BCAP 6144     // passB LDS stage capacity (mean 4096 + 32 sigma)
#define BMAX 8192     // arena slot per bucket (mean + 64 sigma)
#define NB_POOL 98
#define RT_PER_BLK 32

typedef __attribute__((ext_vector_type(8))) short short8;
typedef __attribute__((ext_vector_type(4))) float float4v;
typedef __attribute__((ext_vector_type(2))) float float2v;

// ---------- bf16 helpers ----------
__device__ __forceinline__ float bf2f(uint_t u) {
    union { uint_t i; float f; } v; v.i = u << 16; return v.f;
}
__device__ __forceinline__ ushort_t f2bf(float f) {
    union { float f; uint_t i; } v; v.f = f;
    uint_t r = v.i + 0x7FFFu + ((v.i >> 16) & 1u);
    return (ushort_t)(r >> 16);
}

// ---------- fp8 e4m3 helpers ----------
#if __has_builtin(__builtin_amdgcn_cvt_pk_fp8_f32) && __has_builtin(__builtin_amdgcn_cvt_pk_f32_fp8)
#define HAS_FP8_CVT 1
#else
#define HAS_FP8_CVT 0
#endif

__device__ __forceinline__ uchar_t f2fp8(float x) {
#if HAS_FP8_CVT
    int p = __builtin_amdgcn_cvt_pk_fp8_f32(x, x, 0, false);
    return (uchar_t)(p & 0xFF);
#else
    union { float f; uint_t u; } v; v.f = x;
    uint_t s = (v.u >> 31) << 7;
    float a = fabsf(x);
    a = fminf(a, 448.f);
    if (a < 0.015625f) {
        int m3 = (int)(a * 512.f + 0.5f);
        return (uchar_t)(s | (uint_t)m3);
    }
    v.f = a;
    uint_t r = v.u + 0x7FFFFu + ((v.u >> 20) & 1u);
    uint_t e = r >> 23;
    return (uchar_t)(s | ((e - 120u) << 3) | ((r >> 20) & 7u));
#endif
}

__device__ __forceinline__ float fp8dec1(uint_t b) {
    uint_t e = (b >> 3) & 15u, mnt = b & 7u;
    union { uint_t u; float f; } v;
    v.u = ((e + 120u) << 23) | (mnt << 20);
    float mag = e ? v.f : (float)mnt * 0.001953125f;  // 2^-9
    return (b & 0x80u) ? -mag : mag;
}

__device__ __forceinline__ void fp8x4_dec2(uint_t w, float2v* o) {
#if HAS_FP8_CVT
    o[0] = __builtin_amdgcn_cvt_pk_f32_fp8(w, false);
    o[1] = __builtin_amdgcn_cvt_pk_f32_fp8(w, true);
#else
    float2v a, b;
    a.x = fp8dec1(w & 0xFFu);  a.y = fp8dec1((w >> 8) & 0xFFu);
    b.x = fp8dec1((w >> 16) & 0xFFu); b.y = fp8dec1(w >> 24);
    o[0] = a; o[1] = b;
#endif
}

// ---------- prep mega-kernel: passA + temporal + wsplit + docemb ------------
__global__ __launch_bounds__(256) void prep_kernel(
    const int* __restrict__ ei,
    int* __restrict__ bucketcur, int* __restrict__ arena,
    const float* __restrict__ x, const float* __restrict__ ts,
    ushort_t* __restrict__ h,
    const float* __restrict__ Wq1, const float* __restrict__ Wk1,
    const float* __restrict__ Wv1, const float* __restrict__ Ws1,
    const float* __restrict__ Wq2, const float* __restrict__ Wk2,
    const float* __restrict__ Wv2, const float* __restrict__ Ws2,
    const float* __restrict__ bq1, const float* __restrict__ bk1,
    const float* __restrict__ bv1, const float* __restrict__ bs1,
    const float* __restrict__ bq2, const float* __restrict__ bk2,
    const float* __restrict__ bv2, const float* __restrict__ bs2,
    ushort_t* __restrict__ WF, float* __restrict__ bias_cat,
    const float* __restrict__ doc, const float* __restrict__ Wdoc,
    const float* __restrict__ bdoc, float* __restrict__ docemb,
    float* __restrict__ sums, float* __restrict__ cnt) {
    __shared__ int hist[NBKT];
    __shared__ int lofs[NBKT];
    __shared__ int lcur[NBKT];
    __shared__ int gbase[NBKT];
    __shared__ int sbuf[256];
    __shared__ uint_t staging[CHUNK];
    __shared__ int tot_s;

    int blk = blockIdx.x;
    int t = threadIdx.x;

    if (blk < NBKT) {
        // ---------------- pass A ----------------
        if (t < NBKT) hist[t] = 0;
        __syncthreads();
        int e0 = blk * CHUNK;
        int srcs[16], dsts[16];
        #pragma unroll
        for (int i = 0; i < 16; i++) {
            int idx = e0 + i * 256 + t;
            bool v = idx < N_EDGES;
            srcs[i] = v ? ei[idx] : -1;
            dsts[i] = v ? ei[N_EDGES + idx] : -1;
            if (v) atomicAdd(&hist[dsts[i] >> 8], 1);
        }
        __syncthreads();
        int hv = (t < NBKT) ? hist[t] : 0;
        sbuf[t] = hv;
        __syncthreads();
        #pragma unroll
        for (int s = 1; s < 256; s <<= 1) {
            int add = (t >= s) ? sbuf[t - s] : 0;
            __syncthreads();
            sbuf[t] += add;
            __syncthreads();
        }
        if (t < NBKT) {
            lofs[t] = sbuf[t] - hv;
            lcur[t] = sbuf[t] - hv;
        }
        if (t == NBKT - 1) tot_s = sbuf[NBKT - 1];
        __syncthreads();
        #pragma unroll
        for (int i = 0; i < 16; i++) {
            if (srcs[i] >= 0) {
                int bkt = dsts[i] >> 8;
                int pos = atomicAdd(&lcur[bkt], 1);
                staging[pos] = ((uint_t)bkt << 24) | ((uint_t)(dsts[i] & 255) << 16)
                             | (uint_t)srcs[i];
            }
        }
        __syncthreads();
        if (t < NBKT) {
            int hcnt = hist[t];
            gbase[t] = t * BMAX + (hcnt ? atomicAdd(&bucketcur[t], hcnt) : 0);
        }
        __syncthreads();
        int tot = tot_s;
        for (int i = t; i < tot; i += 256) {
            uint_t e = staging[i];
            int bkt = e >> 24;
            arena[gbase[bkt] + (i - lofs[bkt])] = (int)(e & 0xFFFFFF);
        }
    } else if (blk < NBKT + NB_TEMP) {
        // ---------------- temporal ----------------
        int base = (blk - NBKT) * 512;
        #pragma unroll
        for (int u = 0; u < 2; u++) {
            int tid = base + u * 256 + t;
            int rt   = tid >> 11;
            int kt   = (tid >> 9) & 3;
            int lane = (tid >> 3) & 63;
            int j    = tid & 7;
            int n = rt * 16 + (lane & 15);
            int c = kt * 32 + (lane >> 4) * 8 + j;
            float tv = ts[n];
            const float coef = -0.07195570687f;  // -ln(10000)/128
            float ang = tv * __expf((float)(c & ~1) * coef);
            float pe = (c & 1) ? __cosf(ang) : __sinf(ang);
            h[tid] = f2bf(x[n * 128 + c] + pe);
        }
    } else if (blk < NBKT + NB_TEMP + NB_WS) {
        // ---------------- wsplit ----------------
        int tid = (blk - NBKT - NB_TEMP) * 256 + t;  // 0..131071
        int j    = tid & 7;
        int lane = (tid >> 3) & 63;
        int kt   = (tid >> 9) & 3;
        int cgy  = (tid >> 11) & 31;
        int L    = tid >> 16;
        int col = cgy * 16 + (lane & 15);
        int k   = kt * 32 + (lane >> 4) * 8 + j;
        int mat = col >> 7, c = col & 127;
        const float* W = (L == 0)
            ? ((mat == 0) ? Wq1 : (mat == 1) ? Wk1 : (mat == 2) ? Wv1 : Ws1)
            : ((mat == 0) ? Wq2 : (mat == 1) ? Wk2 : (mat == 2) ? Wv2 : Ws2);
        size_t base = (size_t)L * 65536 + (size_t)cgy * 2048 + (size_t)kt * 512;
        WF[base + lane * 8 + j] = f2bf(W[k * 128 + c]);
        if (kt == 0 && (lane >> 4) == 0 && j == 0) {
            const float* b = (L == 0)
                ? ((mat == 0) ? bq1 : (mat == 1) ? bk1 : (mat == 2) ? bv1 : bs1)
                : ((mat == 0) ? bq2 : (mat == 1) ? bk2 : (mat == 2) ? bv2 : bs2);
            bias_cat[L * 512 + col] = b[c];
        }
    } else {
        // ---------------- docemb + zero pool accumulators ----------------
        int b = blk - NBKT - NB_TEMP - NB_WS;   // 0..63
        int c = t & 127, half = t >> 7;
        if (t < 128) sums[b * 128 + t] = 0.f;
        if (t == 128) cnt[b] = 0.f;
        float* red = (float*)staging;           // reuse LDS
        float acc = (half == 0) ? bdoc[c] : 0.f;
        int k0 = half * 256;
        #pragma unroll 8
        for (int k = 0; k < 256; k++)
            acc += doc[b * 512 + k0 + k] * Wdoc[(size_t)(k0 + k) * 128 + c];
        red[t] = acc;
        __syncthreads();
        if (t < 128) docemb[b * 128 + c] = fmaxf(red[t] + red[t + 128], 0.f);
    }
}

// ---------- shared gemm body ----------
__device__ __forceinline__ void gemm_body(
    int rp, int cg0, int lane, int quad, int m,
    const ushort_t* __restrict__ hf, const ushort_t* __restrict__ WF,
    const float* __restrict__ bias_cat,
    ushort_t* __restrict__ qsb, uchar_t* __restrict__ kv8) {
    int rt0 = rp * 2;
    if (rt0 >= N_RT) return;
    int rt1 = rt0 + 1;
    int rt1c = (rt1 < N_RT) ? rt1 : rt0;

    short8 a0[4], a1[4];
    {
        const ushort_t* b0 = hf + (size_t)rt0 * 2048 + lane * 8;
        const ushort_t* b1 = hf + (size_t)rt1c * 2048 + lane * 8;
        #pragma unroll
        for (int kt = 0; kt < 4; kt++) {
            a0[kt] = *reinterpret_cast<const short8*>(b0 + kt * 512);
            a1[kt] = *reinterpret_cast<const short8*>(b1 + kt * 512);
        }
    }

    const ushort_t* wfl = WF + (size_t)cg0 * 2048 + lane * 8;
    #pragma unroll 2
    for (int cg = 0; cg < 8; cg++) {
        const ushort_t* fp = wfl + (size_t)cg * 2048;
        float4v acc0 = {0.f, 0.f, 0.f, 0.f};
        float4v acc1 = {0.f, 0.f, 0.f, 0.f};
        #pragma unroll
        for (int kt = 0; kt < 4; kt++) {
            short8 bh = *reinterpret_cast<const short8*>(fp + kt * 512);
            acc0 = __builtin_amdgcn_mfma_f32_16x16x32_bf16(a0[kt], bh, acc0, 0, 0, 0);
            acc1 = __builtin_amdgcn_mfma_f32_16x16x32_bf16(a1[kt], bh, acc1, 0, 0, 0);
        }
        int col = (cg0 + cg) * 16 + m;
        float bias = bias_cat[col];
        int mat = col >> 7;
        #pragma unroll
        for (int r = 0; r < 4; r++) {
            float v0 = acc0[r] + bias;
            size_t row0 = (size_t)rt0 * 16 + quad * 4 + r;
            if (mat == 0)      qsb[row0 * 256 + col] = f2bf(v0);
            else if (mat == 3) qsb[row0 * 256 + (col - 256)] = f2bf(v0);
            else               kv8[row0 * 256 + (col - 128)] = f2fp8(v0);
        }
        if (rt1 < N_RT) {
            #pragma unroll
            for (int r = 0; r < 4; r++) {
                float v1 = acc1[r] + bias;
                size_t row1 = (size_t)rt1 * 16 + quad * 4 + r;
                if (mat == 0)      qsb[row1 * 256 + col] = f2bf(v1);
                else if (mat == 3) qsb[row1 * 256 + (col - 256)] = f2bf(v1);
                else               kv8[row1 * 256 + (col - 128)] = f2fp8(v1);
            }
        }
    }
}

// ---------- fused: passB (off+csr build) + gemm L1 + fusdoc -----------------
__global__ __launch_bounds__(256) void g1_kernel(
    int* __restrict__ off, const int* __restrict__ arena,
    const int* __restrict__ bucketcur, int* __restrict__ csr,
    const ushort_t* __restrict__ hf, const ushort_t* __restrict__ WF,
    const float* __restrict__ bias_cat,
    ushort_t* __restrict__ qsb, uchar_t* __restrict__ kv8,
    const float* __restrict__ docemb, const float* __restrict__ Wfus,
    const float* __restrict__ bfus, float* __restrict__ fusdoc) {
    __shared__ uint_t smem[BCAP + 1024];
    __shared__ int bbase_s;
    int blk = blockIdx.x;
    int t = threadIdx.x;
    if (blk < NBKT) {
        // ---- passB: derive off[] + exact csr from arena bucket ----
        uint_t* stage = smem;
        int* lcnt = (int*)(smem + BCAP);
        int* exc  = (int*)(smem + BCAP + 256);
        int* lcur = (int*)(smem + BCAP + 512);
        int* sb   = (int*)(smem + BCAP + 768);
        int bc = (t < NBKT) ? bucketcur[t] : 0;
        sb[t] = bc;
        __syncthreads();
        #pragma unroll
        for (int s = 1; s < 256; s <<= 1) {
            int a = (t >= s) ? sb[t - s] : 0;
            __syncthreads();
            sb[t] += a;
            __syncthreads();
        }
        if (t == 0) bbase_s = (blk == 0) ? 0 : sb[blk - 1];
        lcnt[t] = 0; lcur[t] = 0;
        __syncthreads();
        int bbase = bbase_s;
        int size = bucketcur[blk];
        int abase = blk * BMAX;
        int lim = (size < BCAP) ? size : BCAP;
        for (int i = t; i < lim; i += 256) stage[i] = (uint_t)arena[abase + i];
        __syncthreads();
        for (int i = t; i < size; i += 256) {
            uint_t e = (i < BCAP) ? stage[i] : (uint_t)arena[abase + i];
            atomicAdd(&lcnt[(e >> 16) & 255], 1);
        }
        __syncthreads();
        int v = lcnt[t];
        sb[t] = v;
        __syncthreads();
        #pragma unroll
        for (int s = 1; s < 256; s <<= 1) {
            int a = (t >= s) ? sb[t - s] : 0;
            __syncthreads();
            sb[t] += a;
            __syncthreads();
        }
        exc[t] = sb[t] - v;
        int n0 = blk * 256;
        if (n0 + t < N_NODES) off[n0 + t] = bbase + sb[t] - v;
        if (blk == NBKT - 1 && t == 0) off[N_NODES] = N_EDGES;
        __syncthreads();
        for (int i = t; i < size; i += 256) {
            uint_t e = (i < BCAP) ? stage[i] : (uint_t)arena[abase + i];
            int dlow = (e >> 16) & 255;
            int src = (int)(e & 0xFFFF);
            int pos = exc[dlow] + atomicAdd(&lcur[dlow], 1);
            csr[bbase + pos] = src;
        }
    } else if (blk < NBKT + NB_GEMM) {
        int blk2 = blk - NBKT;           // 0..1563
        int y = blk2 / 391, bx = blk2 % 391;
        int wave = t >> 6, lane = t & 63;
        gemm_body(bx * 4 + wave, y * 8, lane, lane >> 4, lane & 15,
                  hf, WF, bias_cat, qsb, kv8);
    } else {
        // ---- fusdoc[b][c] = bfus[c] + docemb[b] @ Wfus[128:256] ----
        int b = blk - NBKT - NB_GEMM;    // 0..63
        int c = t & 127, half = t >> 7;
        float* de = (float*)smem;
        float* red = (float*)smem + 128;
        if (t < 128) de[t] = docemb[b * 128 + t];
        __syncthreads();
        float acc = (half == 0) ? bfus[c] : 0.f;
        int k0 = half * 64;
        #pragma unroll 8
        for (int k = 0; k < 64; k++)
            acc += de[k0 + k] * Wfus[(size_t)(128 + k0 + k) * 128 + c];
        red[t] = acc;
        __syncthreads();
        if (t < 128) fusdoc[b * 128 + c] = red[t] + red[t + 128];
    }
}

// ---------- plain gemm (layer 2) ----------
__global__ __launch_bounds__(256) void gemm_qkvs(
    const ushort_t* __restrict__ hf,
    const ushort_t* __restrict__ WF,
    const float* __restrict__ bias_cat,
    ushort_t* __restrict__ qsb, uchar_t* __restrict__ kv8) {
    int t = threadIdx.x;
    int wave = t >> 6, lane = t & 63;
    gemm_body(blockIdx.x * 4 + wave, blockIdx.y * 8, lane, lane >> 4, lane & 15,
              hf, WF, bias_cat, qsb, kv8);
}

// ---------- fused per-node attention + skip + BN + relu -> h (frag-major) ----
__global__ __launch_bounds__(256) void node_attn_bn(
    const int* __restrict__ off, const int* __restrict__ csr_src,
    const ushort_t* __restrict__ qsb, const uchar_t* __restrict__ kv8,
    const float* __restrict__ bng, const float* __restrict__ bnb,
    const float* __restrict__ bnm, const float* __restrict__ bnv,
    ushort_t* __restrict__ h) {
    int wave = threadIdx.x >> 6;
    int n = blockIdx.x * 4 + wave;
    if (n >= N_NODES) return;
    int lane = threadIdx.x & 63;
    int qtr = lane >> 4, s16 = lane & 15;
    int c0 = s16 * 8;

    const ushort_t* row_qs = qsb + (size_t)n * 256;
    float2v q2[4];
    {
        uint4 qu = *reinterpret_cast<const uint4*>(row_qs + c0);
        q2[0].x = bf2f(qu.x & 0xffff) * 0.125f; q2[0].y = bf2f(qu.x >> 16) * 0.125f;
        q2[1].x = bf2f(qu.y & 0xffff) * 0.125f; q2[1].y = bf2f(qu.y >> 16) * 0.125f;
        q2[2].x = bf2f(qu.z & 0xffff) * 0.125f; q2[2].y = bf2f(qu.z >> 16) * 0.125f;
        q2[3].x = bf2f(qu.w & 0xffff) * 0.125f; q2[3].y = bf2f(qu.w >> 16) * 0.125f;
    }

    int e0 = off[n], e1 = off[n + 1];
    float l = 0.f;
    float2v o2[4];
    o2[0] = (float2v){0.f, 0.f}; o2[1] = (float2v){0.f, 0.f};
    o2[2] = (float2v){0.f, 0.f}; o2[3] = (float2v){0.f, 0.f};

    int src_a = (e0 + qtr < e1) ? csr_src[e0 + qtr] : 0;
    int src_b = (e0 + 4 + qtr < e1) ? csr_src[e0 + 4 + qtr] : 0;
    for (int p = e0; p < e1; p += 8) {
        int ia = p + qtr, ib = p + 4 + qtr;
        bool va = ia < e1, vb = ib < e1;
        int sa = src_a, sb = src_b;
        int na = p + 8 + qtr, nb = p + 12 + qtr;
        if (na < e1) src_a = csr_src[na];
        if (nb < e1) src_b = csr_src[nb];
        const uchar_t* kpa = kv8 + (size_t)sa * 256;
        const uchar_t* kpb = kv8 + (size_t)sb * 256;
        uint2 kua = *reinterpret_cast<const uint2*>(kpa + c0);
        uint2 vua = *reinterpret_cast<const uint2*>(kpa + 128 + c0);
        uint2 kub = *reinterpret_cast<const uint2*>(kpb + c0);
        uint2 vub = *reinterpret_cast<const uint2*>(kpb + 128 + c0);
        float2v ka2[4], wa2[4], kb2[4], wb2[4];
        fp8x4_dec2(kua.x, ka2);  fp8x4_dec2(kua.y, ka2 + 2);
        fp8x4_dec2(kub.x, kb2);  fp8x4_dec2(kub.y, kb2 + 2);
        fp8x4_dec2(vua.x, wa2);  fp8x4_dec2(vua.y, wa2 + 2);
        fp8x4_dec2(vub.x, wb2);  fp8x4_dec2(vub.y, wb2 + 2);
        float2v da2 = q2[0] * ka2[0];
        float2v db2 = q2[0] * kb2[0];
        da2 += q2[1] * ka2[1];  db2 += q2[1] * kb2[1];
        da2 += q2[2] * ka2[2];  db2 += q2[2] * kb2[2];
        da2 += q2[3] * ka2[3];  db2 += q2[3] * kb2[3];
        float da = da2.x + da2.y;
        float db = db2.x + db2.y;
        da += __shfl_xor(da, 1);  db += __shfl_xor(db, 1);
        da += __shfl_xor(da, 2);  db += __shfl_xor(db, 2);
        da += __shfl_xor(da, 4);  db += __shfl_xor(db, 4);
        float pea = va ? __expf(da) : 0.f;
        float peb = vb ? __expf(db) : 0.f;
        l += pea + peb;
        float2v pa; pa.x = pea; pa.y = pea;
        float2v pb; pb.x = peb; pb.y = peb;
        #pragma unroll
        for (int i = 0; i < 4; i++) {
            o2[i] += pa * wa2[i];
            o2[i] += pb * wb2[i];
        }
    }
    #pragma unroll
    for (int offx = 16; offx <= 32; offx <<= 1) {
        l += __shfl_xor(l, offx);
        #pragma unroll
        for (int i = 0; i < 4; i++) {
            o2[i].x += __shfl_xor(o2[i].x, offx);
            o2[i].y += __shfl_xor(o2[i].y, offx);
        }
    }

    if (qtr == 0) {
        float inv = 1.f / (l + 1e-16f);
        float o[8] = {o2[0].x, o2[0].y, o2[1].x, o2[1].y,
                      o2[2].x, o2[2].y, o2[3].x, o2[3].y};
        float sv[8];
        {
            uint4 su = *reinterpret_cast<const uint4*>(row_qs + 128 + c0);
            sv[0] = bf2f(su.x & 0xffff); sv[1] = bf2f(su.x >> 16);
            sv[2] = bf2f(su.y & 0xffff); sv[3] = bf2f(su.y >> 16);
            sv[4] = bf2f(su.z & 0xffff); sv[5] = bf2f(su.z >> 16);
            sv[6] = bf2f(su.w & 0xffff); sv[7] = bf2f(su.w >> 16);
        }
        float gv[8], bv[8], mv[8], vr[8];
        *reinterpret_cast<float4*>(gv)     = *reinterpret_cast<const float4*>(bng + c0);
        *reinterpret_cast<float4*>(gv + 4) = *reinterpret_cast<const float4*>(bng + c0 + 4);
        *reinterpret_cast<float4*>(bv)     = *reinterpret_cast<const float4*>(bnb + c0);
        *reinterpret_cast<float4*>(bv + 4) = *reinterpret_cast<const float4*>(bnb + c0 + 4);
        *reinterpret_cast<float4*>(mv)     = *reinterpret_cast<const float4*>(bnm + c0);
        *reinterpret_cast<float4*>(mv + 4) = *reinterpret_cast<const float4*>(bnm + c0 + 4);
        *reinterpret_cast<float4*>(vr)     = *reinterpret_cast<const float4*>(bnv + c0);
        *reinterpret_cast<float4*>(vr + 4) = *reinterpret_cast<const float4*>(bnv + c0 + 4);
        uint_t hw[4];
        #pragma unroll
        for (int i = 0; i < 8; i++) {
            float val = fmaxf(o[i] * inv + sv[i], 0.f);
            val = (val - mv[i]) * rsqrtf(vr[i] + 1e-5f) * gv[i] + bv[i];
            val = fmaxf(val, 0.f);
            ushort_t hb = f2bf(val);
            if (i & 1) hw[i >> 1] |= (uint_t)hb << 16;
            else       hw[i >> 1] = hb;
        }
        int rt = n >> 4, mnode = n & 15;
        int kt = s16 >> 2, qd = s16 & 3;
        size_t fidx = (size_t)rt * 2048 + kt * 512 + (mnode + 16 * qd) * 8;
        uint4 hp; hp.x = hw[0]; hp.y = hw[1]; hp.z = hw[2]; hp.w = hw[3];
        *reinterpret_cast<uint4*>(h + fidx) = hp;
    }
}

// ---------- global mean pool: coalesced reads + register run-length --------
// Thread t owns fragment slot t (channels cb..cb+7, node offset t&15);
// iterates RT_PER_BLK row-tiles: read h[rt*2048 + t*8] (coalesced 2KB/wave).
// batch sorted -> per-thread node sequence monotone in graph: accumulate in
// registers, flush 8 global atomics per graph-run. No LDS, no contention.
__global__ __launch_bounds__(256) void pool_kernel(
    const ushort_t* __restrict__ h, const int* __restrict__ batch,
    float* __restrict__ sums, float* __restrict__ cnt) {
    int t = threadIdx.x;
    int m16 = t & 15;
    int cb = ((t >> 6) & 3) * 32 + ((t >> 4) & 3) * 8;
    int rt0 = blockIdx.x * RT_PER_BLK;
    float acc[8] = {0.f, 0.f, 0.f, 0.f, 0.f, 0.f, 0.f, 0.f};
    float ncnt = 0.f;
    int gcur = -1;
    bool counter = (t < 16);  // exactly one slot per node (kt=0, quad=0)
    for (int i = 0; i < RT_PER_BLK; i++) {
        int rt = rt0 + i;
        if (rt >= N_RT) break;
        int n = rt * 16 + m16;
        int g = batch[n];
        if (g != gcur) {
            if (gcur >= 0) {
                #pragma unroll
                for (int j = 0; j < 8; j++)
                    atomicAdd(&sums[gcur * 128 + cb + j], acc[j]);
                if (counter) atomicAdd(&cnt[gcur], ncnt);
            }
            #pragma unroll
            for (int j = 0; j < 8; j++) acc[j] = 0.f;
            ncnt = 0.f;
            gcur = g;
        }
        uint4 d = *reinterpret_cast<const uint4*>(h + (size_t)rt * 2048 + (size_t)t * 8);
        acc[0] += bf2f(d.x & 0xffff); acc[1] += bf2f(d.x >> 16);
        acc[2] += bf2f(d.y & 0xffff); acc[3] += bf2f(d.y >> 16);
        acc[4] += bf2f(d.z & 0xffff); acc[5] += bf2f(d.z >> 16);
        acc[6] += bf2f(d.w & 0xffff); acc[7] += bf2f(d.w >> 16);
        ncnt += 1.f;
    }
    if (gcur >= 0) {
        #pragma unroll
        for (int j = 0; j < 8; j++)
            atomicAdd(&sums[gcur * 128 + cb + j], acc[j]);
        if (counter) atomicAdd(&cnt[gcur], ncnt);
    }
}

// ---------- final head: gbuf@Wfus[0:128] + fusdoc -> relu -> task/time -----
__global__ __launch_bounds__(128) void final_mlp(
    const float* __restrict__ sums, const float* __restrict__ cnt,
    const float* __restrict__ fusdoc, const float* __restrict__ Wfus,
    const float* __restrict__ Wtask, const float* __restrict__ btask,
    const float* __restrict__ Wtime, const float* __restrict__ btime,
    float* __restrict__ out) {
    int b = blockIdx.x;
    int t = threadIdx.x;
    __shared__ float gbuf[128], fbuf[128];
    float c = fmaxf(cnt[b], 1.0f);
    gbuf[t] = sums[b * 128 + t] / c;
    __syncthreads();
    float f = fusdoc[b * 128 + t];
    #pragma unroll 8
    for (int k = 0; k < 128; k++) f += gbuf[k] * Wfus[(size_t)k * 128 + t];
    fbuf[t] = fmaxf(f, 0.f);
    __syncthreads();
    if (t < 16) {
        float a = btask[t];
        #pragma unroll 8
        for (int k = 0; k < 128; k++) a += fbuf[k] * Wtask[k * 16 + t];
        out[b * 16 + t] = a;
    } else if (t == 16) {
        float a = btime[0];
        #pragma unroll 8
        for (int k = 0; k < 128; k++) a += fbuf[k] * Wtime[k];
        out[NGRAPH * 16 + b] = a;
    }
}

extern "C" void kernel_launch(void* const* d_in, const int* in_sizes, int n_in,
                              void* d_out, int out_size, void* d_ws, size_t ws_size,
                              hipStream_t stream) {
    (void)in_sizes; (void)n_in; (void)out_size; (void)ws_size;
    const float* x    = (const float*)d_in[0];
    const int*   ei   = (const int*)d_in[1];
    const int*   batch= (const int*)d_in[2];
    const float* ts   = (const float*)d_in[3];
    const float* doc  = (const float*)d_in[4];
    const float* Wq1  = (const float*)d_in[5];
    const float* bq1  = (const float*)d_in[6];
    const float* Wk1  = (const float*)d_in[7];
    const float* bk1  = (const float*)d_in[8];
    const float* Wv1  = (const float*)d_in[9];
    const float* bv1  = (const float*)d_in[10];
    const float* Ws1  = (const float*)d_in[11];
    const float* bs1  = (const float*)d_in[12];
    const float* Wq2  = (const float*)d_in[13];
    const float* bq2  = (const float*)d_in[14];
    const float* Wk2  = (const float*)d_in[15];
    const float* bk2  = (const float*)d_in[16];
    const float* Wv2  = (const float*)d_in[17];
    const float* bv2  = (const float*)d_in[18];
    const float* Ws2  = (const float*)d_in[19];
    const float* bs2  = (const float*)d_in[20];
    const float* bn1g = (const float*)d_in[21];
    const float* bn1b = (const float*)d_in[22];
    const float* bn1m = (const float*)d_in[23];
    const float* bn1v = (const float*)d_in[24];
    const float* bn2g = (const float*)d_in[25];
    const float* bn2b = (const float*)d_in[26];
    const float* bn2m = (const float*)d_in[27];
    const float* bn2v = (const float*)d_in[28];
    const float* Wdoc = (const float*)d_in[29];
    const float* bdoc = (const float*)d_in[30];
    const float* Wfus = (const float*)d_in[31];
    const float* bfus = (const float*)d_in[32];
    const float* Wtask= (const float*)d_in[33];
    const float* btask= (const float*)d_in[34];
    const float* Wtime= (const float*)d_in[35];
    const float* btime= (const float*)d_in[36];

    char* ws = (char*)d_ws;
    ushort_t* h      = (ushort_t*)(ws + 0);           // 12.8 MB
    ushort_t* qsb    = (ushort_t*)(ws + 12800000);    // 25.6 MB
    uchar_t*  kv8    = (uchar_t*)(ws + 38400000);     // 12.8 MB
    ushort_t* WF     = (ushort_t*)(ws + 51200000);    // 256 KB
    float*    biasc  = (float*)(ws + 51462144);       // 4 KB
    float*    sums   = (float*)(ws + 51466240);       // 32768 B
    float*    cnt    = (float*)(ws + 51499008);       // 256 B
    int*      off    = (int*)(ws + 51499264);         // 200004 B
    int*      bucketcur = (int*)(ws + 51699268);      // 784 B
    int*      arena  = (int*)(ws + 51700052);         // 196*8192*4 = 6.42 MB
    int*      csr    = (int*)(ws + 58122580);         // 3.2 MB
    float*    docemb = (float*)(ws + 61322580);       // 32 KB
    float*    fusdoc = (float*)(ws + 61355348);       // 32 KB

    float* out = (float*)d_out;

    hipMemsetAsync(bucketcur, 0, 784, stream);

    prep_kernel<<<NBKT + NB_TEMP + NB_WS + NGRAPH, 256, 0, stream>>>(
        ei, bucketcur, arena, x, ts, h,
        Wq1, Wk1, Wv1, Ws1, Wq2, Wk2, Wv2, Ws2,
        bq1, bk1, bv1, bs1, bq2, bk2, bv2, bs2, WF, biasc,
        doc, Wdoc, bdoc, docemb, sums, cnt);

    const size_t WF_LAYER = 65536;  // shorts per layer

    // ---- layer 1 (gemm fused with passB(off+csr) + fusdoc) ----
    g1_kernel<<<NBKT + NB_GEMM + NGRAPH, 256, 0, stream>>>(
        off, arena, bucketcur, csr, h, WF, biasc, qsb, kv8,
        docemb, Wfus, bfus, fusdoc);
    node_attn_bn<<<12500, 256, 0, stream>>>(off, csr, qsb, kv8, bn1g, bn1b, bn1m, bn1v, h);

    // ---- layer 2 ----
    gemm_qkvs<<<dim3(391, 4), 256, 0, stream>>>(h, WF + WF_LAYER, biasc + 512, qsb, kv8);
    node_attn_bn<<<12500, 256, 0, stream>>>(off, csr, qsb, kv8, bn2g, bn2b, bn2m, bn2v, h);

    // ---- pool + final head ----
    pool_kernel<<<NB_POOL, 256, 0, stream>>>(h, batch, sums, cnt);
    final_mlp<<<NGRAPH, 128, 0, stream>>>(sums, cnt, fusdoc, Wfus,
                                          Wtask, btask, Wtime, btime, out);
}

// Round 17
// 333.064 us; speedup vs baseline: 1.1967x; 1.0747x over previous
//
#include <hip/hip_runtime.h>

typedef unsigned short ushort_t;
typedef unsigned int uint_t;
typedef unsigned char uchar_t;
typedef unsigned long long ull_t;

#define N_NODES 50000
#define N_EDGES 800000
#define HID 128
#define NGRAPH 64
#define N_RT 3125     // row tiles of 16 nodes
#define NBKT 196      // coarse buckets of 256 nodes
#define CHUNK 4096    // edges per pass-A block
#define NB_TEMP 12500 // temporal blocks (x512 elems)
#define NB_WS 512     // wsplit blocks
#define NB_GEMM 1564  // 4*391
#define BCAP 6144     // passB LDS stage capacity (mean 4096 + 32 sigma)
#define BMAX 8192     // arena slot per bucket (mean + 64 sigma)
#define NB_POOL 782   // 4 row-tiles (64 nodes) per block

typedef __attribute__((ext_vector_type(8))) short short8;
typedef __attribute__((ext_vector_type(4))) float float4v;
typedef __attribute__((ext_vector_type(2))) float float2v;

// ---------- bf16 helpers ----------
__device__ __forceinline__ float bf2f(uint_t u) {
    union { uint_t i; float f; } v; v.i = u << 16; return v.f;
}
__device__ __forceinline__ ushort_t f2bf(float f) {
    union { float f; uint_t i; } v; v.f = f;
    uint_t r = v.i + 0x7FFFu + ((v.i >> 16) & 1u);
    return (ushort_t)(r >> 16);
}

// ---------- fp8 e4m3 helpers ----------
#if __has_builtin(__builtin_amdgcn_cvt_pk_fp8_f32) && __has_builtin(__builtin_amdgcn_cvt_pk_f32_fp8)
#define HAS_FP8_CVT 1
#else
#define HAS_FP8_CVT 0
#endif

__device__ __forceinline__ uchar_t f2fp8(float x) {
#if HAS_FP8_CVT
    int p = __builtin_amdgcn_cvt_pk_fp8_f32(x, x, 0, false);
    return (uchar_t)(p & 0xFF);
#else
    union { float f; uint_t u; } v; v.f = x;
    uint_t s = (v.u >> 31) << 7;
    float a = fabsf(x);
    a = fminf(a, 448.f);
    if (a < 0.015625f) {
        int m3 = (int)(a * 512.f + 0.5f);
        return (uchar_t)(s | (uint_t)m3);
    }
    v.f = a;
    uint_t r = v.u + 0x7FFFFu + ((v.u >> 20) & 1u);
    uint_t e = r >> 23;
    return (uchar_t)(s | ((e - 120u) << 3) | ((r >> 20) & 7u));
#endif
}

__device__ __forceinline__ float fp8dec1(uint_t b) {
    uint_t e = (b >> 3) & 15u, mnt = b & 7u;
    union { uint_t u; float f; } v;
    v.u = ((e + 120u) << 23) | (mnt << 20);
    float mag = e ? v.f : (float)mnt * 0.001953125f;  // 2^-9
    return (b & 0x80u) ? -mag : mag;
}

__device__ __forceinline__ void fp8x4_dec2(uint_t w, float2v* o) {
#if HAS_FP8_CVT
    o[0] = __builtin_amdgcn_cvt_pk_f32_fp8(w, false);
    o[1] = __builtin_amdgcn_cvt_pk_f32_fp8(w, true);
#else
    float2v a, b;
    a.x = fp8dec1(w & 0xFFu);  a.y = fp8dec1((w >> 8) & 0xFFu);
    b.x = fp8dec1((w >> 16) & 0xFFu); b.y = fp8dec1(w >> 24);
    o[0] = a; o[1] = b;
#endif
}

// ---------- prep mega-kernel: passA + temporal + wsplit + docemb ------------
__global__ __launch_bounds__(256) void prep_kernel(
    const int* __restrict__ ei,
    int* __restrict__ bucketcur, int* __restrict__ arena,
    const float* __restrict__ x, const float* __restrict__ ts,
    ushort_t* __restrict__ h,
    const float* __restrict__ Wq1, const float* __restrict__ Wk1,
    const float* __restrict__ Wv1, const float* __restrict__ Ws1,
    const float* __restrict__ Wq2, const float* __restrict__ Wk2,
    const float* __restrict__ Wv2, const float* __restrict__ Ws2,
    const float* __restrict__ bq1, const float* __restrict__ bk1,
    const float* __restrict__ bv1, const float* __restrict__ bs1,
    const float* __restrict__ bq2, const float* __restrict__ bk2,
    const float* __restrict__ bv2, const float* __restrict__ bs2,
    ushort_t* __restrict__ WF, float* __restrict__ bias_cat,
    const float* __restrict__ doc, const float* __restrict__ Wdoc,
    const float* __restrict__ bdoc, float* __restrict__ docemb,
    float* __restrict__ sums, float* __restrict__ cnt) {
    __shared__ int hist[NBKT];
    __shared__ int lofs[NBKT];
    __shared__ int lcur[NBKT];
    __shared__ int gbase[NBKT];
    __shared__ int sbuf[256];
    __shared__ uint_t staging[CHUNK];
    __shared__ int tot_s;

    int blk = blockIdx.x;
    int t = threadIdx.x;

    if (blk < NBKT) {
        // ---------------- pass A ----------------
        if (t < NBKT) hist[t] = 0;
        __syncthreads();
        int e0 = blk * CHUNK;
        int srcs[16], dsts[16];
        #pragma unroll
        for (int i = 0; i < 16; i++) {
            int idx = e0 + i * 256 + t;
            bool v = idx < N_EDGES;
            srcs[i] = v ? ei[idx] : -1;
            dsts[i] = v ? ei[N_EDGES + idx] : -1;
            if (v) atomicAdd(&hist[dsts[i] >> 8], 1);
        }
        __syncthreads();
        int hv = (t < NBKT) ? hist[t] : 0;
        sbuf[t] = hv;
        __syncthreads();
        #pragma unroll
        for (int s = 1; s < 256; s <<= 1) {
            int add = (t >= s) ? sbuf[t - s] : 0;
            __syncthreads();
            sbuf[t] += add;
            __syncthreads();
        }
        if (t < NBKT) {
            lofs[t] = sbuf[t] - hv;
            lcur[t] = sbuf[t] - hv;
        }
        if (t == NBKT - 1) tot_s = sbuf[NBKT - 1];
        __syncthreads();
        #pragma unroll
        for (int i = 0; i < 16; i++) {
            if (srcs[i] >= 0) {
                int bkt = dsts[i] >> 8;
                int pos = atomicAdd(&lcur[bkt], 1);
                staging[pos] = ((uint_t)bkt << 24) | ((uint_t)(dsts[i] & 255) << 16)
                             | (uint_t)srcs[i];
            }
        }
        __syncthreads();
        if (t < NBKT) {
            int hcnt = hist[t];
            gbase[t] = t * BMAX + (hcnt ? atomicAdd(&bucketcur[t], hcnt) : 0);
        }
        __syncthreads();
        int tot = tot_s;
        for (int i = t; i < tot; i += 256) {
            uint_t e = staging[i];
            int bkt = e >> 24;
            arena[gbase[bkt] + (i - lofs[bkt])] = (int)(e & 0xFFFFFF);
        }
    } else if (blk < NBKT + NB_TEMP) {
        // ---------------- temporal ----------------
        int base = (blk - NBKT) * 512;
        #pragma unroll
        for (int u = 0; u < 2; u++) {
            int tid = base + u * 256 + t;
            int rt   = tid >> 11;
            int kt   = (tid >> 9) & 3;
            int lane = (tid >> 3) & 63;
            int j    = tid & 7;
            int n = rt * 16 + (lane & 15);
            int c = kt * 32 + (lane >> 4) * 8 + j;
            float tv = ts[n];
            const float coef = -0.07195570687f;  // -ln(10000)/128
            float ang = tv * __expf((float)(c & ~1) * coef);
            float pe = (c & 1) ? __cosf(ang) : __sinf(ang);
            h[tid] = f2bf(x[n * 128 + c] + pe);
        }
    } else if (blk < NBKT + NB_TEMP + NB_WS) {
        // ---------------- wsplit ----------------
        int tid = (blk - NBKT - NB_TEMP) * 256 + t;  // 0..131071
        int j    = tid & 7;
        int lane = (tid >> 3) & 63;
        int kt   = (tid >> 9) & 3;
        int cgy  = (tid >> 11) & 31;
        int L    = tid >> 16;
        int col = cgy * 16 + (lane & 15);
        int k   = kt * 32 + (lane >> 4) * 8 + j;
        int mat = col >> 7, c = col & 127;
        const float* W = (L == 0)
            ? ((mat == 0) ? Wq1 : (mat == 1) ? Wk1 : (mat == 2) ? Wv1 : Ws1)
            : ((mat == 0) ? Wq2 : (mat == 1) ? Wk2 : (mat == 2) ? Wv2 : Ws2);
        size_t base = (size_t)L * 65536 + (size_t)cgy * 2048 + (size_t)kt * 512;
        WF[base + lane * 8 + j] = f2bf(W[k * 128 + c]);
        if (kt == 0 && (lane >> 4) == 0 && j == 0) {
            const float* b = (L == 0)
                ? ((mat == 0) ? bq1 : (mat == 1) ? bk1 : (mat == 2) ? bv1 : bs1)
                : ((mat == 0) ? bq2 : (mat == 1) ? bk2 : (mat == 2) ? bv2 : bs2);
            bias_cat[L * 512 + col] = b[c];
        }
    } else {
        // ---------------- docemb + zero pool accumulators ----------------
        int b = blk - NBKT - NB_TEMP - NB_WS;   // 0..63
        int c = t & 127, half = t >> 7;
        if (t < 128) sums[b * 128 + t] = 0.f;
        if (t == 128) cnt[b] = 0.f;
        float* red = (float*)staging;           // reuse LDS
        float acc = (half == 0) ? bdoc[c] : 0.f;
        int k0 = half * 256;
        #pragma unroll 8
        for (int k = 0; k < 256; k++)
            acc += doc[b * 512 + k0 + k] * Wdoc[(size_t)(k0 + k) * 128 + c];
        red[t] = acc;
        __syncthreads();
        if (t < 128) docemb[b * 128 + c] = fmaxf(red[t] + red[t + 128], 0.f);
    }
}

// ---------- shared gemm body ----------
__device__ __forceinline__ void gemm_body(
    int rp, int cg0, int lane, int quad, int m,
    const ushort_t* __restrict__ hf, const ushort_t* __restrict__ WF,
    const float* __restrict__ bias_cat,
    ushort_t* __restrict__ qsb, uchar_t* __restrict__ kv8) {
    int rt0 = rp * 2;
    if (rt0 >= N_RT) return;
    int rt1 = rt0 + 1;
    int rt1c = (rt1 < N_RT) ? rt1 : rt0;

    short8 a0[4], a1[4];
    {
        const ushort_t* b0 = hf + (size_t)rt0 * 2048 + lane * 8;
        const ushort_t* b1 = hf + (size_t)rt1c * 2048 + lane * 8;
        #pragma unroll
        for (int kt = 0; kt < 4; kt++) {
            a0[kt] = *reinterpret_cast<const short8*>(b0 + kt * 512);
            a1[kt] = *reinterpret_cast<const short8*>(b1 + kt * 512);
        }
    }

    const ushort_t* wfl = WF + (size_t)cg0 * 2048 + lane * 8;
    #pragma unroll 2
    for (int cg = 0; cg < 8; cg++) {
        const ushort_t* fp = wfl + (size_t)cg * 2048;
        float4v acc0 = {0.f, 0.f, 0.f, 0.f};
        float4v acc1 = {0.f, 0.f, 0.f, 0.f};
        #pragma unroll
        for (int kt = 0; kt < 4; kt++) {
            short8 bh = *reinterpret_cast<const short8*>(fp + kt * 512);
            acc0 = __builtin_amdgcn_mfma_f32_16x16x32_bf16(a0[kt], bh, acc0, 0, 0, 0);
            acc1 = __builtin_amdgcn_mfma_f32_16x16x32_bf16(a1[kt], bh, acc1, 0, 0, 0);
        }
        int col = (cg0 + cg) * 16 + m;
        float bias = bias_cat[col];
        int mat = col >> 7;
        #pragma unroll
        for (int r = 0; r < 4; r++) {
            float v0 = acc0[r] + bias;
            size_t row0 = (size_t)rt0 * 16 + quad * 4 + r;
            if (mat == 0)      qsb[row0 * 256 + col] = f2bf(v0);
            else if (mat == 3) qsb[row0 * 256 + (col - 256)] = f2bf(v0);
            else               kv8[row0 * 256 + (col - 128)] = f2fp8(v0);
        }
        if (rt1 < N_RT) {
            #pragma unroll
            for (int r = 0; r < 4; r++) {
                float v1 = acc1[r] + bias;
                size_t row1 = (size_t)rt1 * 16 + quad * 4 + r;
                if (mat == 0)      qsb[row1 * 256 + col] = f2bf(v1);
                else if (mat == 3) qsb[row1 * 256 + (col - 256)] = f2bf(v1);
                else               kv8[row1 * 256 + (col - 128)] = f2fp8(v1);
            }
        }
    }
}

// ---------- fused: passB (off+csr build) + gemm L1 + fusdoc -----------------
__global__ __launch_bounds__(256) void g1_kernel(
    int* __restrict__ off, const int* __restrict__ arena,
    const int* __restrict__ bucketcur, int* __restrict__ csr,
    const ushort_t* __restrict__ hf, const ushort_t* __restrict__ WF,
    const float* __restrict__ bias_cat,
    ushort_t* __restrict__ qsb, uchar_t* __restrict__ kv8,
    const float* __restrict__ docemb, const float* __restrict__ Wfus,
    const float* __restrict__ bfus, float* __restrict__ fusdoc) {
    __shared__ uint_t smem[BCAP + 1024];
    __shared__ int bbase_s;
    int blk = blockIdx.x;
    int t = threadIdx.x;
    if (blk < NBKT) {
        // ---- passB: derive off[] + exact csr from arena bucket ----
        uint_t* stage = smem;
        int* lcnt = (int*)(smem + BCAP);
        int* exc  = (int*)(smem + BCAP + 256);
        int* lcur = (int*)(smem + BCAP + 512);
        int* sb   = (int*)(smem + BCAP + 768);
        int bc = (t < NBKT) ? bucketcur[t] : 0;
        sb[t] = bc;
        __syncthreads();
        #pragma unroll
        for (int s = 1; s < 256; s <<= 1) {
            int a = (t >= s) ? sb[t - s] : 0;
            __syncthreads();
            sb[t] += a;
            __syncthreads();
        }
        if (t == 0) bbase_s = (blk == 0) ? 0 : sb[blk - 1];
        lcnt[t] = 0; lcur[t] = 0;
        __syncthreads();
        int bbase = bbase_s;
        int size = bucketcur[blk];
        int abase = blk * BMAX;
        int lim = (size < BCAP) ? size : BCAP;
        for (int i = t; i < lim; i += 256) stage[i] = (uint_t)arena[abase + i];
        __syncthreads();
        for (int i = t; i < size; i += 256) {
            uint_t e = (i < BCAP) ? stage[i] : (uint_t)arena[abase + i];
            atomicAdd(&lcnt[(e >> 16) & 255], 1);
        }
        __syncthreads();
        int v = lcnt[t];
        sb[t] = v;
        __syncthreads();
        #pragma unroll
        for (int s = 1; s < 256; s <<= 1) {
            int a = (t >= s) ? sb[t - s] : 0;
            __syncthreads();
            sb[t] += a;
            __syncthreads();
        }
        exc[t] = sb[t] - v;
        int n0 = blk * 256;
        if (n0 + t < N_NODES) off[n0 + t] = bbase + sb[t] - v;
        if (blk == NBKT - 1 && t == 0) off[N_NODES] = N_EDGES;
        __syncthreads();
        for (int i = t; i < size; i += 256) {
            uint_t e = (i < BCAP) ? stage[i] : (uint_t)arena[abase + i];
            int dlow = (e >> 16) & 255;
            int src = (int)(e & 0xFFFF);
            int pos = exc[dlow] + atomicAdd(&lcur[dlow], 1);
            csr[bbase + pos] = src;
        }
    } else if (blk < NBKT + NB_GEMM) {
        int blk2 = blk - NBKT;           // 0..1563
        int y = blk2 / 391, bx = blk2 % 391;
        int wave = t >> 6, lane = t & 63;
        gemm_body(bx * 4 + wave, y * 8, lane, lane >> 4, lane & 15,
                  hf, WF, bias_cat, qsb, kv8);
    } else {
        // ---- fusdoc[b][c] = bfus[c] + docemb[b] @ Wfus[128:256] ----
        int b = blk - NBKT - NB_GEMM;    // 0..63
        int c = t & 127, half = t >> 7;
        float* de = (float*)smem;
        float* red = (float*)smem + 128;
        if (t < 128) de[t] = docemb[b * 128 + t];
        __syncthreads();
        float acc = (half == 0) ? bfus[c] : 0.f;
        int k0 = half * 64;
        #pragma unroll 8
        for (int k = 0; k < 64; k++)
            acc += de[k0 + k] * Wfus[(size_t)(128 + k0 + k) * 128 + c];
        red[t] = acc;
        __syncthreads();
        if (t < 128) fusdoc[b * 128 + c] = red[t] + red[t + 128];
    }
}

// ---------- plain gemm (layer 2) ----------
__global__ __launch_bounds__(256) void gemm_qkvs(
    const ushort_t* __restrict__ hf,
    const ushort_t* __restrict__ WF,
    const float* __restrict__ bias_cat,
    ushort_t* __restrict__ qsb, uchar_t* __restrict__ kv8) {
    int t = threadIdx.x;
    int wave = t >> 6, lane = t & 63;
    gemm_body(blockIdx.x * 4 + wave, blockIdx.y * 8, lane, lane >> 4, lane & 15,
              hf, WF, bias_cat, qsb, kv8);
}

// ---------- fused per-node attention + skip + BN + relu -> h (frag-major) ----
__global__ __launch_bounds__(256) void node_attn_bn(
    const int* __restrict__ off, const int* __restrict__ csr_src,
    const ushort_t* __restrict__ qsb, const uchar_t* __restrict__ kv8,
    const float* __restrict__ bng, const float* __restrict__ bnb,
    const float* __restrict__ bnm, const float* __restrict__ bnv,
    ushort_t* __restrict__ h) {
    int wave = threadIdx.x >> 6;
    int n = blockIdx.x * 4 + wave;
    if (n >= N_NODES) return;
    int lane = threadIdx.x & 63;
    int qtr = lane >> 4, s16 = lane & 15;
    int c0 = s16 * 8;

    const ushort_t* row_qs = qsb + (size_t)n * 256;
    float2v q2[4];
    {
        uint4 qu = *reinterpret_cast<const uint4*>(row_qs + c0);
        q2[0].x = bf2f(qu.x & 0xffff) * 0.125f; q2[0].y = bf2f(qu.x >> 16) * 0.125f;
        q2[1].x = bf2f(qu.y & 0xffff) * 0.125f; q2[1].y = bf2f(qu.y >> 16) * 0.125f;
        q2[2].x = bf2f(qu.z & 0xffff) * 0.125f; q2[2].y = bf2f(qu.z >> 16) * 0.125f;
        q2[3].x = bf2f(qu.w & 0xffff) * 0.125f; q2[3].y = bf2f(qu.w >> 16) * 0.125f;
    }

    int e0 = off[n], e1 = off[n + 1];
    float l = 0.f;
    float2v o2[4];
    o2[0] = (float2v){0.f, 0.f}; o2[1] = (float2v){0.f, 0.f};
    o2[2] = (float2v){0.f, 0.f}; o2[3] = (float2v){0.f, 0.f};

    int src_a = (e0 + qtr < e1) ? csr_src[e0 + qtr] : 0;
    int src_b = (e0 + 4 + qtr < e1) ? csr_src[e0 + 4 + qtr] : 0;
    for (int p = e0; p < e1; p += 8) {
        int ia = p + qtr, ib = p + 4 + qtr;
        bool va = ia < e1, vb = ib < e1;
        int sa = src_a, sb = src_b;
        int na = p + 8 + qtr, nb = p + 12 + qtr;
        if (na < e1) src_a = csr_src[na];
        if (nb < e1) src_b = csr_src[nb];
        const uchar_t* kpa = kv8 + (size_t)sa * 256;
        const uchar_t* kpb = kv8 + (size_t)sb * 256;
        uint2 kua = *reinterpret_cast<const uint2*>(kpa + c0);
        uint2 vua = *reinterpret_cast<const uint2*>(kpa + 128 + c0);
        uint2 kub = *reinterpret_cast<const uint2*>(kpb + c0);
        uint2 vub = *reinterpret_cast<const uint2*>(kpb + 128 + c0);
        float2v ka2[4], wa2[4], kb2[4], wb2[4];
        fp8x4_dec2(kua.x, ka2);  fp8x4_dec2(kua.y, ka2 + 2);
        fp8x4_dec2(kub.x, kb2);  fp8x4_dec2(kub.y, kb2 + 2);
        fp8x4_dec2(vua.x, wa2);  fp8x4_dec2(vua.y, wa2 + 2);
        fp8x4_dec2(vub.x, wb2);  fp8x4_dec2(vub.y, wb2 + 2);
        float2v da2 = q2[0] * ka2[0];
        float2v db2 = q2[0] * kb2[0];
        da2 += q2[1] * ka2[1];  db2 += q2[1] * kb2[1];
        da2 += q2[2] * ka2[2];  db2 += q2[2] * kb2[2];
        da2 += q2[3] * ka2[3];  db2 += q2[3] * kb2[3];
        float da = da2.x + da2.y;
        float db = db2.x + db2.y;
        da += __shfl_xor(da, 1);  db += __shfl_xor(db, 1);
        da += __shfl_xor(da, 2);  db += __shfl_xor(db, 2);
        da += __shfl_xor(da, 4);  db += __shfl_xor(db, 4);
        float pea = va ? __expf(da) : 0.f;
        float peb = vb ? __expf(db) : 0.f;
        l += pea + peb;
        float2v pa; pa.x = pea; pa.y = pea;
        float2v pb; pb.x = peb; pb.y = peb;
        #pragma unroll
        for (int i = 0; i < 4; i++) {
            o2[i] += pa * wa2[i];
            o2[i] += pb * wb2[i];
        }
    }
    #pragma unroll
    for (int offx = 16; offx <= 32; offx <<= 1) {
        l += __shfl_xor(l, offx);
        #pragma unroll
        for (int i = 0; i < 4; i++) {
            o2[i].x += __shfl_xor(o2[i].x, offx);
            o2[i].y += __shfl_xor(o2[i].y, offx);
        }
    }

    if (qtr == 0) {
        float inv = 1.f / (l + 1e-16f);
        float o[8] = {o2[0].x, o2[0].y, o2[1].x, o2[1].y,
                      o2[2].x, o2[2].y, o2[3].x, o2[3].y};
        float sv[8];
        {
            uint4 su = *reinterpret_cast<const uint4*>(row_qs + 128 + c0);
            sv[0] = bf2f(su.x & 0xffff); sv[1] = bf2f(su.x >> 16);
            sv[2] = bf2f(su.y & 0xffff); sv[3] = bf2f(su.y >> 16);
            sv[4] = bf2f(su.z & 0xffff); sv[5] = bf2f(su.z >> 16);
            sv[6] = bf2f(su.w & 0xffff); sv[7] = bf2f(su.w >> 16);
        }
        float gv[8], bv[8], mv[8], vr[8];
        *reinterpret_cast<float4*>(gv)     = *reinterpret_cast<const float4*>(bng + c0);
        *reinterpret_cast<float4*>(gv + 4) = *reinterpret_cast<const float4*>(bng + c0 + 4);
        *reinterpret_cast<float4*>(bv)     = *reinterpret_cast<const float4*>(bnb + c0);
        *reinterpret_cast<float4*>(bv + 4) = *reinterpret_cast<const float4*>(bnb + c0 + 4);
        *reinterpret_cast<float4*>(mv)     = *reinterpret_cast<const float4*>(bnm + c0);
        *reinterpret_cast<float4*>(mv + 4) = *reinterpret_cast<const float4*>(bnm + c0 + 4);
        *reinterpret_cast<float4*>(vr)     = *reinterpret_cast<const float4*>(bnv + c0);
        *reinterpret_cast<float4*>(vr + 4) = *reinterpret_cast<const float4*>(bnv + c0 + 4);
        uint_t hw[4];
        #pragma unroll
        for (int i = 0; i < 8; i++) {
            float val = fmaxf(o[i] * inv + sv[i], 0.f);
            val = (val - mv[i]) * rsqrtf(vr[i] + 1e-5f) * gv[i] + bv[i];
            val = fmaxf(val, 0.f);
            ushort_t hb = f2bf(val);
            if (i & 1) hw[i >> 1] |= (uint_t)hb << 16;
            else       hw[i >> 1] = hb;
        }
        int rt = n >> 4, mnode = n & 15;
        int kt = s16 >> 2, qd = s16 & 3;
        size_t fidx = (size_t)rt * 2048 + kt * 512 + (mnode + 16 * qd) * 8;
        uint4 hp; hp.x = hw[0]; hp.y = hw[1]; hp.z = hw[2]; hp.w = hw[3];
        *reinterpret_cast<uint4*>(h + fidx) = hp;
    }
}

// ---------- global mean pool v3: coalesced load -> LDS transpose -> -------
// register run-length per channel. 782 blocks (64 nodes each), <=2-way
// atomic contention per (graph,channel) per block.
__global__ __launch_bounds__(256) void pool_kernel(
    const ushort_t* __restrict__ h, const int* __restrict__ batch,
    float* __restrict__ sums, float* __restrict__ cnt) {
    __shared__ float lsum[64][129];   // pad 129: conflict-free both phases
    int t = threadIdx.x;
    int rt0 = blockIdx.x * 4;
    int m16 = t & 15;
    int cb = ((t >> 6) & 3) * 32 + ((t >> 4) & 3) * 8;
    // phase 1: coalesced fragment loads -> LDS (node-major)
    #pragma unroll
    for (int i = 0; i < 4; i++) {
        int rt = rt0 + i;
        int nl = i * 16 + m16;
        float* dst = &lsum[nl][cb];
        if (rt < N_RT) {
            uint4 d = *reinterpret_cast<const uint4*>(
                h + (size_t)rt * 2048 + (size_t)t * 8);
            dst[0] = bf2f(d.x & 0xffff); dst[1] = bf2f(d.x >> 16);
            dst[2] = bf2f(d.y & 0xffff); dst[3] = bf2f(d.y >> 16);
            dst[4] = bf2f(d.z & 0xffff); dst[5] = bf2f(d.z >> 16);
            dst[6] = bf2f(d.w & 0xffff); dst[7] = bf2f(d.w >> 16);
        } else {
            #pragma unroll
            for (int j = 0; j < 8; j++) dst[j] = 0.f;
        }
    }
    __syncthreads();
    // phase 2: thread owns channel c, half of the 64 nodes; run-length flush
    int c = t & 127;
    int n0 = (t >> 7) * 32;
    int nbase = rt0 * 16;
    float acc = 0.f, ncnt = 0.f;
    int gcur = -1;
    for (int i = 0; i < 32; i++) {
        int nl = n0 + i;
        int n = nbase + nl;
        if (n >= N_NODES) break;
        int g = batch[n];           // broadcast (uniform per half-block)
        if (g != gcur) {
            if (gcur >= 0) {
                atomicAdd(&sums[gcur * 128 + c], acc);
                if (c == 0) atomicAdd(&cnt[gcur], ncnt);
            }
            acc = 0.f; ncnt = 0.f; gcur = g;
        }
        acc += lsum[nl][c];
        ncnt += 1.f;
    }
    if (gcur >= 0) {
        atomicAdd(&sums[gcur * 128 + c], acc);
        if (c == 0) atomicAdd(&cnt[gcur], ncnt);
    }
}

// ---------- final head: gbuf@Wfus[0:128] + fusdoc -> relu -> task/time -----
__global__ __launch_bounds__(128) void final_mlp(
    const float* __restrict__ sums, const float* __restrict__ cnt,
    const float* __restrict__ fusdoc, const float* __restrict__ Wfus,
    const float* __restrict__ Wtask, const float* __restrict__ btask,
    const float* __restrict__ Wtime, const float* __restrict__ btime,
    float* __restrict__ out) {
    int b = blockIdx.x;
    int t = threadIdx.x;
    __shared__ float gbuf[128], fbuf[128];
    float c = fmaxf(cnt[b], 1.0f);
    gbuf[t] = sums[b * 128 + t] / c;
    __syncthreads();
    float f = fusdoc[b * 128 + t];
    #pragma unroll 8
    for (int k = 0; k < 128; k++) f += gbuf[k] * Wfus[(size_t)k * 128 + t];
    fbuf[t] = fmaxf(f, 0.f);
    __syncthreads();
    if (t < 16) {
        float a = btask[t];
        #pragma unroll 8
        for (int k = 0; k < 128; k++) a += fbuf[k] * Wtask[k * 16 + t];
        out[b * 16 + t] = a;
    } else if (t == 16) {
        float a = btime[0];
        #pragma unroll 8
        for (int k = 0; k < 128; k++) a += fbuf[k] * Wtime[k];
        out[NGRAPH * 16 + b] = a;
    }
}

extern "C" void kernel_launch(void* const* d_in, const int* in_sizes, int n_in,
                              void* d_out, int out_size, void* d_ws, size_t ws_size,
                              hipStream_t stream) {
    (void)in_sizes; (void)n_in; (void)out_size; (void)ws_size;
    const float* x    = (const float*)d_in[0];
    const int*   ei   = (const int*)d_in[1];
    const int*   batch= (const int*)d_in[2];
    const float* ts   = (const float*)d_in[3];
    const float* doc  = (const float*)d_in[4];
    const float* Wq1  = (const float*)d_in[5];
    const float* bq1  = (const float*)d_in[6];
    const float* Wk1  = (const float*)d_in[7];
    const float* bk1  = (const float*)d_in[8];
    const float* Wv1  = (const float*)d_in[9];
    const float* bv1  = (const float*)d_in[10];
    const float* Ws1  = (const float*)d_in[11];
    const float* bs1  = (const float*)d_in[12];
    const float* Wq2  = (const float*)d_in[13];
    const float* bq2  = (const float*)d_in[14];
    const float* Wk2  = (const float*)d_in[15];
    const float* bk2  = (const float*)d_in[16];
    const float* Wv2  = (const float*)d_in[17];
    const float* bv2  = (const float*)d_in[18];
    const float* Ws2  = (const float*)d_in[19];
    const float* bs2  = (const float*)d_in[20];
    const float* bn1g = (const float*)d_in[21];
    const float* bn1b = (const float*)d_in[22];
    const float* bn1m = (const float*)d_in[23];
    const float* bn1v = (const float*)d_in[24];
    const float* bn2g = (const float*)d_in[25];
    const float* bn2b = (const float*)d_in[26];
    const float* bn2m = (const float*)d_in[27];
    const float* bn2v = (const float*)d_in[28];
    const float* Wdoc = (const float*)d_in[29];
    const float* bdoc = (const float*)d_in[30];
    const float* Wfus = (const float*)d_in[31];
    const float* bfus = (const float*)d_in[32];
    const float* Wtask= (const float*)d_in[33];
    const float* btask= (const float*)d_in[34];
    const float* Wtime= (const float*)d_in[35];
    const float* btime= (const float*)d_in[36];

    char* ws = (char*)d_ws;
    ushort_t* h      = (ushort_t*)(ws + 0);           // 12.8 MB
    ushort_t* qsb    = (ushort_t*)(ws + 12800000);    // 25.6 MB
    uchar_t*  kv8    = (uchar_t*)(ws + 38400000);     // 12.8 MB
    ushort_t* WF     = (ushort_t*)(ws + 51200000);    // 256 KB
    float*    biasc  = (float*)(ws + 51462144);       // 4 KB
    float*    sums   = (float*)(ws + 51466240);       // 32768 B
    float*    cnt    = (float*)(ws + 51499008);       // 256 B
    int*      off    = (int*)(ws + 51499264);         // 200004 B
    int*      bucketcur = (int*)(ws + 51699268);      // 784 B
    int*      arena  = (int*)(ws + 51700052);         // 196*8192*4 = 6.42 MB
    int*      csr    = (int*)(ws + 58122580);         // 3.2 MB
    float*    docemb = (float*)(ws + 61322580);       // 32 KB
    float*    fusdoc = (float*)(ws + 61355348);       // 32 KB

    float* out = (float*)d_out;

    hipMemsetAsync(bucketcur, 0, 784, stream);

    prep_kernel<<<NBKT + NB_TEMP + NB_WS + NGRAPH, 256, 0, stream>>>(
        ei, bucketcur, arena, x, ts, h,
        Wq1, Wk1, Wv1, Ws1, Wq2, Wk2, Wv2, Ws2,
        bq1, bk1, bv1, bs1, bq2, bk2, bv2, bs2, WF, biasc,
        doc, Wdoc, bdoc, docemb, sums, cnt);

    const size_t WF_LAYER = 65536;  // shorts per layer

    // ---- layer 1 (gemm fused with passB(off+csr) + fusdoc) ----
    g1_kernel<<<NBKT + NB_GEMM + NGRAPH, 256, 0, stream>>>(
        off, arena, bucketcur, csr, h, WF, biasc, qsb, kv8,
        docemb, Wfus, bfus, fusdoc);
    node_attn_bn<<<12500, 256, 0, stream>>>(off, csr, qsb, kv8, bn1g, bn1b, bn1m, bn1v, h);

    // ---- layer 2 ----
    gemm_qkvs<<<dim3(391, 4), 256, 0, stream>>>(h, WF + WF_LAYER, biasc + 512, qsb, kv8);
    node_attn_bn<<<12500, 256, 0, stream>>>(off, csr, qsb, kv8, bn2g, bn2b, bn2m, bn2v, h);

    // ---- pool + final head ----
    pool_kernel<<<NB_POOL, 256, 0, stream>>>(h, batch, sums, cnt);
    final_mlp<<<NGRAPH, 128, 0, stream>>>(sums, cnt, fusdoc, Wfus,
                                          Wtask, btask, Wtime, btime, out);
}

// Round 18
// 328.006 us; speedup vs baseline: 1.2151x; 1.0154x over previous
//
#include <hip/hip_runtime.h>

typedef unsigned short ushort_t;
typedef unsigned int uint_t;
typedef unsigned char uchar_t;
typedef unsigned long long ull_t;

#define N_NODES 50000
#define N_EDGES 800000
#define HID 128
#define NGRAPH 64
#define N_RT 3125     // row tiles of 16 nodes
#define NBKT 196      // coarse buckets of 256 nodes
#define CHUNK 4096    // edges per pass-A block
#define NB_TEMP 12500 // temporal blocks (x512 elems)
#define NB_WS 512     // wsplit blocks
#define NB_GEMM 1564  // 4*391
#define BCAP 6144     // passB LDS stage capacity (mean 4096 + 32 sigma)
#define BMAX 8192     // arena slot per bucket (mean + 64 sigma)
#define NB_POOL 782   // 4 row-tiles (64 nodes) per block

typedef __attribute__((ext_vector_type(8))) short short8;
typedef __attribute__((ext_vector_type(4))) float float4v;
typedef __attribute__((ext_vector_type(2))) float float2v;

// ---------- bf16 helpers ----------
__device__ __forceinline__ float bf2f(uint_t u) {
    union { uint_t i; float f; } v; v.i = u << 16; return v.f;
}
__device__ __forceinline__ ushort_t f2bf(float f) {
    union { float f; uint_t i; } v; v.f = f;
    uint_t r = v.i + 0x7FFFu + ((v.i >> 16) & 1u);
    return (ushort_t)(r >> 16);
}

// ---------- fp8 e4m3 helpers ----------
#if __has_builtin(__builtin_amdgcn_cvt_pk_fp8_f32) && __has_builtin(__builtin_amdgcn_cvt_pk_f32_fp8)
#define HAS_FP8_CVT 1
#else
#define HAS_FP8_CVT 0
#endif

__device__ __forceinline__ uchar_t f2fp8(float x) {
#if HAS_FP8_CVT
    int p = __builtin_amdgcn_cvt_pk_fp8_f32(x, x, 0, false);
    return (uchar_t)(p & 0xFF);
#else
    union { float f; uint_t u; } v; v.f = x;
    uint_t s = (v.u >> 31) << 7;
    float a = fabsf(x);
    a = fminf(a, 448.f);
    if (a < 0.015625f) {
        int m3 = (int)(a * 512.f + 0.5f);
        return (uchar_t)(s | (uint_t)m3);
    }
    v.f = a;
    uint_t r = v.u + 0x7FFFFu + ((v.u >> 20) & 1u);
    uint_t e = r >> 23;
    return (uchar_t)(s | ((e - 120u) << 3) | ((r >> 20) & 7u));
#endif
}

__device__ __forceinline__ float fp8dec1(uint_t b) {
    uint_t e = (b >> 3) & 15u, mnt = b & 7u;
    union { uint_t u; float f; } v;
    v.u = ((e + 120u) << 23) | (mnt << 20);
    float mag = e ? v.f : (float)mnt * 0.001953125f;  // 2^-9
    return (b & 0x80u) ? -mag : mag;
}

__device__ __forceinline__ void fp8x4_dec2(uint_t w, float2v* o) {
#if HAS_FP8_CVT
    o[0] = __builtin_amdgcn_cvt_pk_f32_fp8(w, false);
    o[1] = __builtin_amdgcn_cvt_pk_f32_fp8(w, true);
#else
    float2v a, b;
    a.x = fp8dec1(w & 0xFFu);  a.y = fp8dec1((w >> 8) & 0xFFu);
    b.x = fp8dec1((w >> 16) & 0xFFu); b.y = fp8dec1(w >> 24);
    o[0] = a; o[1] = b;
#endif
}

// ---------- prep mega-kernel: passA + temporal + wsplit + docemb ------------
__global__ __launch_bounds__(256) void prep_kernel(
    const int* __restrict__ ei,
    int* __restrict__ bucketcur, int* __restrict__ arena,
    const float* __restrict__ x, const float* __restrict__ ts,
    ushort_t* __restrict__ h,
    const float* __restrict__ Wq1, const float* __restrict__ Wk1,
    const float* __restrict__ Wv1, const float* __restrict__ Ws1,
    const float* __restrict__ Wq2, const float* __restrict__ Wk2,
    const float* __restrict__ Wv2, const float* __restrict__ Ws2,
    const float* __restrict__ bq1, const float* __restrict__ bk1,
    const float* __restrict__ bv1, const float* __restrict__ bs1,
    const float* __restrict__ bq2, const float* __restrict__ bk2,
    const float* __restrict__ bv2, const float* __restrict__ bs2,
    ushort_t* __restrict__ WF, float* __restrict__ bias_cat,
    const float* __restrict__ doc, const float* __restrict__ Wdoc,
    const float* __restrict__ bdoc, float* __restrict__ docemb,
    float* __restrict__ sums, float* __restrict__ cnt) {
    __shared__ int hist[NBKT];
    __shared__ int lofs[NBKT];
    __shared__ int lcur[NBKT];
    __shared__ int gbase[NBKT];
    __shared__ int sbuf[256];
    __shared__ uint_t staging[CHUNK];
    __shared__ int tot_s;

    int blk = blockIdx.x;
    int t = threadIdx.x;

    if (blk < NBKT) {
        // ---------------- pass A ----------------
        if (t < NBKT) hist[t] = 0;
        __syncthreads();
        int e0 = blk * CHUNK;
        int srcs[16], dsts[16];
        #pragma unroll
        for (int i = 0; i < 16; i++) {
            int idx = e0 + i * 256 + t;
            bool v = idx < N_EDGES;
            srcs[i] = v ? ei[idx] : -1;
            dsts[i] = v ? ei[N_EDGES + idx] : -1;
            if (v) atomicAdd(&hist[dsts[i] >> 8], 1);
        }
        __syncthreads();
        int hv = (t < NBKT) ? hist[t] : 0;
        sbuf[t] = hv;
        __syncthreads();
        #pragma unroll
        for (int s = 1; s < 256; s <<= 1) {
            int add = (t >= s) ? sbuf[t - s] : 0;
            __syncthreads();
            sbuf[t] += add;
            __syncthreads();
        }
        if (t < NBKT) {
            lofs[t] = sbuf[t] - hv;
            lcur[t] = sbuf[t] - hv;
        }
        if (t == NBKT - 1) tot_s = sbuf[NBKT - 1];
        __syncthreads();
        #pragma unroll
        for (int i = 0; i < 16; i++) {
            if (srcs[i] >= 0) {
                int bkt = dsts[i] >> 8;
                int pos = atomicAdd(&lcur[bkt], 1);
                staging[pos] = ((uint_t)bkt << 24) | ((uint_t)(dsts[i] & 255) << 16)
                             | (uint_t)srcs[i];
            }
        }
        __syncthreads();
        if (t < NBKT) {
            int hcnt = hist[t];
            gbase[t] = t * BMAX + (hcnt ? atomicAdd(&bucketcur[t], hcnt) : 0);
        }
        __syncthreads();
        int tot = tot_s;
        for (int i = t; i < tot; i += 256) {
            uint_t e = staging[i];
            int bkt = e >> 24;
            arena[gbase[bkt] + (i - lofs[bkt])] = (int)(e & 0xFFFFFF);
        }
    } else if (blk < NBKT + NB_TEMP) {
        // ---------------- temporal ----------------
        int base = (blk - NBKT) * 512;
        #pragma unroll
        for (int u = 0; u < 2; u++) {
            int tid = base + u * 256 + t;
            int rt   = tid >> 11;
            int kt   = (tid >> 9) & 3;
            int lane = (tid >> 3) & 63;
            int j    = tid & 7;
            int n = rt * 16 + (lane & 15);
            int c = kt * 32 + (lane >> 4) * 8 + j;
            float tv = ts[n];
            const float coef = -0.07195570687f;  // -ln(10000)/128
            float ang = tv * __expf((float)(c & ~1) * coef);
            float pe = (c & 1) ? __cosf(ang) : __sinf(ang);
            h[tid] = f2bf(x[n * 128 + c] + pe);
        }
    } else if (blk < NBKT + NB_TEMP + NB_WS) {
        // ---------------- wsplit ----------------
        int tid = (blk - NBKT - NB_TEMP) * 256 + t;  // 0..131071
        int j    = tid & 7;
        int lane = (tid >> 3) & 63;
        int kt   = (tid >> 9) & 3;
        int cgy  = (tid >> 11) & 31;
        int L    = tid >> 16;
        int col = cgy * 16 + (lane & 15);
        int k   = kt * 32 + (lane >> 4) * 8 + j;
        int mat = col >> 7, c = col & 127;
        const float* W = (L == 0)
            ? ((mat == 0) ? Wq1 : (mat == 1) ? Wk1 : (mat == 2) ? Wv1 : Ws1)
            : ((mat == 0) ? Wq2 : (mat == 1) ? Wk2 : (mat == 2) ? Wv2 : Ws2);
        size_t base = (size_t)L * 65536 + (size_t)cgy * 2048 + (size_t)kt * 512;
        WF[base + lane * 8 + j] = f2bf(W[k * 128 + c]);
        if (kt == 0 && (lane >> 4) == 0 && j == 0) {
            const float* b = (L == 0)
                ? ((mat == 0) ? bq1 : (mat == 1) ? bk1 : (mat == 2) ? bv1 : bs1)
                : ((mat == 0) ? bq2 : (mat == 1) ? bk2 : (mat == 2) ? bv2 : bs2);
            bias_cat[L * 512 + col] = b[c];
        }
    } else {
        // ---------------- docemb + zero pool accumulators ----------------
        int b = blk - NBKT - NB_TEMP - NB_WS;   // 0..63
        int c = t & 127, half = t >> 7;
        if (t < 128) sums[b * 128 + t] = 0.f;
        if (t == 128) cnt[b] = 0.f;
        float* red = (float*)staging;           // reuse LDS
        float acc = (half == 0) ? bdoc[c] : 0.f;
        int k0 = half * 256;
        #pragma unroll 8
        for (int k = 0; k < 256; k++)
            acc += doc[b * 512 + k0 + k] * Wdoc[(size_t)(k0 + k) * 128 + c];
        red[t] = acc;
        __syncthreads();
        if (t < 128) docemb[b * 128 + c] = fmaxf(red[t] + red[t + 128], 0.f);
    }
}

// ---------- shared gemm body: double-buffered B prefetch --------------------
__device__ __forceinline__ void gemm_body(
    int rp, int cg0, int lane, int quad, int m,
    const ushort_t* __restrict__ hf, const ushort_t* __restrict__ WF,
    const float* __restrict__ bias_cat,
    ushort_t* __restrict__ qsb, uchar_t* __restrict__ kv8) {
    int rt0 = rp * 2;
    if (rt0 >= N_RT) return;
    int rt1 = rt0 + 1;
    int rt1c = (rt1 < N_RT) ? rt1 : rt0;

    short8 a0[4], a1[4];
    {
        const ushort_t* b0 = hf + (size_t)rt0 * 2048 + lane * 8;
        const ushort_t* b1 = hf + (size_t)rt1c * 2048 + lane * 8;
        #pragma unroll
        for (int kt = 0; kt < 4; kt++) {
            a0[kt] = *reinterpret_cast<const short8*>(b0 + kt * 512);
            a1[kt] = *reinterpret_cast<const short8*>(b1 + kt * 512);
        }
    }

    const ushort_t* wfl = WF + (size_t)cg0 * 2048 + lane * 8;
    short8 bh[4];
    #pragma unroll
    for (int kt = 0; kt < 4; kt++)
        bh[kt] = *reinterpret_cast<const short8*>(wfl + kt * 512);

    #pragma unroll 2
    for (int cg = 0; cg < 8; cg++) {
        // prefetch next cg's B fragments before consuming current
        short8 bn[4];
        if (cg < 7) {
            const ushort_t* fpn = wfl + (size_t)(cg + 1) * 2048;
            #pragma unroll
            for (int kt = 0; kt < 4; kt++)
                bn[kt] = *reinterpret_cast<const short8*>(fpn + kt * 512);
        }
        float4v acc0 = {0.f, 0.f, 0.f, 0.f};
        float4v acc1 = {0.f, 0.f, 0.f, 0.f};
        #pragma unroll
        for (int kt = 0; kt < 4; kt++) {
            acc0 = __builtin_amdgcn_mfma_f32_16x16x32_bf16(a0[kt], bh[kt], acc0, 0, 0, 0);
            acc1 = __builtin_amdgcn_mfma_f32_16x16x32_bf16(a1[kt], bh[kt], acc1, 0, 0, 0);
        }
        int col = (cg0 + cg) * 16 + m;
        float bias = bias_cat[col];
        int mat = col >> 7;
        #pragma unroll
        for (int r = 0; r < 4; r++) {
            float v0 = acc0[r] + bias;
            size_t row0 = (size_t)rt0 * 16 + quad * 4 + r;
            if (mat == 0)      qsb[row0 * 256 + col] = f2bf(v0);
            else if (mat == 3) qsb[row0 * 256 + (col - 256)] = f2bf(v0);
            else               kv8[row0 * 256 + (col - 128)] = f2fp8(v0);
        }
        if (rt1 < N_RT) {
            #pragma unroll
            for (int r = 0; r < 4; r++) {
                float v1 = acc1[r] + bias;
                size_t row1 = (size_t)rt1 * 16 + quad * 4 + r;
                if (mat == 0)      qsb[row1 * 256 + col] = f2bf(v1);
                else if (mat == 3) qsb[row1 * 256 + (col - 256)] = f2bf(v1);
                else               kv8[row1 * 256 + (col - 128)] = f2fp8(v1);
            }
        }
        #pragma unroll
        for (int kt = 0; kt < 4; kt++) bh[kt] = bn[kt];
    }
}

// ---------- fused: passB (off+csr build) + gemm L1 + fusdoc -----------------
__global__ __launch_bounds__(256) void g1_kernel(
    int* __restrict__ off, const int* __restrict__ arena,
    const int* __restrict__ bucketcur, int* __restrict__ csr,
    const ushort_t* __restrict__ hf, const ushort_t* __restrict__ WF,
    const float* __restrict__ bias_cat,
    ushort_t* __restrict__ qsb, uchar_t* __restrict__ kv8,
    const float* __restrict__ docemb, const float* __restrict__ Wfus,
    const float* __restrict__ bfus, float* __restrict__ fusdoc) {
    __shared__ uint_t smem[BCAP + 1024];
    __shared__ int bbase_s;
    int blk = blockIdx.x;
    int t = threadIdx.x;
    if (blk < NBKT) {
        // ---- passB: derive off[] + exact csr from arena bucket ----
        uint_t* stage = smem;
        int* lcnt = (int*)(smem + BCAP);
        int* exc  = (int*)(smem + BCAP + 256);
        int* lcur = (int*)(smem + BCAP + 512);
        int* sb   = (int*)(smem + BCAP + 768);
        int bc = (t < NBKT) ? bucketcur[t] : 0;
        sb[t] = bc;
        __syncthreads();
        #pragma unroll
        for (int s = 1; s < 256; s <<= 1) {
            int a = (t >= s) ? sb[t - s] : 0;
            __syncthreads();
            sb[t] += a;
            __syncthreads();
        }
        if (t == 0) bbase_s = (blk == 0) ? 0 : sb[blk - 1];
        lcnt[t] = 0; lcur[t] = 0;
        __syncthreads();
        int bbase = bbase_s;
        int size = bucketcur[blk];
        int abase = blk * BMAX;
        int lim = (size < BCAP) ? size : BCAP;
        for (int i = t; i < lim; i += 256) stage[i] = (uint_t)arena[abase + i];
        __syncthreads();
        for (int i = t; i < size; i += 256) {
            uint_t e = (i < BCAP) ? stage[i] : (uint_t)arena[abase + i];
            atomicAdd(&lcnt[(e >> 16) & 255], 1);
        }
        __syncthreads();
        int v = lcnt[t];
        sb[t] = v;
        __syncthreads();
        #pragma unroll
        for (int s = 1; s < 256; s <<= 1) {
            int a = (t >= s) ? sb[t - s] : 0;
            __syncthreads();
            sb[t] += a;
            __syncthreads();
        }
        exc[t] = sb[t] - v;
        int n0 = blk * 256;
        if (n0 + t < N_NODES) off[n0 + t] = bbase + sb[t] - v;
        if (blk == NBKT - 1 && t == 0) off[N_NODES] = N_EDGES;
        __syncthreads();
        for (int i = t; i < size; i += 256) {
            uint_t e = (i < BCAP) ? stage[i] : (uint_t)arena[abase + i];
            int dlow = (e >> 16) & 255;
            int src = (int)(e & 0xFFFF);
            int pos = exc[dlow] + atomicAdd(&lcur[dlow], 1);
            csr[bbase + pos] = src;
        }
    } else if (blk < NBKT + NB_GEMM) {
        int blk2 = blk - NBKT;           // 0..1563
        int y = blk2 / 391, bx = blk2 % 391;
        int wave = t >> 6, lane = t & 63;
        gemm_body(bx * 4 + wave, y * 8, lane, lane >> 4, lane & 15,
                  hf, WF, bias_cat, qsb, kv8);
    } else {
        // ---- fusdoc[b][c] = bfus[c] + docemb[b] @ Wfus[128:256] ----
        int b = blk - NBKT - NB_GEMM;    // 0..63
        int c = t & 127, half = t >> 7;
        float* de = (float*)smem;
        float* red = (float*)smem + 128;
        if (t < 128) de[t] = docemb[b * 128 + t];
        __syncthreads();
        float acc = (half == 0) ? bfus[c] : 0.f;
        int k0 = half * 64;
        #pragma unroll 8
        for (int k = 0; k < 64; k++)
            acc += de[k0 + k] * Wfus[(size_t)(128 + k0 + k) * 128 + c];
        red[t] = acc;
        __syncthreads();
        if (t < 128) fusdoc[b * 128 + c] = red[t] + red[t + 128];
    }
}

// ---------- plain gemm (layer 2) ----------
__global__ __launch_bounds__(256) void gemm_qkvs(
    const ushort_t* __restrict__ hf,
    const ushort_t* __restrict__ WF,
    const float* __restrict__ bias_cat,
    ushort_t* __restrict__ qsb, uchar_t* __restrict__ kv8) {
    int t = threadIdx.x;
    int wave = t >> 6, lane = t & 63;
    gemm_body(blockIdx.x * 4 + wave, blockIdx.y * 8, lane, lane >> 4, lane & 15,
              hf, WF, bias_cat, qsb, kv8);
}

// ---------- fused per-node attention + skip + BN + relu -> h (frag-major) ----
__global__ __launch_bounds__(256) void node_attn_bn(
    const int* __restrict__ off, const int* __restrict__ csr_src,
    const ushort_t* __restrict__ qsb, const uchar_t* __restrict__ kv8,
    const float* __restrict__ bng, const float* __restrict__ bnb,
    const float* __restrict__ bnm, const float* __restrict__ bnv,
    ushort_t* __restrict__ h) {
    int wave = threadIdx.x >> 6;
    int n = blockIdx.x * 4 + wave;
    if (n >= N_NODES) return;
    int lane = threadIdx.x & 63;
    int qtr = lane >> 4, s16 = lane & 15;
    int c0 = s16 * 8;

    const ushort_t* row_qs = qsb + (size_t)n * 256;
    float2v q2[4];
    {
        uint4 qu = *reinterpret_cast<const uint4*>(row_qs + c0);
        q2[0].x = bf2f(qu.x & 0xffff) * 0.125f; q2[0].y = bf2f(qu.x >> 16) * 0.125f;
        q2[1].x = bf2f(qu.y & 0xffff) * 0.125f; q2[1].y = bf2f(qu.y >> 16) * 0.125f;
        q2[2].x = bf2f(qu.z & 0xffff) * 0.125f; q2[2].y = bf2f(qu.z >> 16) * 0.125f;
        q2[3].x = bf2f(qu.w & 0xffff) * 0.125f; q2[3].y = bf2f(qu.w >> 16) * 0.125f;
    }

    int e0 = off[n], e1 = off[n + 1];
    float l = 0.f;
    float2v o2[4];
    o2[0] = (float2v){0.f, 0.f}; o2[1] = (float2v){0.f, 0.f};
    o2[2] = (float2v){0.f, 0.f}; o2[3] = (float2v){0.f, 0.f};

    int src_a = (e0 + qtr < e1) ? csr_src[e0 + qtr] : 0;
    int src_b = (e0 + 4 + qtr < e1) ? csr_src[e0 + 4 + qtr] : 0;
    for (int p = e0; p < e1; p += 8) {
        int ia = p + qtr, ib = p + 4 + qtr;
        bool va = ia < e1, vb = ib < e1;
        int sa = src_a, sb = src_b;
        int na = p + 8 + qtr, nb = p + 12 + qtr;
        if (na < e1) src_a = csr_src[na];
        if (nb < e1) src_b = csr_src[nb];
        const uchar_t* kpa = kv8 + (size_t)sa * 256;
        const uchar_t* kpb = kv8 + (size_t)sb * 256;
        uint2 kua = *reinterpret_cast<const uint2*>(kpa + c0);
        uint2 vua = *reinterpret_cast<const uint2*>(kpa + 128 + c0);
        uint2 kub = *reinterpret_cast<const uint2*>(kpb + c0);
        uint2 vub = *reinterpret_cast<const uint2*>(kpb + 128 + c0);
        float2v ka2[4], wa2[4], kb2[4], wb2[4];
        fp8x4_dec2(kua.x, ka2);  fp8x4_dec2(kua.y, ka2 + 2);
        fp8x4_dec2(kub.x, kb2);  fp8x4_dec2(kub.y, kb2 + 2);
        fp8x4_dec2(vua.x, wa2);  fp8x4_dec2(vua.y, wa2 + 2);
        fp8x4_dec2(vub.x, wb2);  fp8x4_dec2(vub.y, wb2 + 2);
        float2v da2 = q2[0] * ka2[0];
        float2v db2 = q2[0] * kb2[0];
        da2 += q2[1] * ka2[1];  db2 += q2[1] * kb2[1];
        da2 += q2[2] * ka2[2];  db2 += q2[2] * kb2[2];
        da2 += q2[3] * ka2[3];  db2 += q2[3] * kb2[3];
        float da = da2.x + da2.y;
        float db = db2.x + db2.y;
        da += __shfl_xor(da, 1);  db += __shfl_xor(db, 1);
        da += __shfl_xor(da, 2);  db += __shfl_xor(db, 2);
        da += __shfl_xor(da, 4);  db += __shfl_xor(db, 4);
        float pea = va ? __expf(da) : 0.f;
        float peb = vb ? __expf(db) : 0.f;
        l += pea + peb;
        float2v pa; pa.x = pea; pa.y = pea;
        float2v pb; pb.x = peb; pb.y = peb;
        #pragma unroll
        for (int i = 0; i < 4; i++) {
            o2[i] += pa * wa2[i];
            o2[i] += pb * wb2[i];
        }
    }
    #pragma unroll
    for (int offx = 16; offx <= 32; offx <<= 1) {
        l += __shfl_xor(l, offx);
        #pragma unroll
        for (int i = 0; i < 4; i++) {
            o2[i].x += __shfl_xor(o2[i].x, offx);
            o2[i].y += __shfl_xor(o2[i].y, offx);
        }
    }

    if (qtr == 0) {
        float inv = 1.f / (l + 1e-16f);
        float o[8] = {o2[0].x, o2[0].y, o2[1].x, o2[1].y,
                      o2[2].x, o2[2].y, o2[3].x, o2[3].y};
        float sv[8];
        {
            uint4 su = *reinterpret_cast<const uint4*>(row_qs + 128 + c0);
            sv[0] = bf2f(su.x & 0xffff); sv[1] = bf2f(su.x >> 16);
            sv[2] = bf2f(su.y & 0xffff); sv[3] = bf2f(su.y >> 16);
            sv[4] = bf2f(su.z & 0xffff); sv[5] = bf2f(su.z >> 16);
            sv[6] = bf2f(su.w & 0xffff); sv[7] = bf2f(su.w >> 16);
        }
        float gv[8], bv[8], mv[8], vr[8];
        *reinterpret_cast<float4*>(gv)     = *reinterpret_cast<const float4*>(bng + c0);
        *reinterpret_cast<float4*>(gv + 4) = *reinterpret_cast<const float4*>(bng + c0 + 4);
        *reinterpret_cast<float4*>(bv)     = *reinterpret_cast<const float4*>(bnb + c0);
        *reinterpret_cast<float4*>(bv + 4) = *reinterpret_cast<const float4*>(bnb + c0 + 4);
        *reinterpret_cast<float4*>(mv)     = *reinterpret_cast<const float4*>(bnm + c0);
        *reinterpret_cast<float4*>(mv + 4) = *reinterpret_cast<const float4*>(bnm + c0 + 4);
        *reinterpret_cast<float4*>(vr)     = *reinterpret_cast<const float4*>(bnv + c0);
        *reinterpret_cast<float4*>(vr + 4) = *reinterpret_cast<const float4*>(bnv + c0 + 4);
        uint_t hw[4];
        #pragma unroll
        for (int i = 0; i < 8; i++) {
            float val = fmaxf(o[i] * inv + sv[i], 0.f);
            val = (val - mv[i]) * rsqrtf(vr[i] + 1e-5f) * gv[i] + bv[i];
            val = fmaxf(val, 0.f);
            ushort_t hb = f2bf(val);
            if (i & 1) hw[i >> 1] |= (uint_t)hb << 16;
            else       hw[i >> 1] = hb;
        }
        int rt = n >> 4, mnode = n & 15;
        int kt = s16 >> 2, qd = s16 & 3;
        size_t fidx = (size_t)rt * 2048 + kt * 512 + (mnode + 16 * qd) * 8;
        uint4 hp; hp.x = hw[0]; hp.y = hw[1]; hp.z = hw[2]; hp.w = hw[3];
        *reinterpret_cast<uint4*>(h + fidx) = hp;
    }
}

// ---------- global mean pool v3: coalesced load -> LDS transpose -> --------
// register run-length per channel. 782 blocks, <=2-way atomic contention.
__global__ __launch_bounds__(256) void pool_kernel(
    const ushort_t* __restrict__ h, const int* __restrict__ batch,
    float* __restrict__ sums, float* __restrict__ cnt) {
    __shared__ float lsum[64][129];   // pad 129: conflict-free both phases
    int t = threadIdx.x;
    int rt0 = blockIdx.x * 4;
    int m16 = t & 15;
    int cb = ((t >> 6) & 3) * 32 + ((t >> 4) & 3) * 8;
    #pragma unroll
    for (int i = 0; i < 4; i++) {
        int rt = rt0 + i;
        int nl = i * 16 + m16;
        float* dst = &lsum[nl][cb];
        if (rt < N_RT) {
            uint4 d = *reinterpret_cast<const uint4*>(
                h + (size_t)rt * 2048 + (size_t)t * 8);
            dst[0] = bf2f(d.x & 0xffff); dst[1] = bf2f(d.x >> 16);
            dst[2] = bf2f(d.y & 0xffff); dst[3] = bf2f(d.y >> 16);
            dst[4] = bf2f(d.z & 0xffff); dst[5] = bf2f(d.z >> 16);
            dst[6] = bf2f(d.w & 0xffff); dst[7] = bf2f(d.w >> 16);
        } else {
            #pragma unroll
            for (int j = 0; j < 8; j++) dst[j] = 0.f;
        }
    }
    __syncthreads();
    int c = t & 127;
    int n0 = (t >> 7) * 32;
    int nbase = rt0 * 16;
    float acc = 0.f, ncnt = 0.f;
    int gcur = -1;
    for (int i = 0; i < 32; i++) {
        int nl = n0 + i;
        int n = nbase + nl;
        if (n >= N_NODES) break;
        int g = batch[n];
        if (g != gcur) {
            if (gcur >= 0) {
                atomicAdd(&sums[gcur * 128 + c], acc);
                if (c == 0) atomicAdd(&cnt[gcur], ncnt);
            }
            acc = 0.f; ncnt = 0.f; gcur = g;
        }
        acc += lsum[nl][c];
        ncnt += 1.f;
    }
    if (gcur >= 0) {
        atomicAdd(&sums[gcur * 128 + c], acc);
        if (c == 0) atomicAdd(&cnt[gcur], ncnt);
    }
}

// ---------- final head: gbuf@Wfus[0:128] + fusdoc -> relu -> task/time -----
__global__ __launch_bounds__(128) void final_mlp(
    const float* __restrict__ sums, const float* __restrict__ cnt,
    const float* __restrict__ fusdoc, const float* __restrict__ Wfus,
    const float* __restrict__ Wtask, const float* __restrict__ btask,
    const float* __restrict__ Wtime, const float* __restrict__ btime,
    float* __restrict__ out) {
    int b = blockIdx.x;
    int t = threadIdx.x;
    __shared__ float gbuf[128], fbuf[128];
    float c = fmaxf(cnt[b], 1.0f);
    gbuf[t] = sums[b * 128 + t] / c;
    __syncthreads();
    float f = fusdoc[b * 128 + t];
    #pragma unroll 8
    for (int k = 0; k < 128; k++) f += gbuf[k] * Wfus[(size_t)k * 128 + t];
    fbuf[t] = fmaxf(f, 0.f);
    __syncthreads();
    if (t < 16) {
        float a = btask[t];
        #pragma unroll 8
        for (int k = 0; k < 128; k++) a += fbuf[k] * Wtask[k * 16 + t];
        out[b * 16 + t] = a;
    } else if (t == 16) {
        float a = btime[0];
        #pragma unroll 8
        for (int k = 0; k < 128; k++) a += fbuf[k] * Wtime[k];
        out[NGRAPH * 16 + b] = a;
    }
}

extern "C" void kernel_launch(void* const* d_in, const int* in_sizes, int n_in,
                              void* d_out, int out_size, void* d_ws, size_t ws_size,
                              hipStream_t stream) {
    (void)in_sizes; (void)n_in; (void)out_size; (void)ws_size;
    const float* x    = (const float*)d_in[0];
    const int*   ei   = (const int*)d_in[1];
    const int*   batch= (const int*)d_in[2];
    const float* ts   = (const float*)d_in[3];
    const float* doc  = (const float*)d_in[4];
    const float* Wq1  = (const float*)d_in[5];
    const float* bq1  = (const float*)d_in[6];
    const float* Wk1  = (const float*)d_in[7];
    const float* bk1  = (const float*)d_in[8];
    const float* Wv1  = (const float*)d_in[9];
    const float* bv1  = (const float*)d_in[10];
    const float* Ws1  = (const float*)d_in[11];
    const float* bs1  = (const float*)d_in[12];
    const float* Wq2  = (const float*)d_in[13];
    const float* bq2  = (const float*)d_in[14];
    const float* Wk2  = (const float*)d_in[15];
    const float* bk2  = (const float*)d_in[16];
    const float* Wv2  = (const float*)d_in[17];
    const float* bv2  = (const float*)d_in[18];
    const float* Ws2  = (const float*)d_in[19];
    const float* bs2  = (const float*)d_in[20];
    const float* bn1g = (const float*)d_in[21];
    const float* bn1b = (const float*)d_in[22];
    const float* bn1m = (const float*)d_in[23];
    const float* bn1v = (const float*)d_in[24];
    const float* bn2g = (const float*)d_in[25];
    const float* bn2b = (const float*)d_in[26];
    const float* bn2m = (const float*)d_in[27];
    const float* bn2v = (const float*)d_in[28];
    const float* Wdoc = (const float*)d_in[29];
    const float* bdoc = (const float*)d_in[30];
    const float* Wfus = (const float*)d_in[31];
    const float* bfus = (const float*)d_in[32];
    const float* Wtask= (const float*)d_in[33];
    const float* btask= (const float*)d_in[34];
    const float* Wtime= (const float*)d_in[35];
    const float* btime= (const float*)d_in[36];

    char* ws = (char*)d_ws;
    ushort_t* h      = (ushort_t*)(ws + 0);           // 12.8 MB
    ushort_t* qsb    = (ushort_t*)(ws + 12800000);    // 25.6 MB
    uchar_t*  kv8    = (uchar_t*)(ws + 38400000);     // 12.8 MB
    ushort_t* WF     = (ushort_t*)(ws + 51200000);    // 256 KB
    float*    biasc  = (float*)(ws + 51462144);       // 4 KB
    float*    sums   = (float*)(ws + 51466240);       // 32768 B
    float*    cnt    = (float*)(ws + 51499008);       // 256 B
    int*      off    = (int*)(ws + 51499264);         // 200004 B
    int*      bucketcur = (int*)(ws + 51699268);      // 784 B
    int*      arena  = (int*)(ws + 51700052);         // 196*8192*4 = 6.42 MB
    int*      csr    = (int*)(ws + 58122580);         // 3.2 MB
    float*    docemb = (float*)(ws + 61322580);       // 32 KB
    float*    fusdoc = (float*)(ws + 61355348);       // 32 KB

    float* out = (float*)d_out;

    hipMemsetAsync(bucketcur, 0, 784, stream);

    prep_kernel<<<NBKT + NB_TEMP + NB_WS + NGRAPH, 256, 0, stream>>>(
        ei, bucketcur, arena, x, ts, h,
        Wq1, Wk1, Wv1, Ws1, Wq2, Wk2, Wv2, Ws2,
        bq1, bk1, bv1, bs1, bq2, bk2, bv2, bs2, WF, biasc,
        doc, Wdoc, bdoc, docemb, sums, cnt);

    const size_t WF_LAYER = 65536;  // shorts per layer

    // ---- layer 1 (gemm fused with passB(off+csr) + fusdoc) ----
    g1_kernel<<<NBKT + NB_GEMM + NGRAPH, 256, 0, stream>>>(
        off, arena, bucketcur, csr, h, WF, biasc, qsb, kv8,
        docemb, Wfus, bfus, fusdoc);
    node_attn_bn<<<12500, 256, 0, stream>>>(off, csr, qsb, kv8, bn1g, bn1b, bn1m, bn1v, h);

    // ---- layer 2 ----
    gemm_qkvs<<<dim3(391, 4), 256, 0, stream>>>(h, WF + WF_LAYER, biasc + 512, qsb, kv8);
    node_attn_bn<<<12500, 256, 0, stream>>>(off, csr, qsb, kv8, bn2g, bn2b, bn2m, bn2v, h);

    // ---- pool + final head ----
    pool_kernel<<<NB_POOL, 256, 0, stream>>>(h, batch, sums, cnt);
    final_mlp<<<NGRAPH, 128, 0, stream>>>(sums, cnt, fusdoc, Wfus,
                                          Wtask, btask, Wtime, btime, out);
}